// Round 1
// baseline (1349.919 us; speedup 1.0000x reference)
//
#include <hip/hip_runtime.h>

#define NN 50000
#define NE 800000
#define NT 850000   // NE + NN self-loops
#define FN 128
#define HH 256      // HEADS*HID
#define HID 64

__device__ __forceinline__ float lrelu(float v){ return v >= 0.f ? v : 0.2f * v; }
__device__ __forceinline__ float elu_(float v){ return v > 0.f ? v : expm1f(v); }

// h1 = x @ W1   (NN x 128) @ (128 x 256), 8 rows per block
__global__ void k_gemm1(const float* __restrict__ x, const float* __restrict__ W,
                        float* __restrict__ h1){
  __shared__ float xs[8][FN];
  int row0 = blockIdx.x * 8;
  int t = threadIdx.x;
  for (int i = t; i < 8 * FN; i += 256){
    int r = i >> 7, c = i & 127;
    xs[r][c] = x[(row0 + r) * FN + c];
  }
  __syncthreads();
  float acc[8] = {0.f,0.f,0.f,0.f,0.f,0.f,0.f,0.f};
  for (int k = 0; k < FN; ++k){
    float w = W[k * HH + t];
#pragma unroll
    for (int r = 0; r < 8; ++r) acc[r] = fmaf(xs[r][k], w, acc[r]);
  }
#pragma unroll
  for (int r = 0; r < 8; ++r) h1[(row0 + r) * HH + t] = acc[r];
}

// per-node attention logits, 4 heads; one block per node, wave per head
__global__ void k_alpha1(const float* __restrict__ h1, const float* __restrict__ as_,
                         const float* __restrict__ ad_, float* __restrict__ als,
                         float* __restrict__ ald){
  int n = blockIdx.x; int t = threadIdx.x;
  float hv = h1[n * HH + t];
  float vs = hv * as_[t];
  float vd = hv * ad_[t];
#pragma unroll
  for (int off = 32; off > 0; off >>= 1){ vs += __shfl_down(vs, off); vd += __shfl_down(vd, off); }
  if ((t & 63) == 0){ int head = t >> 6; als[n*4 + head] = vs; ald[n*4 + head] = vd; }
}

// softmax denominators, layer 1 (4 heads)
__global__ void k_den1(const int* __restrict__ ei, const float* __restrict__ als,
                       const float* __restrict__ ald, float* __restrict__ den){
  int e = blockIdx.x * 256 + threadIdx.x;
  if (e >= NT) return;
  int s, d;
  if (e < NE){ s = ei[e]; d = ei[NE + e]; } else { s = d = e - NE; }
  float4 a = *(const float4*)(als + s*4);
  float4 b = *(const float4*)(ald + d*4);
  atomicAdd(den + d*4 + 0, expf(lrelu(a.x + b.x)));
  atomicAdd(den + d*4 + 1, expf(lrelu(a.y + b.y)));
  atomicAdd(den + d*4 + 2, expf(lrelu(a.z + b.z)));
  atomicAdd(den + d*4 + 3, expf(lrelu(a.w + b.w)));
}

// scatter aggregate, layer 1: out1[d,:] += h1[s,:] * alpha
#define EPB1 8
__global__ void k_agg1(const int* __restrict__ ei, const float* __restrict__ h1,
                       const float* __restrict__ als, const float* __restrict__ ald,
                       const float* __restrict__ den, float* __restrict__ out1){
  int t = threadIdx.x; int head = t >> 6;
  long e0 = (long)blockIdx.x * EPB1;
  for (int i = 0; i < EPB1; ++i){
    long e = e0 + i;
    if (e >= NT) return;
    int s, d;
    if (e < NE){ s = ei[e]; d = ei[NE + e]; } else { s = d = (int)(e - NE); }
    float ev = lrelu(als[s*4 + head] + ald[d*4 + head]);
    float w  = expf(ev) / (den[d*4 + head] + 1e-16f);
    atomicAdd(out1 + d * HH + t, h1[s * HH + t] * w);
  }
}

__global__ void k_fin1(float* __restrict__ g, const float* __restrict__ b){
  int i = blockIdx.x * 256 + threadIdx.x;   // 12.8M elems, exact
  g[i] = elu_(g[i] + b[i & 255]);
}

// h2 = g1 @ W2  (NN x 256) @ (256 x 64), 16 rows per block
__global__ void k_gemm2(const float* __restrict__ g, const float* __restrict__ W,
                        float* __restrict__ h2){
  __shared__ float xs[16][HH];
  int row0 = blockIdx.x * 16;
  int t = threadIdx.x;
  for (int i = t; i < 16 * HH; i += 256){
    int r = i >> 8, c = i & 255;
    xs[r][c] = g[(row0 + r) * HH + c];
  }
  __syncthreads();
  int col = t & 63, rs = t >> 6;
  float acc[4] = {0.f,0.f,0.f,0.f};
  for (int k = 0; k < HH; ++k){
    float w = W[k * HID + col];
#pragma unroll
    for (int j = 0; j < 4; ++j) acc[j] = fmaf(xs[rs*4 + j][k], w, acc[j]);
  }
#pragma unroll
  for (int j = 0; j < 4; ++j) h2[(row0 + rs*4 + j) * HID + col] = acc[j];
}

// attention logits layer 2 (1 head), 4 nodes per block (wave per node)
__global__ void k_alpha2(const float* __restrict__ h2, const float* __restrict__ as_,
                         const float* __restrict__ ad_, float* __restrict__ als,
                         float* __restrict__ ald){
  int t = threadIdx.x; int wv = t >> 6, lane = t & 63;
  int n = blockIdx.x * 4 + wv;
  float hv = h2[n * HID + lane];
  float vs = hv * as_[lane];
  float vd = hv * ad_[lane];
#pragma unroll
  for (int off = 32; off > 0; off >>= 1){ vs += __shfl_down(vs, off); vd += __shfl_down(vd, off); }
  if (lane == 0){ als[n] = vs; ald[n] = vd; }
}

__global__ void k_den2(const int* __restrict__ ei, const float* __restrict__ als,
                       const float* __restrict__ ald, float* __restrict__ den){
  int e = blockIdx.x * 256 + threadIdx.x;
  if (e >= NT) return;
  int s, d;
  if (e < NE){ s = ei[e]; d = ei[NE + e]; } else { s = d = e - NE; }
  atomicAdd(den + d, expf(lrelu(als[s] + ald[d])));
}

#define EPB2 16
__global__ void k_agg2(const int* __restrict__ ei, const float* __restrict__ h2,
                       const float* __restrict__ als, const float* __restrict__ ald,
                       const float* __restrict__ den, float* __restrict__ out2){
  int t = threadIdx.x; int wv = t >> 6, lane = t & 63;
  long e0 = (long)blockIdx.x * EPB2 + wv;
  for (int i = 0; i < EPB2; i += 4){
    long e = e0 + i;
    if (e >= NT) continue;
    int s, d;
    if (e < NE){ s = ei[e]; d = ei[NE + e]; } else { s = d = (int)(e - NE); }
    float w = expf(lrelu(als[s] + ald[d])) / (den[d] + 1e-16f);
    atomicAdd(out2 + d * HID + lane, h2[s * HID + lane] * w);
  }
}

__global__ void k_fin2(float* __restrict__ g, const float* __restrict__ b){
  int i = blockIdx.x * 256 + threadIdx.x;   // 3.2M elems, exact
  g[i] = elu_(g[i] + b[i & 63]);
}

// task encoder + fold classifier: tWb[b,c] = (relu(task@teW1+teb1)@teW2+teb2)@Wt + cl_b1
__global__ void k_task(const float* __restrict__ task, const float* __restrict__ W1t,
                       const float* __restrict__ b1t, const float* __restrict__ W2t,
                       const float* __restrict__ b2t, const float* __restrict__ clW1,
                       const float* __restrict__ clb1, float* __restrict__ tWb){
  __shared__ float t1[16][64];
  __shared__ float t2[16][64];
  int t = threadIdx.x;
  for (int idx = t; idx < 1024; idx += 256){
    int b = idx >> 6, c = idx & 63;
    float acc = b1t[c];
    for (int k = 0; k < 128; ++k) acc = fmaf(task[b*128 + k], W1t[k*64 + c], acc);
    t1[b][c] = fmaxf(acc, 0.f);
  }
  __syncthreads();
  for (int idx = t; idx < 1024; idx += 256){
    int b = idx >> 6, c = idx & 63;
    float acc = b2t[c];
    for (int k = 0; k < 64; ++k) acc = fmaf(t1[b][k], W2t[k*64 + c], acc);
    t2[b][c] = acc;
  }
  __syncthreads();
  for (int idx = t; idx < 1024; idx += 256){
    int b = idx >> 6, c = idx & 63;
    float acc = clb1[c];
    for (int k = 0; k < 64; ++k) acc = fmaf(t2[b][k], clW1[(64 + k)*64 + c], acc);
    tWb[idx] = acc;
  }
}

// hW = h_final @ Wh (cl_W1 rows 0..63), 16 rows per block
__global__ void k_hw(const float* __restrict__ h, const float* __restrict__ clW1,
                     float* __restrict__ hW){
  __shared__ float xs[16][64];
  int row0 = blockIdx.x * 16;
  int t = threadIdx.x;
  for (int i = t; i < 16 * 64; i += 256){ int r = i >> 6, c = i & 63; xs[r][c] = h[(row0 + r)*64 + c]; }
  __syncthreads();
  int col = t & 63, rs = t >> 6;
  float acc[4] = {0.f,0.f,0.f,0.f};
  for (int k = 0; k < 64; ++k){
    float w = clW1[k*64 + col];
#pragma unroll
    for (int j = 0; j < 4; ++j) acc[j] = fmaf(xs[rs*4 + j][k], w, acc[j]);
  }
#pragma unroll
  for (int j = 0; j < 4; ++j) hW[(row0 + rs*4 + j)*64 + col] = acc[j];
}

// scores[b,n] = sum_k relu(hW[n,k] + tWb[b,k]) * w2[k] + cl_b2
__global__ void k_scores(const float* __restrict__ hW, const float* __restrict__ tWb,
                         const float* __restrict__ w2, const float* __restrict__ b2s,
                         float* __restrict__ out){
  __shared__ float tw[16][64];
  __shared__ float w2s[64];
  int t = threadIdx.x;
  for (int i = t; i < 1024; i += 256) tw[i >> 6][i & 63] = tWb[i];
  if (t < 64) w2s[t] = w2[t];
  __syncthreads();
  int wv = t >> 6, lane = t & 63;
  int n = blockIdx.x * 4 + wv;
  float hv = hW[n * 64 + lane];
  float bias = b2s[0];
  for (int b = 0; b < 16; ++b){
    float v = fmaxf(hv + tw[b][lane], 0.f) * w2s[lane];
#pragma unroll
    for (int off = 32; off > 0; off >>= 1) v += __shfl_xor(v, off);
    if (lane == b) out[b * NN + n] = v + bias;
  }
}

extern "C" void kernel_launch(void* const* d_in, const int* in_sizes, int n_in,
                              void* d_out, int out_size, void* d_ws, size_t ws_size,
                              hipStream_t stream){
  const float* x    = (const float*)d_in[0];
  const int*   ei   = (const int*)  d_in[1];
  const float* task = (const float*)d_in[2];
  const float* W1   = (const float*)d_in[3];
  const float* as1  = (const float*)d_in[4];
  const float* ad1  = (const float*)d_in[5];
  const float* b1   = (const float*)d_in[6];
  const float* W2   = (const float*)d_in[7];
  const float* as2  = (const float*)d_in[8];
  const float* ad2  = (const float*)d_in[9];
  const float* b2   = (const float*)d_in[10];
  const float* teW1 = (const float*)d_in[11];
  const float* teb1 = (const float*)d_in[12];
  const float* teW2 = (const float*)d_in[13];
  const float* teb2 = (const float*)d_in[14];
  const float* clW1 = (const float*)d_in[15];
  const float* clb1 = (const float*)d_in[16];
  const float* clW2 = (const float*)d_in[17];
  const float* clb2 = (const float*)d_in[18];
  float* out = (float*)d_out;
  float* ws  = (float*)d_ws;

  // region layout (floats)
  float* h1   = ws;                 // 12,800,000
  float* g1   = ws + 12800000;      // 12,800,000 (out1, then elu in place)
  float* als1 = ws + 25600000;      // 200,000
  float* ald1 = als1 + 200000;      // 200,000
  float* den1 = ald1 + 200000;      // 200,000
  // layer-2 region reuses h1's panel (free after k_agg1/k_fin1)
  float* h2   = ws;                 // 3,200,000
  float* o2   = ws + 3200000;       // 3,200,000
  float* hW   = ws + 6400000;       // 3,200,000
  float* als2 = ws + 9600000;       // 50,000
  float* ald2 = als2 + 50000;       // 50,000
  float* den2 = ald2 + 50000;       // 50,000
  float* tWb  = den2 + 50000;       // 1,024

  // ---- layer 1 ----
  hipMemsetAsync(g1,   0, 12800000 * sizeof(float), stream);
  hipMemsetAsync(den1, 0,   200000 * sizeof(float), stream);
  k_gemm1 <<<6250, 256, 0, stream>>>(x, W1, h1);
  k_alpha1<<<50000, 256, 0, stream>>>(h1, as1, ad1, als1, ald1);
  k_den1  <<<(NT + 255)/256, 256, 0, stream>>>(ei, als1, ald1, den1);
  k_agg1  <<<(NT + EPB1 - 1)/EPB1, 256, 0, stream>>>(ei, h1, als1, ald1, den1, g1);
  k_fin1  <<<50000, 256, 0, stream>>>(g1, b1);
  // ---- layer 2 ----
  k_gemm2 <<<3125, 256, 0, stream>>>(g1, W2, h2);
  hipMemsetAsync(o2,   0, 3200000 * sizeof(float), stream);
  hipMemsetAsync(den2, 0,   50000 * sizeof(float), stream);
  k_alpha2<<<12500, 256, 0, stream>>>(h2, as2, ad2, als2, ald2);
  k_den2  <<<(NT + 255)/256, 256, 0, stream>>>(ei, als2, ald2, den2);
  k_agg2  <<<(NT + EPB2 - 1)/EPB2, 256, 0, stream>>>(ei, h2, als2, ald2, den2, o2);
  k_fin2  <<<12500, 256, 0, stream>>>(o2, b2);
  // ---- task encoder + classifier ----
  k_task  <<<1, 256, 0, stream>>>(task, teW1, teb1, teW2, teb2, clW1, clb1, tWb);
  k_hw    <<<3125, 256, 0, stream>>>(o2, clW1, hW);
  k_scores<<<12500, 256, 0, stream>>>(hW, tWb, clW2, clb2, out);
}

// Round 2
// 742.311 us; speedup vs baseline: 1.8185x; 1.8185x over previous
//
#include <hip/hip_runtime.h>

#define NN 50000
#define NE 800000
#define FN 128
#define HH 256      // HEADS*HID
#define HID 64

__device__ __forceinline__ float lrelu(float v){ return v >= 0.f ? v : 0.2f * v; }
__device__ __forceinline__ float elu_(float v){ return v > 0.f ? v : expm1f(v); }

// ---------- CSR build ----------
__global__ void k_deg(const int* __restrict__ ei, int* __restrict__ deg){
  int e = blockIdx.x * 256 + threadIdx.x;
  if (e >= NE) return;
  atomicAdd(deg + ei[NE + e], 1);
}

__global__ void k_scan(const int* __restrict__ deg, int* __restrict__ rs, int* __restrict__ cur){
  __shared__ int part[256];
  int t = threadIdx.x;
  const int CH = 196;            // 256*196 = 50176 >= NN
  int base = t * CH;
  int s = 0;
  for (int i = 0; i < CH; ++i){ int idx = base + i; if (idx < NN) s += deg[idx]; }
  part[t] = s; __syncthreads();
  for (int off = 1; off < 256; off <<= 1){
    int v = (t >= off) ? part[t - off] : 0;
    __syncthreads();
    part[t] += v;
    __syncthreads();
  }
  int run = part[t] - s;         // exclusive prefix at chunk start
  for (int i = 0; i < CH; ++i){
    int idx = base + i;
    if (idx < NN){ rs[idx] = run; cur[idx] = run; run += deg[idx]; }
  }
  if (t == 255) rs[NN] = part[255];
}

__global__ void k_scatter(const int* __restrict__ ei, int* __restrict__ cur, int* __restrict__ csr){
  int e = blockIdx.x * 256 + threadIdx.x;
  if (e >= NE) return;
  int s = ei[e], d = ei[NE + e];
  int pos = atomicAdd(cur + d, 1);
  csr[pos] = s;
}

// ---------- h1 = x @ W1 (+ fused alpha1) ----------
__global__ void k_gemm1(const float* __restrict__ x, const float* __restrict__ W,
                        const float* __restrict__ as1, const float* __restrict__ ad1,
                        float* __restrict__ h1, float* __restrict__ als, float* __restrict__ ald){
  __shared__ float xs[8][FN];
  int row0 = blockIdx.x * 8;
  int t = threadIdx.x;
  for (int i = t; i < 8 * FN; i += 256){
    int r = i >> 7, c = i & 127;
    xs[r][c] = x[(row0 + r) * FN + c];
  }
  __syncthreads();
  float acc[8] = {0.f,0.f,0.f,0.f,0.f,0.f,0.f,0.f};
  for (int k = 0; k < FN; ++k){
    float w = W[k * HH + t];
#pragma unroll
    for (int r = 0; r < 8; ++r) acc[r] = fmaf(xs[r][k], w, acc[r]);
  }
  float avs = as1[t], avd = ad1[t];
#pragma unroll
  for (int r = 0; r < 8; ++r){
    h1[(row0 + r) * HH + t] = acc[r];
    float vs = acc[r] * avs, vd = acc[r] * avd;
#pragma unroll
    for (int off = 32; off > 0; off >>= 1){ vs += __shfl_down(vs, off); vd += __shfl_down(vd, off); }
    if ((t & 63) == 0){
      int head = t >> 6;
      als[(row0 + r) * 4 + head] = vs;
      ald[(row0 + r) * 4 + head] = vd;
    }
  }
}

// ---------- fused layer1 aggregate + ELU + gemm2 + alpha2 ----------
// 4 nodes per block, 256 threads
__global__ void k_agg1f(const int* __restrict__ rs, const int* __restrict__ csr,
                        const float* __restrict__ h1, const float* __restrict__ als,
                        const float* __restrict__ ald, const float* __restrict__ b1,
                        const float* __restrict__ W2, const float* __restrict__ as2,
                        const float* __restrict__ ad2, float* __restrict__ h2,
                        float* __restrict__ als2, float* __restrict__ ald2){
  __shared__ float gs[4][HH];
  __shared__ float h2s[4][HID];
  int t = threadIdx.x; int head = t >> 6, lane = t & 63;
  int n0 = blockIdx.x * 4;
#pragma unroll 1
  for (int j = 0; j < 4; ++j){
    int n = n0 + j;
    float aldn = ald[n * 4 + head];
    float w = expf(lrelu(als[n * 4 + head] + aldn));   // self-loop
    float den = w;
    float acc = w * h1[n * HH + t];
    int e0 = rs[n], e1 = rs[n + 1];
    for (int e = e0; e < e1; ++e){
      int s = csr[e];
      float we = expf(lrelu(als[s * 4 + head] + aldn));
      den += we;
      acc = fmaf(we, h1[s * HH + t], acc);
    }
    gs[j][t] = elu_(acc / (den + 1e-16f) + b1[t]);
  }
  __syncthreads();
  // h2 row = g @ W2 : thread (row=head, col=lane)
  {
    float acc = 0.f;
    const float* g = gs[head];
    for (int k = 0; k < HH; ++k) acc = fmaf(g[k], W2[k * HID + lane], acc);
    h2[(n0 + head) * HID + lane] = acc;
    h2s[head][lane] = acc;
  }
  __syncthreads();
  {
    float hv = h2s[head][lane];
    float vs = hv * as2[lane], vd = hv * ad2[lane];
#pragma unroll
    for (int off = 32; off > 0; off >>= 1){ vs += __shfl_down(vs, off); vd += __shfl_down(vd, off); }
    if (lane == 0){ als2[n0 + head] = vs; ald2[n0 + head] = vd; }
  }
}

// ---------- fused layer2 aggregate + ELU + hW projection ----------
// 4 nodes per block (one wave per node)
__global__ void k_agg2f(const int* __restrict__ rs, const int* __restrict__ csr,
                        const float* __restrict__ h2, const float* __restrict__ als,
                        const float* __restrict__ ald, const float* __restrict__ b2,
                        const float* __restrict__ clW1, float* __restrict__ hW){
  __shared__ float os[4][HID];
  int t = threadIdx.x; int wv = t >> 6, lane = t & 63;
  int n = blockIdx.x * 4 + wv;
  float aldn = ald[n];
  float w = expf(lrelu(als[n] + aldn));                // self-loop
  float den = w;
  float acc = w * h2[n * HID + lane];
  int e0 = rs[n], e1 = rs[n + 1];
  for (int e = e0; e < e1; ++e){
    int s = csr[e];
    float we = expf(lrelu(als[s] + aldn));
    den += we;
    acc = fmaf(we, h2[s * HID + lane], acc);
  }
  os[wv][lane] = elu_(acc / (den + 1e-16f) + b2[lane]);
  __syncthreads();
  float a2 = 0.f;
  const float* o = os[wv];
  for (int k = 0; k < HID; ++k) a2 = fmaf(o[k], clW1[k * HID + lane], a2);
  hW[n * HID + lane] = a2;
}

// ---------- task encoder + fold classifier bias ----------
__global__ void k_task(const float* __restrict__ task, const float* __restrict__ W1t,
                       const float* __restrict__ b1t, const float* __restrict__ W2t,
                       const float* __restrict__ b2t, const float* __restrict__ clW1,
                       const float* __restrict__ clb1, float* __restrict__ tWb){
  __shared__ float t1[16][64];
  __shared__ float t2[16][64];
  int t = threadIdx.x;
  for (int idx = t; idx < 1024; idx += 256){
    int b = idx >> 6, c = idx & 63;
    float acc = b1t[c];
    for (int k = 0; k < 128; ++k) acc = fmaf(task[b*128 + k], W1t[k*64 + c], acc);
    t1[b][c] = fmaxf(acc, 0.f);
  }
  __syncthreads();
  for (int idx = t; idx < 1024; idx += 256){
    int b = idx >> 6, c = idx & 63;
    float acc = b2t[c];
    for (int k = 0; k < 64; ++k) acc = fmaf(t1[b][k], W2t[k*64 + c], acc);
    t2[b][c] = acc;
  }
  __syncthreads();
  for (int idx = t; idx < 1024; idx += 256){
    int b = idx >> 6, c = idx & 63;
    float acc = clb1[c];
    for (int k = 0; k < 64; ++k) acc = fmaf(t2[b][k], clW1[(64 + k)*64 + c], acc);
    tWb[idx] = acc;
  }
}

// ---------- scores[b,n] = sum_k relu(hW[n,k] + tWb[b,k]) * w2[k] + cl_b2 ----------
__global__ void k_scores(const float* __restrict__ hW, const float* __restrict__ tWb,
                         const float* __restrict__ w2, const float* __restrict__ b2s,
                         float* __restrict__ out){
  __shared__ float tw[16][64];
  __shared__ float w2s[64];
  int t = threadIdx.x;
  for (int i = t; i < 1024; i += 256) tw[i >> 6][i & 63] = tWb[i];
  if (t < 64) w2s[t] = w2[t];
  __syncthreads();
  int wv = t >> 6, lane = t & 63;
  int n = blockIdx.x * 4 + wv;
  float hv = hW[n * 64 + lane];
  float bias = b2s[0];
  for (int b = 0; b < 16; ++b){
    float v = fmaxf(hv + tw[b][lane], 0.f) * w2s[lane];
#pragma unroll
    for (int off = 32; off > 0; off >>= 1) v += __shfl_xor(v, off);
    if (lane == b) out[b * NN + n] = v + bias;
  }
}

extern "C" void kernel_launch(void* const* d_in, const int* in_sizes, int n_in,
                              void* d_out, int out_size, void* d_ws, size_t ws_size,
                              hipStream_t stream){
  const float* x    = (const float*)d_in[0];
  const int*   ei   = (const int*)  d_in[1];
  const float* task = (const float*)d_in[2];
  const float* W1   = (const float*)d_in[3];
  const float* as1  = (const float*)d_in[4];
  const float* ad1  = (const float*)d_in[5];
  const float* b1   = (const float*)d_in[6];
  const float* W2   = (const float*)d_in[7];
  const float* as2  = (const float*)d_in[8];
  const float* ad2  = (const float*)d_in[9];
  const float* b2   = (const float*)d_in[10];
  const float* teW1 = (const float*)d_in[11];
  const float* teb1 = (const float*)d_in[12];
  const float* teW2 = (const float*)d_in[13];
  const float* teb2 = (const float*)d_in[14];
  const float* clW1 = (const float*)d_in[15];
  const float* clb1 = (const float*)d_in[16];
  const float* clW2 = (const float*)d_in[17];
  const float* clb2 = (const float*)d_in[18];
  float* out = (float*)d_out;
  float* ws  = (float*)d_ws;

  // workspace layout (float offsets)
  float* h1   = ws;                        // 12,800,000
  float* als1 = ws + 12800000;             // 200,000
  float* ald1 = als1 + 200000;             // 200,000
  float* h2   = ald1 + 200000;             // 3,200,000
  float* als2 = h2 + 3200000;              // 50,000
  float* ald2 = als2 + 50000;              // 50,000
  float* hW   = ald2 + 50000;              // 3,200,000
  float* tWb  = hW + 3200000;              // 1,024
  int*   deg  = (int*)(tWb + 1024);        // 50,000
  int*   rs   = deg + 50000;               // 50,001
  int*   cur  = rs + 50004;                // 50,000
  int*   csr  = cur + 50000;               // 800,000

  // CSR build
  hipMemsetAsync(deg, 0, 50000 * sizeof(int), stream);
  k_deg    <<<(NE + 255)/256, 256, 0, stream>>>(ei, deg);
  k_scan   <<<1, 256, 0, stream>>>(deg, rs, cur);
  k_scatter<<<(NE + 255)/256, 256, 0, stream>>>(ei, cur, csr);

  // layer 1 (+ fused alpha1, agg, elu, gemm2, alpha2)
  k_gemm1 <<<6250, 256, 0, stream>>>(x, W1, as1, ad1, h1, als1, ald1);
  k_agg1f <<<12500, 256, 0, stream>>>(rs, csr, h1, als1, ald1, b1, W2, as2, ad2, h2, als2, ald2);

  // layer 2 (+ fused elu, hW projection)
  k_agg2f <<<12500, 256, 0, stream>>>(rs, csr, h2, als2, ald2, b2, clW1, hW);

  // task encoder + classifier
  k_task  <<<1, 256, 0, stream>>>(task, teW1, teb1, teW2, teb2, clW1, clb1, tWb);
  k_scores<<<12500, 256, 0, stream>>>(hW, tWb, clW2, clb2, out);
}

// Round 3
// 667.842 us; speedup vs baseline: 2.0213x; 1.1115x over previous
//
#include <hip/hip_runtime.h>
#include <hip/hip_fp16.h>

#define NN 50000
#define NE 800000
#define FN 128
#define HH 256      // HEADS*HID
#define HID 64

__device__ __forceinline__ float lrelu(float v){ return v >= 0.f ? v : 0.2f * v; }
__device__ __forceinline__ float elu_(float v){ return v > 0.f ? v : expm1f(v); }

// ---------- CSR build ----------
__global__ void k_deg(const int* __restrict__ ei, int* __restrict__ deg){
  int e = blockIdx.x * 256 + threadIdx.x;
  if (e >= NE) return;
  atomicAdd(deg + ei[NE + e], 1);
}

__global__ void k_scan(const int* __restrict__ deg, int* __restrict__ rs, int* __restrict__ cur){
  __shared__ int part[256];
  int t = threadIdx.x;
  const int CH = 196;            // 256*196 = 50176 >= NN
  int base = t * CH;
  int s = 0;
  for (int i = 0; i < CH; ++i){ int idx = base + i; if (idx < NN) s += deg[idx]; }
  part[t] = s; __syncthreads();
  for (int off = 1; off < 256; off <<= 1){
    int v = (t >= off) ? part[t - off] : 0;
    __syncthreads();
    part[t] += v;
    __syncthreads();
  }
  int run = part[t] - s;         // exclusive prefix at chunk start
  for (int i = 0; i < CH; ++i){
    int idx = base + i;
    if (idx < NN){ rs[idx] = run; cur[idx] = run; run += deg[idx]; }
  }
  if (t == 255) rs[NN] = part[255];
}

__global__ void k_scatter(const int* __restrict__ ei, int* __restrict__ cur, int* __restrict__ csr){
  int e = blockIdx.x * 256 + threadIdx.x;
  if (e >= NE) return;
  int s = ei[e], d = ei[NE + e];
  int pos = atomicAdd(cur + d, 1);
  csr[pos] = s;
}

// ---------- h1 = x @ W1 (fp16 out, + fused alpha1) ----------
__global__ void k_gemm1(const float* __restrict__ x, const float* __restrict__ W,
                        const float* __restrict__ as1, const float* __restrict__ ad1,
                        __half* __restrict__ h1h, float* __restrict__ als, float* __restrict__ ald){
  __shared__ float xs[8][FN];
  int row0 = blockIdx.x * 8;
  int t = threadIdx.x;
  for (int i = t; i < 8 * FN; i += 256){
    int r = i >> 7, c = i & 127;
    xs[r][c] = x[(row0 + r) * FN + c];
  }
  __syncthreads();
  float acc[8] = {0.f,0.f,0.f,0.f,0.f,0.f,0.f,0.f};
  for (int k = 0; k < FN; ++k){
    float w = W[k * HH + t];
#pragma unroll
    for (int r = 0; r < 8; ++r) acc[r] = fmaf(xs[r][k], w, acc[r]);
  }
  float avs = as1[t], avd = ad1[t];
#pragma unroll
  for (int r = 0; r < 8; ++r){
    h1h[(row0 + r) * HH + t] = (__half)acc[r];
    float vs = acc[r] * avs, vd = acc[r] * avd;
#pragma unroll
    for (int off = 32; off > 0; off >>= 1){ vs += __shfl_down(vs, off); vd += __shfl_down(vd, off); }
    if ((t & 63) == 0){
      int head = t >> 6;
      als[(row0 + r) * 4 + head] = vs;
      ald[(row0 + r) * 4 + head] = vd;
    }
  }
}

// ---------- layer-1 normalized edge weights (wave per node) ----------
__global__ void k_w1(const int* __restrict__ rs, const int* __restrict__ csr,
                     const float* __restrict__ als, const float* __restrict__ ald,
                     float* __restrict__ w1, float* __restrict__ wself){
  int t = threadIdx.x, wv = t >> 6, lane = t & 63;
  int n = blockIdx.x * 4 + wv;
  int e0 = rs[n], e1 = rs[n + 1];
  float4 ad = *(const float4*)(ald + n * 4);
  float d0 = 0.f, d1 = 0.f, d2 = 0.f, d3 = 0.f;
  for (int e = e0 + lane; e < e1; e += 64){
    int s = csr[e];
    float4 a = *(const float4*)(als + s * 4);
    d0 += expf(lrelu(a.x + ad.x)); d1 += expf(lrelu(a.y + ad.y));
    d2 += expf(lrelu(a.z + ad.z)); d3 += expf(lrelu(a.w + ad.w));
  }
#pragma unroll
  for (int off = 32; off > 0; off >>= 1){
    d0 += __shfl_xor(d0, off); d1 += __shfl_xor(d1, off);
    d2 += __shfl_xor(d2, off); d3 += __shfl_xor(d3, off);
  }
  float4 as_ = *(const float4*)(als + n * 4);
  float s0 = expf(lrelu(as_.x + ad.x)), s1 = expf(lrelu(as_.y + ad.y));
  float s2 = expf(lrelu(as_.z + ad.z)), s3 = expf(lrelu(as_.w + ad.w));
  float i0 = 1.f / (d0 + s0 + 1e-16f), i1 = 1.f / (d1 + s1 + 1e-16f);
  float i2 = 1.f / (d2 + s2 + 1e-16f), i3 = 1.f / (d3 + s3 + 1e-16f);
  if (lane == 0){
    wself[n*4 + 0] = s0 * i0; wself[n*4 + 1] = s1 * i1;
    wself[n*4 + 2] = s2 * i2; wself[n*4 + 3] = s3 * i3;
  }
  for (int e = e0 + lane; e < e1; e += 64){
    int s = csr[e];
    float4 a = *(const float4*)(als + s * 4);
    float4 w;
    w.x = expf(lrelu(a.x + ad.x)) * i0; w.y = expf(lrelu(a.y + ad.y)) * i1;
    w.z = expf(lrelu(a.z + ad.z)) * i2; w.w = expf(lrelu(a.w + ad.w)) * i3;
    *(float4*)(w1 + e * 4) = w;
  }
}

// ---------- fused layer1 aggregate + ELU + gemm2 + alpha2 ----------
__global__ void k_agg1f(const int* __restrict__ rs, const int* __restrict__ csr,
                        const __half* __restrict__ h1h, const float* __restrict__ w1,
                        const float* __restrict__ wself, const float* __restrict__ b1,
                        const float* __restrict__ W2, const float* __restrict__ as2,
                        const float* __restrict__ ad2, __half* __restrict__ h2h,
                        float* __restrict__ als2, float* __restrict__ ald2){
  __shared__ float gs[4][HH];
  __shared__ float h2s[4][HID];
  int t = threadIdx.x; int head = t >> 6, lane = t & 63;
  int n0 = blockIdx.x * 4;
#pragma unroll 1
  for (int j = 0; j < 4; ++j){
    int n = n0 + j;
    float acc = wself[n*4 + head] * (float)h1h[n * HH + t];
    int e0 = rs[n], e1 = rs[n + 1];
    int e = e0;
    for (; e + 1 < e1; e += 2){
      int s0 = csr[e], s1 = csr[e + 1];
      float wa = w1[e*4 + head], wb = w1[(e+1)*4 + head];
      float v0 = (float)h1h[s0 * HH + t], v1 = (float)h1h[s1 * HH + t];
      acc = fmaf(wa, v0, acc);
      acc = fmaf(wb, v1, acc);
    }
    if (e < e1){
      int s = csr[e];
      acc = fmaf(w1[e*4 + head], (float)h1h[s * HH + t], acc);
    }
    gs[j][t] = elu_(acc + b1[t]);
  }
  __syncthreads();
  // h2 row = g @ W2 : thread (row=head, col=lane)
  {
    float acc = 0.f;
    const float* g = gs[head];
    for (int k = 0; k < HH; ++k) acc = fmaf(g[k], W2[k * HID + lane], acc);
    h2h[(n0 + head) * HID + lane] = (__half)acc;
    h2s[head][lane] = acc;
  }
  __syncthreads();
  {
    float hv = h2s[head][lane];
    float vs = hv * as2[lane], vd = hv * ad2[lane];
#pragma unroll
    for (int off = 32; off > 0; off >>= 1){ vs += __shfl_down(vs, off); vd += __shfl_down(vd, off); }
    if (lane == 0){ als2[n0 + head] = vs; ald2[n0 + head] = vd; }
  }
}

// ---------- layer-2 normalized edge weights (wave per node) ----------
__global__ void k_w2(const int* __restrict__ rs, const int* __restrict__ csr,
                     const float* __restrict__ als, const float* __restrict__ ald,
                     float* __restrict__ w2c, float* __restrict__ wself){
  int t = threadIdx.x, wv = t >> 6, lane = t & 63;
  int n = blockIdx.x * 4 + wv;
  int e0 = rs[n], e1 = rs[n + 1];
  float ad = ald[n];
  float den = 0.f;
  for (int e = e0 + lane; e < e1; e += 64) den += expf(lrelu(als[csr[e]] + ad));
#pragma unroll
  for (int off = 32; off > 0; off >>= 1) den += __shfl_xor(den, off);
  float sw = expf(lrelu(als[n] + ad));
  float inv = 1.f / (den + sw + 1e-16f);
  if (lane == 0) wself[n] = sw * inv;
  for (int e = e0 + lane; e < e1; e += 64) w2c[e] = expf(lrelu(als[csr[e]] + ad)) * inv;
}

// ---------- fused layer2 aggregate + ELU + hW projection ----------
__global__ void k_agg2f(const int* __restrict__ rs, const int* __restrict__ csr,
                        const __half* __restrict__ h2h, const float* __restrict__ w2c,
                        const float* __restrict__ wself, const float* __restrict__ b2,
                        const float* __restrict__ clW1, float* __restrict__ hW){
  __shared__ float os[4][HID];
  int t = threadIdx.x; int wv = t >> 6, lane = t & 63;
  int n = blockIdx.x * 4 + wv;
  float acc = wself[n] * (float)h2h[n * HID + lane];
  int e0 = rs[n], e1 = rs[n + 1];
  int e = e0;
  for (; e + 1 < e1; e += 2){
    int s0 = csr[e], s1 = csr[e + 1];
    float wa = w2c[e], wb = w2c[e + 1];
    float v0 = (float)h2h[s0 * HID + lane], v1 = (float)h2h[s1 * HID + lane];
    acc = fmaf(wa, v0, acc);
    acc = fmaf(wb, v1, acc);
  }
  if (e < e1) acc = fmaf(w2c[e], (float)h2h[csr[e] * HID + lane], acc);
  os[wv][lane] = elu_(acc + b2[lane]);
  __syncthreads();
  float a2 = 0.f;
  const float* o = os[wv];
  for (int k = 0; k < HID; ++k) a2 = fmaf(o[k], clW1[k * HID + lane], a2);
  hW[n * HID + lane] = a2;
}

// ---------- task encoder + fold classifier bias ----------
__global__ void k_task(const float* __restrict__ task, const float* __restrict__ W1t,
                       const float* __restrict__ b1t, const float* __restrict__ W2t,
                       const float* __restrict__ b2t, const float* __restrict__ clW1,
                       const float* __restrict__ clb1, float* __restrict__ tWb){
  __shared__ float t1[16][64];
  __shared__ float t2[16][64];
  int t = threadIdx.x;
  for (int idx = t; idx < 1024; idx += 256){
    int b = idx >> 6, c = idx & 63;
    float acc = b1t[c];
    for (int k = 0; k < 128; ++k) acc = fmaf(task[b*128 + k], W1t[k*64 + c], acc);
    t1[b][c] = fmaxf(acc, 0.f);
  }
  __syncthreads();
  for (int idx = t; idx < 1024; idx += 256){
    int b = idx >> 6, c = idx & 63;
    float acc = b2t[c];
    for (int k = 0; k < 64; ++k) acc = fmaf(t1[b][k], W2t[k*64 + c], acc);
    t2[b][c] = acc;
  }
  __syncthreads();
  for (int idx = t; idx < 1024; idx += 256){
    int b = idx >> 6, c = idx & 63;
    float acc = clb1[c];
    for (int k = 0; k < 64; ++k) acc = fmaf(t2[b][k], clW1[(64 + k)*64 + c], acc);
    tWb[idx] = acc;
  }
}

// ---------- scores[b,n] = sum_k relu(hW[n,k] + tWb[b,k]) * w2[k] + cl_b2 ----------
__global__ void k_scores(const float* __restrict__ hW, const float* __restrict__ tWb,
                         const float* __restrict__ w2, const float* __restrict__ b2s,
                         float* __restrict__ out){
  __shared__ float tw[16][64];
  __shared__ float w2s[64];
  int t = threadIdx.x;
  for (int i = t; i < 1024; i += 256) tw[i >> 6][i & 63] = tWb[i];
  if (t < 64) w2s[t] = w2[t];
  __syncthreads();
  int wv = t >> 6, lane = t & 63;
  int n = blockIdx.x * 4 + wv;
  float hv = hW[n * 64 + lane];
  float bias = b2s[0];
  for (int b = 0; b < 16; ++b){
    float v = fmaxf(hv + tw[b][lane], 0.f) * w2s[lane];
#pragma unroll
    for (int off = 32; off > 0; off >>= 1) v += __shfl_xor(v, off);
    if (lane == b) out[b * NN + n] = v + bias;
  }
}

extern "C" void kernel_launch(void* const* d_in, const int* in_sizes, int n_in,
                              void* d_out, int out_size, void* d_ws, size_t ws_size,
                              hipStream_t stream){
  const float* x    = (const float*)d_in[0];
  const int*   ei   = (const int*)  d_in[1];
  const float* task = (const float*)d_in[2];
  const float* W1   = (const float*)d_in[3];
  const float* as1  = (const float*)d_in[4];
  const float* ad1  = (const float*)d_in[5];
  const float* b1   = (const float*)d_in[6];
  const float* W2   = (const float*)d_in[7];
  const float* as2  = (const float*)d_in[8];
  const float* ad2  = (const float*)d_in[9];
  const float* b2   = (const float*)d_in[10];
  const float* teW1 = (const float*)d_in[11];
  const float* teb1 = (const float*)d_in[12];
  const float* teW2 = (const float*)d_in[13];
  const float* teb2 = (const float*)d_in[14];
  const float* clW1 = (const float*)d_in[15];
  const float* clb1 = (const float*)d_in[16];
  const float* clW2 = (const float*)d_in[17];
  const float* clb2 = (const float*)d_in[18];
  float* out = (float*)d_out;
  float* ws  = (float*)d_ws;

  // workspace layout (float-sized slots)
  __half* h1h  = (__half*)ws;              // 12.8M halfs  -> 6.4M floats
  float* als1  = ws + 6400000;             // 200,000
  float* ald1  = als1 + 200000;            // 200,000
  float* w1    = ald1 + 200000;            // 3,200,000
  float* wself1= w1 + 3200000;             // 200,000
  __half* h2h  = (__half*)(wself1 + 200000); // 3.2M halfs -> 1.6M floats
  float* als2  = wself1 + 200000 + 1600000; // 50,000
  float* ald2  = als2 + 50000;             // 50,000
  float* w2c   = ald2 + 50000;             // 800,000
  float* wself2= w2c + 800000;             // 50,000
  float* hW    = wself2 + 50000;           // 3,200,000
  float* tWb   = hW + 3200000;             // 1,024
  int*   deg   = (int*)(tWb + 1024);       // 50,000
  int*   rs    = deg + 50000;              // 50,001 (+pad)
  int*   cur   = rs + 50004;               // 50,000
  int*   csr   = cur + 50000;              // 800,000

  // CSR build
  hipMemsetAsync(deg, 0, 50000 * sizeof(int), stream);
  k_deg    <<<(NE + 255)/256, 256, 0, stream>>>(ei, deg);
  k_scan   <<<1, 256, 0, stream>>>(deg, rs, cur);
  k_scatter<<<(NE + 255)/256, 256, 0, stream>>>(ei, cur, csr);

  // layer 1
  k_gemm1 <<<6250, 256, 0, stream>>>(x, W1, as1, ad1, h1h, als1, ald1);
  k_w1    <<<12500, 256, 0, stream>>>(rs, csr, als1, ald1, w1, wself1);
  k_agg1f <<<12500, 256, 0, stream>>>(rs, csr, h1h, w1, wself1, b1, W2, as2, ad2, h2h, als2, ald2);

  // layer 2
  k_w2    <<<12500, 256, 0, stream>>>(rs, csr, als2, ald2, w2c, wself2);
  k_agg2f <<<12500, 256, 0, stream>>>(rs, csr, h2h, w2c, wself2, b2, clW1, hW);

  // task encoder + classifier
  k_task  <<<1, 256, 0, stream>>>(task, teW1, teb1, teW2, teb2, clW1, clb1, tWb);
  k_scores<<<12500, 256, 0, stream>>>(hW, tWb, clW2, clb2, out);
}

// Round 4
// 652.756 us; speedup vs baseline: 2.0680x; 1.0231x over previous
//
#include <hip/hip_runtime.h>
#include <hip/hip_fp16.h>

#define NN 50000
#define NE 800000
#define FN 128
#define HH 256      // HEADS*HID
#define HID 64

__device__ __forceinline__ float lrelu(float v){ return v >= 0.f ? v : 0.2f * v; }
__device__ __forceinline__ float elu_(float v){ return v > 0.f ? v : expm1f(v); }

__device__ __forceinline__ void unp4(const float2 r, float& f0, float& f1, float& f2, float& f3){
  const __half2* hp = (const __half2*)&r;
  float2 a = __half22float2(hp[0]);
  float2 b = __half22float2(hp[1]);
  f0 = a.x; f1 = a.y; f2 = b.x; f3 = b.y;
}

// ---------- CSR build ----------
__global__ void k_deg(const int* __restrict__ ei, int* __restrict__ deg){
  int e = blockIdx.x * 256 + threadIdx.x;
  if (e >= NE) return;
  atomicAdd(deg + ei[NE + e], 1);
}

__global__ void k_scan(const int* __restrict__ deg, int* __restrict__ rs, int* __restrict__ cur){
  __shared__ int part[256];
  int t = threadIdx.x;
  const int CH = 196;            // 256*196 = 50176 >= NN
  int base = t * CH;
  int s = 0;
  for (int i = 0; i < CH; ++i){ int idx = base + i; if (idx < NN) s += deg[idx]; }
  part[t] = s; __syncthreads();
  for (int off = 1; off < 256; off <<= 1){
    int v = (t >= off) ? part[t - off] : 0;
    __syncthreads();
    part[t] += v;
    __syncthreads();
  }
  int run = part[t] - s;         // exclusive prefix at chunk start
  for (int i = 0; i < CH; ++i){
    int idx = base + i;
    if (idx < NN){ rs[idx] = run; cur[idx] = run; run += deg[idx]; }
  }
  if (t == 255) rs[NN] = part[255];
}

__global__ void k_scatter(const int* __restrict__ ei, int* __restrict__ cur, int* __restrict__ csr){
  int e = blockIdx.x * 256 + threadIdx.x;
  if (e >= NE) return;
  int s = ei[e], d = ei[NE + e];
  int pos = atomicAdd(cur + d, 1);
  csr[pos] = s;
}

// ---------- h1 = x @ W1 (fp16 out, + fused alpha1) ----------
__global__ void k_gemm1(const float* __restrict__ x, const float* __restrict__ W,
                        const float* __restrict__ as1, const float* __restrict__ ad1,
                        __half* __restrict__ h1h, float* __restrict__ als, float* __restrict__ ald){
  __shared__ float xs[8][FN];
  int row0 = blockIdx.x * 8;
  int t = threadIdx.x;
  for (int i = t; i < 8 * FN; i += 256){
    int r = i >> 7, c = i & 127;
    xs[r][c] = x[(row0 + r) * FN + c];
  }
  __syncthreads();
  float acc[8] = {0.f,0.f,0.f,0.f,0.f,0.f,0.f,0.f};
  for (int k = 0; k < FN; ++k){
    float w = W[k * HH + t];
#pragma unroll
    for (int r = 0; r < 8; ++r) acc[r] = fmaf(xs[r][k], w, acc[r]);
  }
  float avs = as1[t], avd = ad1[t];
#pragma unroll
  for (int r = 0; r < 8; ++r){
    h1h[(row0 + r) * HH + t] = (__half)acc[r];
    float vs = acc[r] * avs, vd = acc[r] * avd;
#pragma unroll
    for (int off = 32; off > 0; off >>= 1){ vs += __shfl_down(vs, off); vd += __shfl_down(vd, off); }
    if ((t & 63) == 0){
      int head = t >> 6;
      als[(row0 + r) * 4 + head] = vs;
      ald[(row0 + r) * 4 + head] = vd;
    }
  }
}

// ---------- layer-1 normalized edge weights (wave per node) ----------
__global__ void k_w1(const int* __restrict__ rs, const int* __restrict__ csr,
                     const float* __restrict__ als, const float* __restrict__ ald,
                     float* __restrict__ w1, float* __restrict__ wself){
  int t = threadIdx.x, wv = t >> 6, lane = t & 63;
  int n = blockIdx.x * 4 + wv;
  int e0 = rs[n], e1 = rs[n + 1];
  float4 ad = *(const float4*)(ald + n * 4);
  float d0 = 0.f, d1 = 0.f, d2 = 0.f, d3 = 0.f;
  for (int e = e0 + lane; e < e1; e += 64){
    int s = csr[e];
    float4 a = *(const float4*)(als + s * 4);
    d0 += expf(lrelu(a.x + ad.x)); d1 += expf(lrelu(a.y + ad.y));
    d2 += expf(lrelu(a.z + ad.z)); d3 += expf(lrelu(a.w + ad.w));
  }
#pragma unroll
  for (int off = 32; off > 0; off >>= 1){
    d0 += __shfl_xor(d0, off); d1 += __shfl_xor(d1, off);
    d2 += __shfl_xor(d2, off); d3 += __shfl_xor(d3, off);
  }
  float4 as_ = *(const float4*)(als + n * 4);
  float s0 = expf(lrelu(as_.x + ad.x)), s1 = expf(lrelu(as_.y + ad.y));
  float s2 = expf(lrelu(as_.z + ad.z)), s3 = expf(lrelu(as_.w + ad.w));
  float i0 = 1.f / (d0 + s0 + 1e-16f), i1 = 1.f / (d1 + s1 + 1e-16f);
  float i2 = 1.f / (d2 + s2 + 1e-16f), i3 = 1.f / (d3 + s3 + 1e-16f);
  if (lane == 0){
    wself[n*4 + 0] = s0 * i0; wself[n*4 + 1] = s1 * i1;
    wself[n*4 + 2] = s2 * i2; wself[n*4 + 3] = s3 * i3;
  }
  for (int e = e0 + lane; e < e1; e += 64){
    int s = csr[e];
    float4 a = *(const float4*)(als + s * 4);
    float4 w;
    w.x = expf(lrelu(a.x + ad.x)) * i0; w.y = expf(lrelu(a.y + ad.y)) * i1;
    w.z = expf(lrelu(a.z + ad.z)) * i2; w.w = expf(lrelu(a.w + ad.w)) * i3;
    *(float4*)(w1 + e * 4) = w;
  }
}

// ---------- layer-1 gather: wave per node, lane = 4 channels ----------
__global__ void k_agg1g(const int* __restrict__ rs, const int* __restrict__ csr,
                        const __half* __restrict__ h1h, const float* __restrict__ w1,
                        const float* __restrict__ wself, const float* __restrict__ b1,
                        __half* __restrict__ g1h){
  int t = threadIdx.x, wv = t >> 6, lane = t & 63;
  int head = lane >> 4;
  int n = blockIdx.x * 4 + wv;
  float a0, a1, a2, a3;
  { // self-loop term
    float w = wself[n*4 + head];
    float2 r = *(const float2*)(h1h + (size_t)n * HH + lane * 4);
    float f0,f1,f2,f3; unp4(r, f0,f1,f2,f3);
    a0 = w*f0; a1 = w*f1; a2 = w*f2; a3 = w*f3;
  }
  int e0 = rs[n], e1 = rs[n + 1];
  int e = e0;
  for (; e + 3 < e1; e += 4){
    int s0 = csr[e], s1 = csr[e+1], s2 = csr[e+2], s3 = csr[e+3];
    float wa = w1[e*4 + head], wb = w1[(e+1)*4 + head];
    float wc = w1[(e+2)*4 + head], wd = w1[(e+3)*4 + head];
    float2 r0 = *(const float2*)(h1h + (size_t)s0 * HH + lane * 4);
    float2 r1 = *(const float2*)(h1h + (size_t)s1 * HH + lane * 4);
    float2 r2 = *(const float2*)(h1h + (size_t)s2 * HH + lane * 4);
    float2 r3 = *(const float2*)(h1h + (size_t)s3 * HH + lane * 4);
    float f0,f1,f2,f3;
    unp4(r0, f0,f1,f2,f3); a0=fmaf(wa,f0,a0); a1=fmaf(wa,f1,a1); a2=fmaf(wa,f2,a2); a3=fmaf(wa,f3,a3);
    unp4(r1, f0,f1,f2,f3); a0=fmaf(wb,f0,a0); a1=fmaf(wb,f1,a1); a2=fmaf(wb,f2,a2); a3=fmaf(wb,f3,a3);
    unp4(r2, f0,f1,f2,f3); a0=fmaf(wc,f0,a0); a1=fmaf(wc,f1,a1); a2=fmaf(wc,f2,a2); a3=fmaf(wc,f3,a3);
    unp4(r3, f0,f1,f2,f3); a0=fmaf(wd,f0,a0); a1=fmaf(wd,f1,a1); a2=fmaf(wd,f2,a2); a3=fmaf(wd,f3,a3);
  }
  for (; e < e1; ++e){
    int s = csr[e];
    float w = w1[e*4 + head];
    float2 r = *(const float2*)(h1h + (size_t)s * HH + lane * 4);
    float f0,f1,f2,f3; unp4(r, f0,f1,f2,f3);
    a0=fmaf(w,f0,a0); a1=fmaf(w,f1,a1); a2=fmaf(w,f2,a2); a3=fmaf(w,f3,a3);
  }
  float4 b4 = *(const float4*)(b1 + lane * 4);
  __half2 p0 = __floats2half2_rn(elu_(a0 + b4.x), elu_(a1 + b4.y));
  __half2 p1 = __floats2half2_rn(elu_(a2 + b4.z), elu_(a3 + b4.w));
  float2 outv; ((__half2*)&outv)[0] = p0; ((__half2*)&outv)[1] = p1;
  *(float2*)(g1h + (size_t)n * HH + lane * 4) = outv;
}

// ---------- h2 = g1 @ W2 (W2 fp16 in LDS, transposed+padded), fused alpha2 ----------
#define G2N 32
__global__ void k_gemm2t(const __half* __restrict__ g1h, const float* __restrict__ W2,
                         const float* __restrict__ as2, const float* __restrict__ ad2,
                         __half* __restrict__ h2h, float* __restrict__ als2, float* __restrict__ ald2){
  __shared__ __half w2t[64 * 258];   // [col][k], stride 258 halfs (516 B) -> conflict-free
  int t = threadIdx.x, wv = t >> 6, lane = t & 63;
  for (int idx = t; idx < 16384; idx += 256){
    int k = idx >> 6, col = idx & 63;
    w2t[col * 258 + k] = (__half)W2[idx];
  }
  __syncthreads();
  int n0 = blockIdx.x * G2N;
  float asv = as2[lane], adv = ad2[lane];
  const __half2* wrow = (const __half2*)(w2t + lane * 258);
  for (int j = 0; j < G2N / 4; ++j){
    int n = n0 + j * 4 + wv;
    if (n >= NN) continue;
    const __half2* grow = (const __half2*)(g1h + (size_t)n * HH);
    float acc = 0.f;
#pragma unroll 4
    for (int k2 = 0; k2 < 128; ++k2){
      float2 g = __half22float2(grow[k2]);
      float2 w = __half22float2(wrow[k2]);
      acc = fmaf(g.x, w.x, acc);
      acc = fmaf(g.y, w.y, acc);
    }
    h2h[(size_t)n * HID + lane] = (__half)acc;
    float vs = acc * asv, vd = acc * adv;
#pragma unroll
    for (int off = 32; off > 0; off >>= 1){ vs += __shfl_down(vs, off); vd += __shfl_down(vd, off); }
    if (lane == 0){ als2[n] = vs; ald2[n] = vd; }
  }
}

// ---------- layer-2 normalized edge weights (wave per node) ----------
__global__ void k_w2(const int* __restrict__ rs, const int* __restrict__ csr,
                     const float* __restrict__ als, const float* __restrict__ ald,
                     float* __restrict__ w2c, float* __restrict__ wself){
  int t = threadIdx.x, wv = t >> 6, lane = t & 63;
  int n = blockIdx.x * 4 + wv;
  int e0 = rs[n], e1 = rs[n + 1];
  float ad = ald[n];
  float den = 0.f;
  for (int e = e0 + lane; e < e1; e += 64) den += expf(lrelu(als[csr[e]] + ad));
#pragma unroll
  for (int off = 32; off > 0; off >>= 1) den += __shfl_xor(den, off);
  float sw = expf(lrelu(als[n] + ad));
  float inv = 1.f / (den + sw + 1e-16f);
  if (lane == 0) wself[n] = sw * inv;
  for (int e = e0 + lane; e < e1; e += 64) w2c[e] = expf(lrelu(als[csr[e]] + ad)) * inv;
}

// ---------- layer-2 gather (16-lane groups own a row) + ELU + hW ----------
__global__ void k_agg2f(const int* __restrict__ rs, const int* __restrict__ csr,
                        const __half* __restrict__ h2h, const float* __restrict__ w2c,
                        const float* __restrict__ wself, const float* __restrict__ b2,
                        const float* __restrict__ clW1, float* __restrict__ hW){
  __shared__ float os[4][64];
  int t = threadIdx.x, wv = t >> 6, lane = t & 63;
  int g16 = lane >> 4, c4 = lane & 15;
  int n = blockIdx.x * 4 + wv;
  int e0 = rs[n], e1 = rs[n + 1];
  float a0 = 0.f, a1 = 0.f, a2 = 0.f, a3 = 0.f;
  int e = e0 + g16;
  for (; e + 4 < e1; e += 8){
    int s0 = csr[e], s1 = csr[e + 4];
    float wa = w2c[e], wb = w2c[e + 4];
    float2 r0 = *(const float2*)(h2h + (size_t)s0 * HID + c4 * 4);
    float2 r1 = *(const float2*)(h2h + (size_t)s1 * HID + c4 * 4);
    float f0,f1,f2,f3;
    unp4(r0, f0,f1,f2,f3); a0=fmaf(wa,f0,a0); a1=fmaf(wa,f1,a1); a2=fmaf(wa,f2,a2); a3=fmaf(wa,f3,a3);
    unp4(r1, f0,f1,f2,f3); a0=fmaf(wb,f0,a0); a1=fmaf(wb,f1,a1); a2=fmaf(wb,f2,a2); a3=fmaf(wb,f3,a3);
  }
  if (e < e1){
    int s = csr[e];
    float w = w2c[e];
    float2 r = *(const float2*)(h2h + (size_t)s * HID + c4 * 4);
    float f0,f1,f2,f3; unp4(r, f0,f1,f2,f3);
    a0=fmaf(w,f0,a0); a1=fmaf(w,f1,a1); a2=fmaf(w,f2,a2); a3=fmaf(w,f3,a3);
  }
  // combine the 4 lane-groups
  a0 += __shfl_xor(a0, 16); a1 += __shfl_xor(a1, 16); a2 += __shfl_xor(a2, 16); a3 += __shfl_xor(a3, 16);
  a0 += __shfl_xor(a0, 32); a1 += __shfl_xor(a1, 32); a2 += __shfl_xor(a2, 32); a3 += __shfl_xor(a3, 32);
  if (lane < 16){
    float w = wself[n];
    float2 r = *(const float2*)(h2h + (size_t)n * HID + lane * 4);
    float f0,f1,f2,f3; unp4(r, f0,f1,f2,f3);
    a0 = fmaf(w, f0, a0); a1 = fmaf(w, f1, a1); a2 = fmaf(w, f2, a2); a3 = fmaf(w, f3, a3);
    float4 b4 = *(const float4*)(b2 + lane * 4);
    float4 o;
    o.x = elu_(a0 + b4.x); o.y = elu_(a1 + b4.y); o.z = elu_(a2 + b4.z); o.w = elu_(a3 + b4.w);
    *(float4*)(&os[wv][lane * 4]) = o;
  }
  __syncthreads();
  float acc = 0.f;
  const float* o = os[wv];
  for (int k = 0; k < HID; ++k) acc = fmaf(o[k], clW1[k * HID + lane], acc);
  hW[(size_t)n * HID + lane] = acc;
}

// ---------- task encoder + fold classifier bias ----------
__global__ void k_task(const float* __restrict__ task, const float* __restrict__ W1t,
                       const float* __restrict__ b1t, const float* __restrict__ W2t,
                       const float* __restrict__ b2t, const float* __restrict__ clW1,
                       const float* __restrict__ clb1, float* __restrict__ tWb){
  __shared__ float t1[16][64];
  __shared__ float t2[16][64];
  int t = threadIdx.x;
  for (int idx = t; idx < 1024; idx += 256){
    int b = idx >> 6, c = idx & 63;
    float acc = b1t[c];
    for (int k = 0; k < 128; ++k) acc = fmaf(task[b*128 + k], W1t[k*64 + c], acc);
    t1[b][c] = fmaxf(acc, 0.f);
  }
  __syncthreads();
  for (int idx = t; idx < 1024; idx += 256){
    int b = idx >> 6, c = idx & 63;
    float acc = b2t[c];
    for (int k = 0; k < 64; ++k) acc = fmaf(t1[b][k], W2t[k*64 + c], acc);
    t2[b][c] = acc;
  }
  __syncthreads();
  for (int idx = t; idx < 1024; idx += 256){
    int b = idx >> 6, c = idx & 63;
    float acc = clb1[c];
    for (int k = 0; k < 64; ++k) acc = fmaf(t2[b][k], clW1[(64 + k)*64 + c], acc);
    tWb[idx] = acc;
  }
}

// ---------- scores[b,n] = sum_k relu(hW[n,k] + tWb[b,k]) * w2[k] + cl_b2 ----------
__global__ void k_scores(const float* __restrict__ hW, const float* __restrict__ tWb,
                         const float* __restrict__ w2, const float* __restrict__ b2s,
                         float* __restrict__ out){
  __shared__ float tw[16][64];
  __shared__ float w2s[64];
  int t = threadIdx.x;
  for (int i = t; i < 1024; i += 256) tw[i >> 6][i & 63] = tWb[i];
  if (t < 64) w2s[t] = w2[t];
  __syncthreads();
  int wv = t >> 6, lane = t & 63;
  int n = blockIdx.x * 4 + wv;
  float hv = hW[n * 64 + lane];
  float bias = b2s[0];
  for (int b = 0; b < 16; ++b){
    float v = fmaxf(hv + tw[b][lane], 0.f) * w2s[lane];
#pragma unroll
    for (int off = 32; off > 0; off >>= 1) v += __shfl_xor(v, off);
    if (lane == b) out[b * NN + n] = v + bias;
  }
}

extern "C" void kernel_launch(void* const* d_in, const int* in_sizes, int n_in,
                              void* d_out, int out_size, void* d_ws, size_t ws_size,
                              hipStream_t stream){
  const float* x    = (const float*)d_in[0];
  const int*   ei   = (const int*)  d_in[1];
  const float* task = (const float*)d_in[2];
  const float* W1   = (const float*)d_in[3];
  const float* as1  = (const float*)d_in[4];
  const float* ad1  = (const float*)d_in[5];
  const float* b1   = (const float*)d_in[6];
  const float* W2   = (const float*)d_in[7];
  const float* as2  = (const float*)d_in[8];
  const float* ad2  = (const float*)d_in[9];
  const float* b2   = (const float*)d_in[10];
  const float* teW1 = (const float*)d_in[11];
  const float* teb1 = (const float*)d_in[12];
  const float* teW2 = (const float*)d_in[13];
  const float* teb2 = (const float*)d_in[14];
  const float* clW1 = (const float*)d_in[15];
  const float* clb1 = (const float*)d_in[16];
  const float* clW2 = (const float*)d_in[17];
  const float* clb2 = (const float*)d_in[18];
  float* out = (float*)d_out;
  float* ws  = (float*)d_ws;

  // workspace layout (float-sized slots)
  __half* h1h  = (__half*)ws;                 // 12.8M halfs -> 6.4M floats
  float* als1  = ws + 6400000;                // 200,000
  float* ald1  = als1 + 200000;               // 200,000
  float* w1    = ald1 + 200000;               // 3,200,000
  float* wself1= w1 + 3200000;                // 200,000
  __half* g1h  = (__half*)(wself1 + 200000);  // 12.8M halfs -> 6.4M floats
  __half* h2h  = (__half*)(wself1 + 200000 + 6400000); // 3.2M halfs -> 1.6M floats
  float* als2  = wself1 + 200000 + 6400000 + 1600000;  // 50,000
  float* ald2  = als2 + 50000;                // 50,000
  float* w2c   = ald2 + 50000;                // 800,000
  float* wself2= w2c + 800000;                // 50,000
  float* hW    = wself2 + 50000;              // 3,200,000
  float* tWb   = hW + 3200000;                // 1,024
  int*   deg   = (int*)(tWb + 1024);          // 50,000
  int*   rs    = deg + 50000;                 // 50,001 (+pad)
  int*   cur   = rs + 50004;                  // 50,000
  int*   csr   = cur + 50000;                 // 800,000

  // CSR build
  hipMemsetAsync(deg, 0, 50000 * sizeof(int), stream);
  k_deg    <<<(NE + 255)/256, 256, 0, stream>>>(ei, deg);
  k_scan   <<<1, 256, 0, stream>>>(deg, rs, cur);
  k_scatter<<<(NE + 255)/256, 256, 0, stream>>>(ei, cur, csr);

  // layer 1
  k_gemm1 <<<6250, 256, 0, stream>>>(x, W1, as1, ad1, h1h, als1, ald1);
  k_w1    <<<12500, 256, 0, stream>>>(rs, csr, als1, ald1, w1, wself1);
  k_agg1g <<<12500, 256, 0, stream>>>(rs, csr, h1h, w1, wself1, b1, g1h);
  k_gemm2t<<<(NN + G2N - 1)/G2N, 256, 0, stream>>>(g1h, W2, as2, ad2, h2h, als2, ald2);

  // layer 2
  k_w2    <<<12500, 256, 0, stream>>>(rs, csr, als2, ald2, w2c, wself2);
  k_agg2f <<<12500, 256, 0, stream>>>(rs, csr, h2h, w2c, wself2, b2, clW1, hW);

  // task encoder + classifier
  k_task  <<<1, 256, 0, stream>>>(task, teW1, teb1, teW2, teb2, clW1, clb1, tWb);
  k_scores<<<12500, 256, 0, stream>>>(hW, tWb, clW2, clb2, out);
}

// Round 5
// 519.761 us; speedup vs baseline: 2.5972x; 1.2559x over previous
//
#include <hip/hip_runtime.h>
#include <hip/hip_fp16.h>

#define NN 50000
#define NE 800000
#define FN 128
#define HH 256      // HEADS*HID
#define HID 64

__device__ __forceinline__ float lrelu(float v){ return v >= 0.f ? v : 0.2f * v; }
__device__ __forceinline__ float elu_(float v){ return v > 0.f ? v : expm1f(v); }

__device__ __forceinline__ void unp4(const float2 r, float& f0, float& f1, float& f2, float& f3){
  const __half2* hp = (const __half2*)&r;
  float2 a = __half22float2(hp[0]);
  float2 b = __half22float2(hp[1]);
  f0 = a.x; f1 = a.y; f2 = b.x; f3 = b.y;
}

// ---------- CSR build ----------
__global__ void k_deg(const int* __restrict__ ei, int* __restrict__ deg){
  int e = blockIdx.x * 256 + threadIdx.x;
  if (e >= NE) return;
  atomicAdd(deg + ei[NE + e], 1);
}

// phase A: per-chunk (256 nodes) sums
__global__ void k_psum(const int* __restrict__ deg, int* __restrict__ psum){
  int b = blockIdx.x, t = threadIdx.x;
  int idx = b * 256 + t;
  int v = (idx < NN) ? deg[idx] : 0;
#pragma unroll
  for (int off = 32; off > 0; off >>= 1) v += __shfl_down(v, off);
  __shared__ int wsum[4];
  if ((t & 63) == 0) wsum[t >> 6] = v;
  __syncthreads();
  if (t == 0) psum[b] = wsum[0] + wsum[1] + wsum[2] + wsum[3];
}

// phase B: exclusive scan of the 196 chunk sums (single tiny block)
__global__ void k_pscan(const int* __restrict__ psum, int* __restrict__ pofs){
  int t = threadIdx.x;            // 256 threads
  int lane = t & 63, wv = t >> 6;
  int v = (t < 196) ? psum[t] : 0;
  int iv = v;
#pragma unroll
  for (int off = 1; off < 64; off <<= 1){
    int u = __shfl_up(iv, off);
    if (lane >= off) iv += u;
  }
  __shared__ int wsum[4];
  if (lane == 63) wsum[wv] = iv;
  __syncthreads();
  int add = 0;
  for (int w = 0; w < wv; ++w) add += wsum[w];
  iv += add;
  if (t < 196) pofs[t] = iv - v;  // exclusive
}

// phase C: block-local exclusive scan + chunk offset -> rs, cur
__global__ void k_wroffs(const int* __restrict__ deg, const int* __restrict__ pofs,
                         int* __restrict__ rs, int* __restrict__ cur){
  int b = blockIdx.x, t = threadIdx.x;
  int idx = b * 256 + t;
  int lane = t & 63, wv = t >> 6;
  int v = (idx < NN) ? deg[idx] : 0;
  int iv = v;
#pragma unroll
  for (int off = 1; off < 64; off <<= 1){
    int u = __shfl_up(iv, off);
    if (lane >= off) iv += u;
  }
  __shared__ int wsum[4];
  if (lane == 63) wsum[wv] = iv;
  __syncthreads();
  int add = pofs[b];
  for (int w = 0; w < wv; ++w) add += wsum[w];
  int excl = add + iv - v;
  if (idx < NN){ rs[idx] = excl; cur[idx] = excl; }
  if (idx == NN) rs[NN] = excl;   // v==0 here -> excl == total edges
}

__global__ void k_scatter(const int* __restrict__ ei, int* __restrict__ cur, int* __restrict__ csr){
  int e = blockIdx.x * 256 + threadIdx.x;
  if (e >= NE) return;
  int s = ei[e], d = ei[NE + e];
  int pos = atomicAdd(cur + d, 1);
  csr[pos] = s;
}

// ---------- h1 = x @ W1 (fp16 out, + fused alpha1) ----------
__global__ void k_gemm1(const float* __restrict__ x, const float* __restrict__ W,
                        const float* __restrict__ as1, const float* __restrict__ ad1,
                        __half* __restrict__ h1h, float* __restrict__ als, float* __restrict__ ald){
  __shared__ float xs[8][FN];
  int row0 = blockIdx.x * 8;
  int t = threadIdx.x;
  for (int i = t; i < 8 * FN; i += 256){
    int r = i >> 7, c = i & 127;
    xs[r][c] = x[(row0 + r) * FN + c];
  }
  __syncthreads();
  float acc[8] = {0.f,0.f,0.f,0.f,0.f,0.f,0.f,0.f};
  for (int k = 0; k < FN; ++k){
    float w = W[k * HH + t];
#pragma unroll
    for (int r = 0; r < 8; ++r) acc[r] = fmaf(xs[r][k], w, acc[r]);
  }
  float avs = as1[t], avd = ad1[t];
#pragma unroll
  for (int r = 0; r < 8; ++r){
    h1h[(row0 + r) * HH + t] = (__half)acc[r];
    float vs = acc[r] * avs, vd = acc[r] * avd;
#pragma unroll
    for (int off = 32; off > 0; off >>= 1){ vs += __shfl_down(vs, off); vd += __shfl_down(vd, off); }
    if ((t & 63) == 0){
      int head = t >> 6;
      als[(row0 + r) * 4 + head] = vs;
      ald[(row0 + r) * 4 + head] = vd;
    }
  }
}

// ---------- layer-1 normalized edge weights (wave per node) ----------
__global__ void k_w1(const int* __restrict__ rs, const int* __restrict__ csr,
                     const float* __restrict__ als, const float* __restrict__ ald,
                     float* __restrict__ w1, float* __restrict__ wself){
  int t = threadIdx.x, wv = t >> 6, lane = t & 63;
  int n = blockIdx.x * 4 + wv;
  int e0 = rs[n], e1 = rs[n + 1];
  float4 ad = *(const float4*)(ald + n * 4);
  float d0 = 0.f, d1 = 0.f, d2 = 0.f, d3 = 0.f;
  for (int e = e0 + lane; e < e1; e += 64){
    int s = csr[e];
    float4 a = *(const float4*)(als + s * 4);
    float4 w;
    w.x = expf(lrelu(a.x + ad.x)); w.y = expf(lrelu(a.y + ad.y));
    w.z = expf(lrelu(a.z + ad.z)); w.w = expf(lrelu(a.w + ad.w));
    *(float4*)(w1 + e * 4) = w;           // unnormalized
    d0 += w.x; d1 += w.y; d2 += w.z; d3 += w.w;
  }
#pragma unroll
  for (int off = 32; off > 0; off >>= 1){
    d0 += __shfl_xor(d0, off); d1 += __shfl_xor(d1, off);
    d2 += __shfl_xor(d2, off); d3 += __shfl_xor(d3, off);
  }
  float4 as_ = *(const float4*)(als + n * 4);
  float s0 = expf(lrelu(as_.x + ad.x)), s1 = expf(lrelu(as_.y + ad.y));
  float s2 = expf(lrelu(as_.z + ad.z)), s3 = expf(lrelu(as_.w + ad.w));
  float i0 = 1.f / (d0 + s0 + 1e-16f), i1 = 1.f / (d1 + s1 + 1e-16f);
  float i2 = 1.f / (d2 + s2 + 1e-16f), i3 = 1.f / (d3 + s3 + 1e-16f);
  if (lane == 0){
    wself[n*4 + 0] = s0 * i0; wself[n*4 + 1] = s1 * i1;
    wself[n*4 + 2] = s2 * i2; wself[n*4 + 3] = s3 * i3;
  }
  for (int e = e0 + lane; e < e1; e += 64){
    float4 w = *(const float4*)(w1 + e * 4);
    w.x *= i0; w.y *= i1; w.z *= i2; w.w *= i3;
    *(float4*)(w1 + e * 4) = w;
  }
}

// ---------- layer-1 gather: wave per node, lane = 4 channels ----------
__global__ void k_agg1g(const int* __restrict__ rs, const int* __restrict__ csr,
                        const __half* __restrict__ h1h, const float* __restrict__ w1,
                        const float* __restrict__ wself, const float* __restrict__ b1,
                        __half* __restrict__ g1h){
  int t = threadIdx.x, wv = t >> 6, lane = t & 63;
  int head = lane >> 4;
  int n = blockIdx.x * 4 + wv;
  float a0, a1, a2, a3;
  { // self-loop term
    float w = wself[n*4 + head];
    float2 r = *(const float2*)(h1h + (size_t)n * HH + lane * 4);
    float f0,f1,f2,f3; unp4(r, f0,f1,f2,f3);
    a0 = w*f0; a1 = w*f1; a2 = w*f2; a3 = w*f3;
  }
  int e0 = rs[n], e1 = rs[n + 1];
  int e = e0;
  for (; e + 3 < e1; e += 4){
    int s0 = csr[e], s1 = csr[e+1], s2 = csr[e+2], s3 = csr[e+3];
    float wa = w1[e*4 + head], wb = w1[(e+1)*4 + head];
    float wc = w1[(e+2)*4 + head], wd = w1[(e+3)*4 + head];
    float2 r0 = *(const float2*)(h1h + (size_t)s0 * HH + lane * 4);
    float2 r1 = *(const float2*)(h1h + (size_t)s1 * HH + lane * 4);
    float2 r2 = *(const float2*)(h1h + (size_t)s2 * HH + lane * 4);
    float2 r3 = *(const float2*)(h1h + (size_t)s3 * HH + lane * 4);
    float f0,f1,f2,f3;
    unp4(r0, f0,f1,f2,f3); a0=fmaf(wa,f0,a0); a1=fmaf(wa,f1,a1); a2=fmaf(wa,f2,a2); a3=fmaf(wa,f3,a3);
    unp4(r1, f0,f1,f2,f3); a0=fmaf(wb,f0,a0); a1=fmaf(wb,f1,a1); a2=fmaf(wb,f2,a2); a3=fmaf(wb,f3,a3);
    unp4(r2, f0,f1,f2,f3); a0=fmaf(wc,f0,a0); a1=fmaf(wc,f1,a1); a2=fmaf(wc,f2,a2); a3=fmaf(wc,f3,a3);
    unp4(r3, f0,f1,f2,f3); a0=fmaf(wd,f0,a0); a1=fmaf(wd,f1,a1); a2=fmaf(wd,f2,a2); a3=fmaf(wd,f3,a3);
  }
  for (; e < e1; ++e){
    int s = csr[e];
    float w = w1[e*4 + head];
    float2 r = *(const float2*)(h1h + (size_t)s * HH + lane * 4);
    float f0,f1,f2,f3; unp4(r, f0,f1,f2,f3);
    a0=fmaf(w,f0,a0); a1=fmaf(w,f1,a1); a2=fmaf(w,f2,a2); a3=fmaf(w,f3,a3);
  }
  float4 b4 = *(const float4*)(b1 + lane * 4);
  __half2 p0 = __floats2half2_rn(elu_(a0 + b4.x), elu_(a1 + b4.y));
  __half2 p1 = __floats2half2_rn(elu_(a2 + b4.z), elu_(a3 + b4.w));
  float2 outv; ((__half2*)&outv)[0] = p0; ((__half2*)&outv)[1] = p1;
  *(float2*)(g1h + (size_t)n * HH + lane * 4) = outv;
}

// ---------- h2 = g1 @ W2 (W2 fp16 in LDS, transposed+padded), fused alpha2 ----------
#define G2N 32
__global__ void k_gemm2t(const __half* __restrict__ g1h, const float* __restrict__ W2,
                         const float* __restrict__ as2, const float* __restrict__ ad2,
                         __half* __restrict__ h2h, float* __restrict__ als2, float* __restrict__ ald2){
  __shared__ __half w2t[64 * 258];   // [col][k], stride 258 halfs (516 B) -> conflict-free
  int t = threadIdx.x, wv = t >> 6, lane = t & 63;
  for (int idx = t; idx < 16384; idx += 256){
    int k = idx >> 6, col = idx & 63;
    w2t[col * 258 + k] = (__half)W2[idx];
  }
  __syncthreads();
  int n0 = blockIdx.x * G2N;
  float asv = as2[lane], adv = ad2[lane];
  const __half2* wrow = (const __half2*)(w2t + lane * 258);
  for (int j = 0; j < G2N / 4; ++j){
    int n = n0 + j * 4 + wv;
    if (n >= NN) continue;
    const __half2* grow = (const __half2*)(g1h + (size_t)n * HH);
    float acc = 0.f;
#pragma unroll 4
    for (int k2 = 0; k2 < 128; ++k2){
      float2 g = __half22float2(grow[k2]);
      float2 w = __half22float2(wrow[k2]);
      acc = fmaf(g.x, w.x, acc);
      acc = fmaf(g.y, w.y, acc);
    }
    h2h[(size_t)n * HID + lane] = (__half)acc;
    float vs = acc * asv, vd = acc * adv;
#pragma unroll
    for (int off = 32; off > 0; off >>= 1){ vs += __shfl_down(vs, off); vd += __shfl_down(vd, off); }
    if (lane == 0){ als2[n] = vs; ald2[n] = vd; }
  }
}

// ---------- layer-2 normalized edge weights (wave per node) ----------
__global__ void k_w2(const int* __restrict__ rs, const int* __restrict__ csr,
                     const float* __restrict__ als, const float* __restrict__ ald,
                     float* __restrict__ w2c, float* __restrict__ wself){
  int t = threadIdx.x, wv = t >> 6, lane = t & 63;
  int n = blockIdx.x * 4 + wv;
  int e0 = rs[n], e1 = rs[n + 1];
  float ad = ald[n];
  float den = 0.f;
  for (int e = e0 + lane; e < e1; e += 64){
    float w = expf(lrelu(als[csr[e]] + ad));
    w2c[e] = w;                          // unnormalized
    den += w;
  }
#pragma unroll
  for (int off = 32; off > 0; off >>= 1) den += __shfl_xor(den, off);
  float sw = expf(lrelu(als[n] + ad));
  float inv = 1.f / (den + sw + 1e-16f);
  if (lane == 0) wself[n] = sw * inv;
  for (int e = e0 + lane; e < e1; e += 64) w2c[e] *= inv;
}

// ---------- layer-2 gather (16-lane groups own a row) + ELU + hW ----------
__global__ void k_agg2f(const int* __restrict__ rs, const int* __restrict__ csr,
                        const __half* __restrict__ h2h, const float* __restrict__ w2c,
                        const float* __restrict__ wself, const float* __restrict__ b2,
                        const float* __restrict__ clW1, float* __restrict__ hW){
  __shared__ float os[4][64];
  int t = threadIdx.x, wv = t >> 6, lane = t & 63;
  int g16 = lane >> 4, c4 = lane & 15;
  int n = blockIdx.x * 4 + wv;
  int e0 = rs[n], e1 = rs[n + 1];
  float a0 = 0.f, a1 = 0.f, a2 = 0.f, a3 = 0.f;
  int e = e0 + g16;
  for (; e + 4 < e1; e += 8){
    int s0 = csr[e], s1 = csr[e + 4];
    float wa = w2c[e], wb = w2c[e + 4];
    float2 r0 = *(const float2*)(h2h + (size_t)s0 * HID + c4 * 4);
    float2 r1 = *(const float2*)(h2h + (size_t)s1 * HID + c4 * 4);
    float f0,f1,f2,f3;
    unp4(r0, f0,f1,f2,f3); a0=fmaf(wa,f0,a0); a1=fmaf(wa,f1,a1); a2=fmaf(wa,f2,a2); a3=fmaf(wa,f3,a3);
    unp4(r1, f0,f1,f2,f3); a0=fmaf(wb,f0,a0); a1=fmaf(wb,f1,a1); a2=fmaf(wb,f2,a2); a3=fmaf(wb,f3,a3);
  }
  if (e < e1){
    int s = csr[e];
    float w = w2c[e];
    float2 r = *(const float2*)(h2h + (size_t)s * HID + c4 * 4);
    float f0,f1,f2,f3; unp4(r, f0,f1,f2,f3);
    a0=fmaf(w,f0,a0); a1=fmaf(w,f1,a1); a2=fmaf(w,f2,a2); a3=fmaf(w,f3,a3);
  }
  // combine the 4 lane-groups
  a0 += __shfl_xor(a0, 16); a1 += __shfl_xor(a1, 16); a2 += __shfl_xor(a2, 16); a3 += __shfl_xor(a3, 16);
  a0 += __shfl_xor(a0, 32); a1 += __shfl_xor(a1, 32); a2 += __shfl_xor(a2, 32); a3 += __shfl_xor(a3, 32);
  if (lane < 16){
    float w = wself[n];
    float2 r = *(const float2*)(h2h + (size_t)n * HID + lane * 4);
    float f0,f1,f2,f3; unp4(r, f0,f1,f2,f3);
    a0 = fmaf(w, f0, a0); a1 = fmaf(w, f1, a1); a2 = fmaf(w, f2, a2); a3 = fmaf(w, f3, a3);
    float4 b4 = *(const float4*)(b2 + lane * 4);
    float4 o;
    o.x = elu_(a0 + b4.x); o.y = elu_(a1 + b4.y); o.z = elu_(a2 + b4.z); o.w = elu_(a3 + b4.w);
    *(float4*)(&os[wv][lane * 4]) = o;
  }
  __syncthreads();
  float acc = 0.f;
  const float* o = os[wv];
  for (int k = 0; k < HID; ++k) acc = fmaf(o[k], clW1[k * HID + lane], acc);
  hW[(size_t)n * HID + lane] = acc;
}

// ---------- task encoder + fold classifier bias ----------
__global__ void k_task(const float* __restrict__ task, const float* __restrict__ W1t,
                       const float* __restrict__ b1t, const float* __restrict__ W2t,
                       const float* __restrict__ b2t, const float* __restrict__ clW1,
                       const float* __restrict__ clb1, float* __restrict__ tWb){
  __shared__ float t1[16][64];
  __shared__ float t2[16][64];
  int t = threadIdx.x;
  for (int idx = t; idx < 1024; idx += 256){
    int b = idx >> 6, c = idx & 63;
    float acc = b1t[c];
    for (int k = 0; k < 128; ++k) acc = fmaf(task[b*128 + k], W1t[k*64 + c], acc);
    t1[b][c] = fmaxf(acc, 0.f);
  }
  __syncthreads();
  for (int idx = t; idx < 1024; idx += 256){
    int b = idx >> 6, c = idx & 63;
    float acc = b2t[c];
    for (int k = 0; k < 64; ++k) acc = fmaf(t1[b][k], W2t[k*64 + c], acc);
    t2[b][c] = acc;
  }
  __syncthreads();
  for (int idx = t; idx < 1024; idx += 256){
    int b = idx >> 6, c = idx & 63;
    float acc = clb1[c];
    for (int k = 0; k < 64; ++k) acc = fmaf(t2[b][k], clW1[(64 + k)*64 + c], acc);
    tWb[idx] = acc;
  }
}

// ---------- scores[b,n] = sum_k relu(hW[n,k] + tWb[b,k]) * w2[k] + cl_b2 ----------
__global__ void k_scores(const float* __restrict__ hW, const float* __restrict__ tWb,
                         const float* __restrict__ w2, const float* __restrict__ b2s,
                         float* __restrict__ out){
  __shared__ float tw[16][64];
  __shared__ float w2s[64];
  int t = threadIdx.x;
  for (int i = t; i < 1024; i += 256) tw[i >> 6][i & 63] = tWb[i];
  if (t < 64) w2s[t] = w2[t];
  __syncthreads();
  int wv = t >> 6, lane = t & 63;
  int n = blockIdx.x * 4 + wv;
  float hv = hW[n * 64 + lane];
  float bias = b2s[0];
  for (int b = 0; b < 16; ++b){
    float v = fmaxf(hv + tw[b][lane], 0.f) * w2s[lane];
#pragma unroll
    for (int off = 32; off > 0; off >>= 1) v += __shfl_xor(v, off);
    if (lane == b) out[b * NN + n] = v + bias;
  }
}

extern "C" void kernel_launch(void* const* d_in, const int* in_sizes, int n_in,
                              void* d_out, int out_size, void* d_ws, size_t ws_size,
                              hipStream_t stream){
  const float* x    = (const float*)d_in[0];
  const int*   ei   = (const int*)  d_in[1];
  const float* task = (const float*)d_in[2];
  const float* W1   = (const float*)d_in[3];
  const float* as1  = (const float*)d_in[4];
  const float* ad1  = (const float*)d_in[5];
  const float* b1   = (const float*)d_in[6];
  const float* W2   = (const float*)d_in[7];
  const float* as2  = (const float*)d_in[8];
  const float* ad2  = (const float*)d_in[9];
  const float* b2   = (const float*)d_in[10];
  const float* teW1 = (const float*)d_in[11];
  const float* teb1 = (const float*)d_in[12];
  const float* teW2 = (const float*)d_in[13];
  const float* teb2 = (const float*)d_in[14];
  const float* clW1 = (const float*)d_in[15];
  const float* clb1 = (const float*)d_in[16];
  const float* clW2 = (const float*)d_in[17];
  const float* clb2 = (const float*)d_in[18];
  float* out = (float*)d_out;
  float* ws  = (float*)d_ws;

  // workspace layout (float-sized slots)
  __half* h1h  = (__half*)ws;                 // 12.8M halfs -> 6.4M floats
  float* als1  = ws + 6400000;                // 200,000
  float* ald1  = als1 + 200000;               // 200,000
  float* w1    = ald1 + 200000;               // 3,200,000
  float* wself1= w1 + 3200000;                // 200,000
  __half* g1h  = (__half*)(wself1 + 200000);  // 12.8M halfs -> 6.4M floats
  __half* h2h  = (__half*)(wself1 + 200000 + 6400000); // 3.2M halfs -> 1.6M floats
  float* als2  = wself1 + 200000 + 6400000 + 1600000;  // 50,000
  float* ald2  = als2 + 50000;                // 50,000
  float* w2c   = ald2 + 50000;                // 800,000
  float* wself2= w2c + 800000;                // 50,000
  float* hW    = wself2 + 50000;              // 3,200,000
  float* tWb   = hW + 3200000;                // 1,024
  int*   deg   = (int*)(tWb + 1024);          // 50,000
  int*   rs    = deg + 50000;                 // 50,001 (+pad)
  int*   cur   = rs + 50004;                  // 50,000
  int*   csr   = cur + 50000;                 // 800,000
  int*   psum  = csr + 800000;                // 256
  int*   pofs  = psum + 256;                  // 256

  // CSR build (parallel scan)
  hipMemsetAsync(deg, 0, 50000 * sizeof(int), stream);
  k_deg    <<<(NE + 255)/256, 256, 0, stream>>>(ei, deg);
  k_psum   <<<196, 256, 0, stream>>>(deg, psum);
  k_pscan  <<<1, 256, 0, stream>>>(psum, pofs);
  k_wroffs <<<196, 256, 0, stream>>>(deg, pofs, rs, cur);
  k_scatter<<<(NE + 255)/256, 256, 0, stream>>>(ei, cur, csr);

  // layer 1
  k_gemm1 <<<6250, 256, 0, stream>>>(x, W1, as1, ad1, h1h, als1, ald1);
  k_w1    <<<12500, 256, 0, stream>>>(rs, csr, als1, ald1, w1, wself1);
  k_agg1g <<<12500, 256, 0, stream>>>(rs, csr, h1h, w1, wself1, b1, g1h);
  k_gemm2t<<<(NN + G2N - 1)/G2N, 256, 0, stream>>>(g1h, W2, as2, ad2, h2h, als2, ald2);

  // layer 2
  k_w2    <<<12500, 256, 0, stream>>>(rs, csr, als2, ald2, w2c, wself2);
  k_agg2f <<<12500, 256, 0, stream>>>(rs, csr, h2h, w2c, wself2, b2, clW1, hW);

  // task encoder + classifier
  k_task  <<<1, 256, 0, stream>>>(task, teW1, teb1, teW2, teb2, clW1, clb1, tWb);
  k_scores<<<12500, 256, 0, stream>>>(hW, tWb, clW2, clb2, out);
}

// Round 6
// 421.950 us; speedup vs baseline: 3.1992x; 1.2318x over previous
//
#include <hip/hip_runtime.h>
#include <hip/hip_fp16.h>

#define NN 50000
#define NE 800000
#define FN 128
#define HH 256      // HEADS*HID
#define HID 64

typedef _Float16 f16x8 __attribute__((ext_vector_type(8)));
typedef float f32x4 __attribute__((ext_vector_type(4)));

__device__ __forceinline__ float lrelu(float v){ return v >= 0.f ? v : 0.2f * v; }
__device__ __forceinline__ float elu_(float v){ return v > 0.f ? v : expm1f(v); }

__device__ __forceinline__ void unp4(const float2 r, float& f0, float& f1, float& f2, float& f3){
  const __half2* hp = (const __half2*)&r;
  float2 a = __half22float2(hp[0]);
  float2 b = __half22float2(hp[1]);
  f0 = a.x; f1 = a.y; f2 = b.x; f3 = b.y;
}

// ---------- CSR build ----------
__global__ void k_deg(const int* __restrict__ ei, int* __restrict__ deg){
  int e = blockIdx.x * 256 + threadIdx.x;
  if (e >= NE) return;
  atomicAdd(deg + ei[NE + e], 1);
}

__global__ void k_psum(const int* __restrict__ deg, int* __restrict__ psum){
  int b = blockIdx.x, t = threadIdx.x;
  int idx = b * 256 + t;
  int v = (idx < NN) ? deg[idx] : 0;
#pragma unroll
  for (int off = 32; off > 0; off >>= 1) v += __shfl_down(v, off);
  __shared__ int wsum[4];
  if ((t & 63) == 0) wsum[t >> 6] = v;
  __syncthreads();
  if (t == 0) psum[b] = wsum[0] + wsum[1] + wsum[2] + wsum[3];
}

__global__ void k_pscan(const int* __restrict__ psum, int* __restrict__ pofs){
  int t = threadIdx.x;            // 256 threads
  int lane = t & 63, wv = t >> 6;
  int v = (t < 196) ? psum[t] : 0;
  int iv = v;
#pragma unroll
  for (int off = 1; off < 64; off <<= 1){
    int u = __shfl_up(iv, off);
    if (lane >= off) iv += u;
  }
  __shared__ int wsum[4];
  if (lane == 63) wsum[wv] = iv;
  __syncthreads();
  int add = 0;
  for (int w = 0; w < wv; ++w) add += wsum[w];
  iv += add;
  if (t < 196) pofs[t] = iv - v;  // exclusive
}

__global__ void k_wroffs(const int* __restrict__ deg, const int* __restrict__ pofs,
                         int* __restrict__ rs, int* __restrict__ cur){
  int b = blockIdx.x, t = threadIdx.x;
  int idx = b * 256 + t;
  int lane = t & 63, wv = t >> 6;
  int v = (idx < NN) ? deg[idx] : 0;
  int iv = v;
#pragma unroll
  for (int off = 1; off < 64; off <<= 1){
    int u = __shfl_up(iv, off);
    if (lane >= off) iv += u;
  }
  __shared__ int wsum[4];
  if (lane == 63) wsum[wv] = iv;
  __syncthreads();
  int add = pofs[b];
  for (int w = 0; w < wv; ++w) add += wsum[w];
  int excl = add + iv - v;
  if (idx < NN){ rs[idx] = excl; cur[idx] = excl; }
  if (idx == NN) rs[NN] = excl;
}

__global__ void k_scatter(const int* __restrict__ ei, int* __restrict__ cur, int* __restrict__ csr){
  int e = blockIdx.x * 256 + threadIdx.x;
  if (e >= NE) return;
  int s = ei[e], d = ei[NE + e];
  int pos = atomicAdd(cur + d, 1);
  csr[pos] = s;
}

// ---------- h1 = x @ W1 (fp16 out, + fused alpha1) ----------
__global__ void k_gemm1(const float* __restrict__ x, const float* __restrict__ W,
                        const float* __restrict__ as1, const float* __restrict__ ad1,
                        __half* __restrict__ h1h, float* __restrict__ als, float* __restrict__ ald){
  __shared__ float xs[8][FN];
  int row0 = blockIdx.x * 8;
  int t = threadIdx.x;
  for (int i = t; i < 8 * FN; i += 256){
    int r = i >> 7, c = i & 127;
    xs[r][c] = x[(row0 + r) * FN + c];
  }
  __syncthreads();
  float acc[8] = {0.f,0.f,0.f,0.f,0.f,0.f,0.f,0.f};
  for (int k = 0; k < FN; ++k){
    float w = W[k * HH + t];
#pragma unroll
    for (int r = 0; r < 8; ++r) acc[r] = fmaf(xs[r][k], w, acc[r]);
  }
  float avs = as1[t], avd = ad1[t];
#pragma unroll
  for (int r = 0; r < 8; ++r){
    h1h[(row0 + r) * HH + t] = (__half)acc[r];
    float vs = acc[r] * avs, vd = acc[r] * avd;
#pragma unroll
    for (int off = 32; off > 0; off >>= 1){ vs += __shfl_down(vs, off); vd += __shfl_down(vd, off); }
    if ((t & 63) == 0){
      int head = t >> 6;
      als[(row0 + r) * 4 + head] = vs;
      ald[(row0 + r) * 4 + head] = vd;
    }
  }
}

// ---------- layer-1 normalized edge weights (wave per node) ----------
__global__ void k_w1(const int* __restrict__ rs, const int* __restrict__ csr,
                     const float* __restrict__ als, const float* __restrict__ ald,
                     float* __restrict__ w1, float* __restrict__ wself){
  int t = threadIdx.x, wv = t >> 6, lane = t & 63;
  int n = blockIdx.x * 4 + wv;
  int e0 = rs[n], e1 = rs[n + 1];
  float4 ad = *(const float4*)(ald + n * 4);
  float d0 = 0.f, d1 = 0.f, d2 = 0.f, d3 = 0.f;
  for (int e = e0 + lane; e < e1; e += 64){
    int s = csr[e];
    float4 a = *(const float4*)(als + s * 4);
    float4 w;
    w.x = expf(lrelu(a.x + ad.x)); w.y = expf(lrelu(a.y + ad.y));
    w.z = expf(lrelu(a.z + ad.z)); w.w = expf(lrelu(a.w + ad.w));
    *(float4*)(w1 + e * 4) = w;           // unnormalized
    d0 += w.x; d1 += w.y; d2 += w.z; d3 += w.w;
  }
#pragma unroll
  for (int off = 32; off > 0; off >>= 1){
    d0 += __shfl_xor(d0, off); d1 += __shfl_xor(d1, off);
    d2 += __shfl_xor(d2, off); d3 += __shfl_xor(d3, off);
  }
  float4 as_ = *(const float4*)(als + n * 4);
  float s0 = expf(lrelu(as_.x + ad.x)), s1 = expf(lrelu(as_.y + ad.y));
  float s2 = expf(lrelu(as_.z + ad.z)), s3 = expf(lrelu(as_.w + ad.w));
  float i0 = 1.f / (d0 + s0 + 1e-16f), i1 = 1.f / (d1 + s1 + 1e-16f);
  float i2 = 1.f / (d2 + s2 + 1e-16f), i3 = 1.f / (d3 + s3 + 1e-16f);
  if (lane == 0){
    wself[n*4 + 0] = s0 * i0; wself[n*4 + 1] = s1 * i1;
    wself[n*4 + 2] = s2 * i2; wself[n*4 + 3] = s3 * i3;
  }
  for (int e = e0 + lane; e < e1; e += 64){
    float4 w = *(const float4*)(w1 + e * 4);
    w.x *= i0; w.y *= i1; w.z *= i2; w.w *= i3;
    *(float4*)(w1 + e * 4) = w;
  }
}

// ---------- layer-1 gather: wave per node, lane = 4 channels ----------
__global__ void k_agg1g(const int* __restrict__ rs, const int* __restrict__ csr,
                        const __half* __restrict__ h1h, const float* __restrict__ w1,
                        const float* __restrict__ wself, const float* __restrict__ b1,
                        __half* __restrict__ g1h){
  int t = threadIdx.x, wv = t >> 6, lane = t & 63;
  int head = lane >> 4;
  int n = blockIdx.x * 4 + wv;
  float a0, a1, a2, a3;
  { // self-loop term
    float w = wself[n*4 + head];
    float2 r = *(const float2*)(h1h + (size_t)n * HH + lane * 4);
    float f0,f1,f2,f3; unp4(r, f0,f1,f2,f3);
    a0 = w*f0; a1 = w*f1; a2 = w*f2; a3 = w*f3;
  }
  int e0 = rs[n], e1 = rs[n + 1];
  int e = e0;
  for (; e + 3 < e1; e += 4){
    int s0 = csr[e], s1 = csr[e+1], s2 = csr[e+2], s3 = csr[e+3];
    float wa = w1[e*4 + head], wb = w1[(e+1)*4 + head];
    float wc = w1[(e+2)*4 + head], wd = w1[(e+3)*4 + head];
    float2 r0 = *(const float2*)(h1h + (size_t)s0 * HH + lane * 4);
    float2 r1 = *(const float2*)(h1h + (size_t)s1 * HH + lane * 4);
    float2 r2 = *(const float2*)(h1h + (size_t)s2 * HH + lane * 4);
    float2 r3 = *(const float2*)(h1h + (size_t)s3 * HH + lane * 4);
    float f0,f1,f2,f3;
    unp4(r0, f0,f1,f2,f3); a0=fmaf(wa,f0,a0); a1=fmaf(wa,f1,a1); a2=fmaf(wa,f2,a2); a3=fmaf(wa,f3,a3);
    unp4(r1, f0,f1,f2,f3); a0=fmaf(wb,f0,a0); a1=fmaf(wb,f1,a1); a2=fmaf(wb,f2,a2); a3=fmaf(wb,f3,a3);
    unp4(r2, f0,f1,f2,f3); a0=fmaf(wc,f0,a0); a1=fmaf(wc,f1,a1); a2=fmaf(wc,f2,a2); a3=fmaf(wc,f3,a3);
    unp4(r3, f0,f1,f2,f3); a0=fmaf(wd,f0,a0); a1=fmaf(wd,f1,a1); a2=fmaf(wd,f2,a2); a3=fmaf(wd,f3,a3);
  }
  for (; e < e1; ++e){
    int s = csr[e];
    float w = w1[e*4 + head];
    float2 r = *(const float2*)(h1h + (size_t)s * HH + lane * 4);
    float f0,f1,f2,f3; unp4(r, f0,f1,f2,f3);
    a0=fmaf(w,f0,a0); a1=fmaf(w,f1,a1); a2=fmaf(w,f2,a2); a3=fmaf(w,f3,a3);
  }
  float4 b4 = *(const float4*)(b1 + lane * 4);
  __half2 p0 = __floats2half2_rn(elu_(a0 + b4.x), elu_(a1 + b4.y));
  __half2 p1 = __floats2half2_rn(elu_(a2 + b4.z), elu_(a3 + b4.w));
  float2 outv; ((__half2*)&outv)[0] = p0; ((__half2*)&outv)[1] = p1;
  *(float2*)(g1h + (size_t)n * HH + lane * 4) = outv;
}

// ---------- W2 -> MFMA fragment-ordered fp16 ----------
// Bp[((kt*4+ct)*64 + lane)*8 + i] = W2[kt*32 + (lane>>4)*8 + i][ct*16 + (lane&15)]
__global__ void k_w2prep(const float* __restrict__ W2, __half* __restrict__ Bp){
  int t = threadIdx.x;
  for (int f = t; f < 2048; f += 256){
    int kt = f >> 8, ct = (f >> 6) & 3, lane = f & 63;
    int kbase = kt * 32 + (lane >> 4) * 8;
    int col = ct * 16 + (lane & 15);
#pragma unroll
    for (int i = 0; i < 8; ++i)
      Bp[(size_t)f * 8 + i] = (__half)W2[(kbase + i) * HID + col];
  }
}

// ---------- h2 = g1 @ W2 via MFMA 16x16x32_f16, fused alpha2 ----------
__global__ void k_gemm2m(const __half* __restrict__ g1h, const __half* __restrict__ Bp,
                         const float* __restrict__ as2, const float* __restrict__ ad2,
                         __half* __restrict__ h2h, float* __restrict__ als2, float* __restrict__ ald2){
  int t = threadIdx.x, wv = t >> 6, lane = t & 63;
  int n0 = blockIdx.x * 64 + wv * 16;    // 16 rows per wave
  int arow = n0 + (lane & 15);
  if (arow > NN - 1) arow = NN - 1;      // clamp for loads; stores guarded
  const _Float16* gbase = (const _Float16*)g1h + (size_t)arow * HH + (lane >> 4) * 8;
  const f16x8* bbase = (const f16x8*)Bp + lane;   // + (kt*4+ct)*64

  f32x4 acc0 = {0.f,0.f,0.f,0.f}, acc1 = {0.f,0.f,0.f,0.f};
  f32x4 acc2 = {0.f,0.f,0.f,0.f}, acc3 = {0.f,0.f,0.f,0.f};
#pragma unroll
  for (int kt = 0; kt < 8; ++kt){
    f16x8 a = *(const f16x8*)(gbase + kt * 32);
    acc0 = __builtin_amdgcn_mfma_f32_16x16x32_f16(a, bbase[(kt*4 + 0) * 64], acc0, 0, 0, 0);
    acc1 = __builtin_amdgcn_mfma_f32_16x16x32_f16(a, bbase[(kt*4 + 1) * 64], acc1, 0, 0, 0);
    acc2 = __builtin_amdgcn_mfma_f32_16x16x32_f16(a, bbase[(kt*4 + 2) * 64], acc2, 0, 0, 0);
    acc3 = __builtin_amdgcn_mfma_f32_16x16x32_f16(a, bbase[(kt*4 + 3) * 64], acc3, 0, 0, 0);
  }
  // C/D mapping: col = ct*16 + (lane&15), row = (lane>>4)*4 + i
  int c4 = lane & 15, g4 = lane >> 4;
  float as2v0 = as2[c4], as2v1 = as2[16 + c4], as2v2 = as2[32 + c4], as2v3 = as2[48 + c4];
  float ad2v0 = ad2[c4], ad2v1 = ad2[16 + c4], ad2v2 = ad2[32 + c4], ad2v3 = ad2[48 + c4];
  float vs[4], vd[4];
#pragma unroll
  for (int i = 0; i < 4; ++i){
    int n = n0 + g4 * 4 + i;
    if (n < NN){
      h2h[(size_t)n * HID + c4]      = (__half)acc0[i];
      h2h[(size_t)n * HID + 16 + c4] = (__half)acc1[i];
      h2h[(size_t)n * HID + 32 + c4] = (__half)acc2[i];
      h2h[(size_t)n * HID + 48 + c4] = (__half)acc3[i];
    }
    vs[i] = acc0[i]*as2v0 + acc1[i]*as2v1 + acc2[i]*as2v2 + acc3[i]*as2v3;
    vd[i] = acc0[i]*ad2v0 + acc1[i]*ad2v1 + acc2[i]*ad2v2 + acc3[i]*ad2v3;
  }
#pragma unroll
  for (int off = 1; off < 16; off <<= 1){
#pragma unroll
    for (int i = 0; i < 4; ++i){
      vs[i] += __shfl_xor(vs[i], off);
      vd[i] += __shfl_xor(vd[i], off);
    }
  }
  if (c4 == 0){
#pragma unroll
    for (int i = 0; i < 4; ++i){
      int n = n0 + g4 * 4 + i;
      if (n < NN){ als2[n] = vs[i]; ald2[n] = vd[i]; }
    }
  }
}

// ---------- layer-2 normalized edge weights (wave per node) ----------
__global__ void k_w2(const int* __restrict__ rs, const int* __restrict__ csr,
                     const float* __restrict__ als, const float* __restrict__ ald,
                     float* __restrict__ w2c, float* __restrict__ wself){
  int t = threadIdx.x, wv = t >> 6, lane = t & 63;
  int n = blockIdx.x * 4 + wv;
  int e0 = rs[n], e1 = rs[n + 1];
  float ad = ald[n];
  float den = 0.f;
  for (int e = e0 + lane; e < e1; e += 64){
    float w = expf(lrelu(als[csr[e]] + ad));
    w2c[e] = w;                          // unnormalized
    den += w;
  }
#pragma unroll
  for (int off = 32; off > 0; off >>= 1) den += __shfl_xor(den, off);
  float sw = expf(lrelu(als[n] + ad));
  float inv = 1.f / (den + sw + 1e-16f);
  if (lane == 0) wself[n] = sw * inv;
  for (int e = e0 + lane; e < e1; e += 64) w2c[e] *= inv;
}

// ---------- layer-2 gather (16-lane groups own a row) + ELU + hW ----------
__global__ void k_agg2f(const int* __restrict__ rs, const int* __restrict__ csr,
                        const __half* __restrict__ h2h, const float* __restrict__ w2c,
                        const float* __restrict__ wself, const float* __restrict__ b2,
                        const float* __restrict__ clW1, float* __restrict__ hW){
  __shared__ float os[4][64];
  int t = threadIdx.x, wv = t >> 6, lane = t & 63;
  int g16 = lane >> 4, c4 = lane & 15;
  int n = blockIdx.x * 4 + wv;
  int e0 = rs[n], e1 = rs[n + 1];
  float a0 = 0.f, a1 = 0.f, a2 = 0.f, a3 = 0.f;
  int e = e0 + g16;
  for (; e + 4 < e1; e += 8){
    int s0 = csr[e], s1 = csr[e + 4];
    float wa = w2c[e], wb = w2c[e + 4];
    float2 r0 = *(const float2*)(h2h + (size_t)s0 * HID + c4 * 4);
    float2 r1 = *(const float2*)(h2h + (size_t)s1 * HID + c4 * 4);
    float f0,f1,f2,f3;
    unp4(r0, f0,f1,f2,f3); a0=fmaf(wa,f0,a0); a1=fmaf(wa,f1,a1); a2=fmaf(wa,f2,a2); a3=fmaf(wa,f3,a3);
    unp4(r1, f0,f1,f2,f3); a0=fmaf(wb,f0,a0); a1=fmaf(wb,f1,a1); a2=fmaf(wb,f2,a2); a3=fmaf(wb,f3,a3);
  }
  if (e < e1){
    int s = csr[e];
    float w = w2c[e];
    float2 r = *(const float2*)(h2h + (size_t)s * HID + c4 * 4);
    float f0,f1,f2,f3; unp4(r, f0,f1,f2,f3);
    a0=fmaf(w,f0,a0); a1=fmaf(w,f1,a1); a2=fmaf(w,f2,a2); a3=fmaf(w,f3,a3);
  }
  a0 += __shfl_xor(a0, 16); a1 += __shfl_xor(a1, 16); a2 += __shfl_xor(a2, 16); a3 += __shfl_xor(a3, 16);
  a0 += __shfl_xor(a0, 32); a1 += __shfl_xor(a1, 32); a2 += __shfl_xor(a2, 32); a3 += __shfl_xor(a3, 32);
  if (lane < 16){
    float w = wself[n];
    float2 r = *(const float2*)(h2h + (size_t)n * HID + lane * 4);
    float f0,f1,f2,f3; unp4(r, f0,f1,f2,f3);
    a0 = fmaf(w, f0, a0); a1 = fmaf(w, f1, a1); a2 = fmaf(w, f2, a2); a3 = fmaf(w, f3, a3);
    float4 b4 = *(const float4*)(b2 + lane * 4);
    float4 o;
    o.x = elu_(a0 + b4.x); o.y = elu_(a1 + b4.y); o.z = elu_(a2 + b4.z); o.w = elu_(a3 + b4.w);
    *(float4*)(&os[wv][lane * 4]) = o;
  }
  __syncthreads();
  float acc = 0.f;
  const float* o = os[wv];
  for (int k = 0; k < HID; ++k) acc = fmaf(o[k], clW1[k * HID + lane], acc);
  hW[(size_t)n * HID + lane] = acc;
}

// ---------- task encoder + fold classifier bias ----------
__global__ void k_task(const float* __restrict__ task, const float* __restrict__ W1t,
                       const float* __restrict__ b1t, const float* __restrict__ W2t,
                       const float* __restrict__ b2t, const float* __restrict__ clW1,
                       const float* __restrict__ clb1, float* __restrict__ tWb){
  __shared__ float t1[16][64];
  __shared__ float t2[16][64];
  int t = threadIdx.x;
  for (int idx = t; idx < 1024; idx += 256){
    int b = idx >> 6, c = idx & 63;
    float acc = b1t[c];
    for (int k = 0; k < 128; ++k) acc = fmaf(task[b*128 + k], W1t[k*64 + c], acc);
    t1[b][c] = fmaxf(acc, 0.f);
  }
  __syncthreads();
  for (int idx = t; idx < 1024; idx += 256){
    int b = idx >> 6, c = idx & 63;
    float acc = b2t[c];
    for (int k = 0; k < 64; ++k) acc = fmaf(t1[b][k], W2t[k*64 + c], acc);
    t2[b][c] = acc;
  }
  __syncthreads();
  for (int idx = t; idx < 1024; idx += 256){
    int b = idx >> 6, c = idx & 63;
    float acc = clb1[c];
    for (int k = 0; k < 64; ++k) acc = fmaf(t2[b][k], clW1[(64 + k)*64 + c], acc);
    tWb[idx] = acc;
  }
}

// ---------- scores[b,n] = sum_k relu(hW[n,k] + tWb[b,k]) * w2[k] + cl_b2 ----------
__global__ void k_scores(const float* __restrict__ hW, const float* __restrict__ tWb,
                         const float* __restrict__ w2, const float* __restrict__ b2s,
                         float* __restrict__ out){
  __shared__ float tw[16][64];
  __shared__ float w2s[64];
  int t = threadIdx.x;
  for (int i = t; i < 1024; i += 256) tw[i >> 6][i & 63] = tWb[i];
  if (t < 64) w2s[t] = w2[t];
  __syncthreads();
  int wv = t >> 6, lane = t & 63;
  int n = blockIdx.x * 4 + wv;
  float hv = hW[n * 64 + lane];
  float bias = b2s[0];
  for (int b = 0; b < 16; ++b){
    float v = fmaxf(hv + tw[b][lane], 0.f) * w2s[lane];
#pragma unroll
    for (int off = 32; off > 0; off >>= 1) v += __shfl_xor(v, off);
    if (lane == b) out[b * NN + n] = v + bias;
  }
}

extern "C" void kernel_launch(void* const* d_in, const int* in_sizes, int n_in,
                              void* d_out, int out_size, void* d_ws, size_t ws_size,
                              hipStream_t stream){
  const float* x    = (const float*)d_in[0];
  const int*   ei   = (const int*)  d_in[1];
  const float* task = (const float*)d_in[2];
  const float* W1   = (const float*)d_in[3];
  const float* as1  = (const float*)d_in[4];
  const float* ad1  = (const float*)d_in[5];
  const float* b1   = (const float*)d_in[6];
  const float* W2   = (const float*)d_in[7];
  const float* as2  = (const float*)d_in[8];
  const float* ad2  = (const float*)d_in[9];
  const float* b2   = (const float*)d_in[10];
  const float* teW1 = (const float*)d_in[11];
  const float* teb1 = (const float*)d_in[12];
  const float* teW2 = (const float*)d_in[13];
  const float* teb2 = (const float*)d_in[14];
  const float* clW1 = (const float*)d_in[15];
  const float* clb1 = (const float*)d_in[16];
  const float* clW2 = (const float*)d_in[17];
  const float* clb2 = (const float*)d_in[18];
  float* out = (float*)d_out;
  float* ws  = (float*)d_ws;

  // workspace layout (float-sized slots)
  __half* h1h  = (__half*)ws;                 // 12.8M halfs -> 6.4M floats
  float* als1  = ws + 6400000;                // 200,000
  float* ald1  = als1 + 200000;               // 200,000
  float* w1    = ald1 + 200000;               // 3,200,000
  float* wself1= w1 + 3200000;                // 200,000
  __half* g1h  = (__half*)(wself1 + 200000);  // 12.8M halfs -> 6.4M floats
  __half* h2h  = (__half*)(wself1 + 200000 + 6400000); // 3.2M halfs -> 1.6M floats
  float* als2  = wself1 + 200000 + 6400000 + 1600000;  // 50,000
  float* ald2  = als2 + 50000;                // 50,000
  float* w2c   = ald2 + 50000;                // 800,000
  float* wself2= w2c + 800000;                // 50,000
  float* hW    = wself2 + 50000;              // 3,200,000
  float* tWb   = hW + 3200000;                // 1,024
  int*   deg   = (int*)(tWb + 1024);          // 50,000
  int*   rs    = deg + 50000;                 // 50,001 (+pad)
  int*   cur   = rs + 50004;                  // 50,000
  int*   csr   = cur + 50000;                 // 800,000
  int*   psum  = csr + 800000;                // 256
  int*   pofs  = psum + 256;                  // 256
  __half* Bp   = (__half*)(pofs + 256);       // 16,384 halfs (MFMA-ordered W2)

  // CSR build (parallel scan)
  hipMemsetAsync(deg, 0, 50000 * sizeof(int), stream);
  k_deg    <<<(NE + 255)/256, 256, 0, stream>>>(ei, deg);
  k_psum   <<<196, 256, 0, stream>>>(deg, psum);
  k_pscan  <<<1, 256, 0, stream>>>(psum, pofs);
  k_wroffs <<<196, 256, 0, stream>>>(deg, pofs, rs, cur);
  k_scatter<<<(NE + 255)/256, 256, 0, stream>>>(ei, cur, csr);

  // layer 1
  k_gemm1 <<<6250, 256, 0, stream>>>(x, W1, as1, ad1, h1h, als1, ald1);
  k_w1    <<<12500, 256, 0, stream>>>(rs, csr, als1, ald1, w1, wself1);
  k_agg1g <<<12500, 256, 0, stream>>>(rs, csr, h1h, w1, wself1, b1, g1h);
  k_w2prep<<<1, 256, 0, stream>>>(W2, Bp);
  k_gemm2m<<<(NN + 63)/64, 256, 0, stream>>>(g1h, Bp, as2, ad2, h2h, als2, ald2);

  // layer 2
  k_w2    <<<12500, 256, 0, stream>>>(rs, csr, als2, ald2, w2c, wself2);
  k_agg2f <<<12500, 256, 0, stream>>>(rs, csr, h2h, w2c, wself2, b2, clW1, hW);

  // task encoder + classifier
  k_task  <<<1, 256, 0, stream>>>(task, teW1, teb1, teW2, teb2, clW1, clb1, tWb);
  k_scores<<<12500, 256, 0, stream>>>(hW, tWb, clW2, clb2, out);
}

// Round 7
// 365.436 us; speedup vs baseline: 3.6940x; 1.1546x over previous
//
#include <hip/hip_runtime.h>
#include <hip/hip_fp16.h>

#define NN 50000
#define NE 800000
#define FN 128
#define HH 256      // HEADS*HID
#define HID 64

typedef _Float16 f16x8 __attribute__((ext_vector_type(8)));
typedef float f32x4 __attribute__((ext_vector_type(4)));

__device__ __forceinline__ float lrelu(float v){ return v >= 0.f ? v : 0.2f * v; }
__device__ __forceinline__ float elu_(float v){ return v > 0.f ? v : expm1f(v); }

__device__ __forceinline__ void unp4(const float2 r, float& f0, float& f1, float& f2, float& f3){
  const __half2* hp = (const __half2*)&r;
  float2 a = __half22float2(hp[0]);
  float2 b = __half22float2(hp[1]);
  f0 = a.x; f1 = a.y; f2 = b.x; f3 = b.y;
}

// ---------- CSR build ----------
__global__ void k_deg(const int* __restrict__ ei, int* __restrict__ deg){
  int e = blockIdx.x * 256 + threadIdx.x;
  if (e >= NE) return;
  atomicAdd(deg + ei[NE + e], 1);
}

__global__ void k_psum(const int* __restrict__ deg, int* __restrict__ psum){
  int b = blockIdx.x, t = threadIdx.x;
  int idx = b * 256 + t;
  int v = (idx < NN) ? deg[idx] : 0;
#pragma unroll
  for (int off = 32; off > 0; off >>= 1) v += __shfl_down(v, off);
  __shared__ int wsum[4];
  if ((t & 63) == 0) wsum[t >> 6] = v;
  __syncthreads();
  if (t == 0) psum[b] = wsum[0] + wsum[1] + wsum[2] + wsum[3];
}

__global__ void k_pscan(const int* __restrict__ psum, int* __restrict__ pofs){
  int t = threadIdx.x;            // 256 threads
  int lane = t & 63, wv = t >> 6;
  int v = (t < 196) ? psum[t] : 0;
  int iv = v;
#pragma unroll
  for (int off = 1; off < 64; off <<= 1){
    int u = __shfl_up(iv, off);
    if (lane >= off) iv += u;
  }
  __shared__ int wsum[4];
  if (lane == 63) wsum[wv] = iv;
  __syncthreads();
  int add = 0;
  for (int w = 0; w < wv; ++w) add += wsum[w];
  iv += add;
  if (t < 196) pofs[t] = iv - v;  // exclusive
}

__global__ void k_wroffs(const int* __restrict__ deg, const int* __restrict__ pofs,
                         int* __restrict__ rs, int* __restrict__ cur){
  int b = blockIdx.x, t = threadIdx.x;
  int idx = b * 256 + t;
  int lane = t & 63, wv = t >> 6;
  int v = (idx < NN) ? deg[idx] : 0;
  int iv = v;
#pragma unroll
  for (int off = 1; off < 64; off <<= 1){
    int u = __shfl_up(iv, off);
    if (lane >= off) iv += u;
  }
  __shared__ int wsum[4];
  if (lane == 63) wsum[wv] = iv;
  __syncthreads();
  int add = pofs[b];
  for (int w = 0; w < wv; ++w) add += wsum[w];
  int excl = add + iv - v;
  if (idx < NN){ rs[idx] = excl; cur[idx] = excl; }
  if (idx == NN) rs[NN] = excl;
}

__global__ void k_scatter(const int* __restrict__ ei, int* __restrict__ cur, int* __restrict__ csr){
  int e = blockIdx.x * 256 + threadIdx.x;
  if (e >= NE) return;
  int s = ei[e], d = ei[NE + e];
  int pos = atomicAdd(cur + d, 1);
  csr[pos] = s;
}

// ---------- W1, W2 -> MFMA fragment-ordered fp16 ----------
// W2: Bp [((kt*4+ct)*64+lane)*8+i]  = W2[kt*32 + (lane>>4)*8 + i][ct*16 + (lane&15)], kt<8, ct<4
// W1: Bp1[((kt*16+ct)*64+lane)*8+i] = W1[kt*32 + (lane>>4)*8 + i][ct*16 + (lane&15)], kt<4, ct<16
__global__ void k_prep(const float* __restrict__ W2, const float* __restrict__ W1,
                       __half* __restrict__ Bp, __half* __restrict__ Bp1){
  int f = blockIdx.x * 256 + threadIdx.x;
  if (f < 2048){
    int lane = f & 63;
    int ct = (f >> 6) & 3, kt = f >> 8;
    int kbase = kt * 32 + (lane >> 4) * 8;
    int col = ct * 16 + (lane & 15);
#pragma unroll
    for (int i = 0; i < 8; ++i)
      Bp[(size_t)f * 8 + i] = (__half)W2[(kbase + i) * HID + col];
  } else if (f < 6144){
    int g = f - 2048;
    int lane = g & 63;
    int ct = (g >> 6) & 15, kt = g >> 10;
    int kbase = kt * 32 + (lane >> 4) * 8;
    int col = ct * 16 + (lane & 15);
#pragma unroll
    for (int i = 0; i < 8; ++i)
      Bp1[(size_t)g * 8 + i] = (__half)W1[(kbase + i) * HH + col];
  }
}

// ---------- h1 = x @ W1 via MFMA 16x16x32_f16, fused alpha1 ----------
__global__ void k_gemm1m(const float* __restrict__ x, const __half* __restrict__ Bp1,
                         const float* __restrict__ as1, const float* __restrict__ ad1,
                         __half* __restrict__ h1h, float* __restrict__ als, float* __restrict__ ald){
  int t = threadIdx.x, wv = t >> 6, lane = t & 63;
  int n0 = blockIdx.x * 64 + wv * 16;    // 16 rows per wave
  int arow = n0 + (lane & 15);
  if (arow > NN - 1) arow = NN - 1;      // clamp for loads; stores guarded
  const float* xbase = x + (size_t)arow * FN + (lane >> 4) * 8;
  const f16x8* bbase = (const f16x8*)Bp1 + lane;   // + (kt*16+ct)*64

  f32x4 acc[16];
#pragma unroll
  for (int ct = 0; ct < 16; ++ct) acc[ct] = (f32x4){0.f,0.f,0.f,0.f};

#pragma unroll
  for (int kt = 0; kt < 4; ++kt){
    float4 xa = *(const float4*)(xbase + kt * 32);
    float4 xb = *(const float4*)(xbase + kt * 32 + 4);
    f16x8 a;
    a[0] = (_Float16)xa.x; a[1] = (_Float16)xa.y; a[2] = (_Float16)xa.z; a[3] = (_Float16)xa.w;
    a[4] = (_Float16)xb.x; a[5] = (_Float16)xb.y; a[6] = (_Float16)xb.z; a[7] = (_Float16)xb.w;
#pragma unroll
    for (int ct = 0; ct < 16; ++ct)
      acc[ct] = __builtin_amdgcn_mfma_f32_16x16x32_f16(a, bbase[(kt*16 + ct) * 64], acc[ct], 0, 0, 0);
  }

  // C/D mapping: col = ct*16 + (lane&15), row = (lane>>4)*4 + i
  int c4 = lane & 15, g4 = lane >> 4;
#pragma unroll
  for (int ct = 0; ct < 16; ++ct){
#pragma unroll
    for (int i = 0; i < 4; ++i){
      int n = n0 + g4 * 4 + i;
      if (n < NN) h1h[(size_t)n * HH + ct * 16 + c4] = (__half)acc[ct][i];
    }
  }
  // fused alpha1: head h covers ct = 4h..4h+3
#pragma unroll
  for (int h = 0; h < 4; ++h){
    float sa0 = as1[(h*4+0)*16 + c4], sa1 = as1[(h*4+1)*16 + c4];
    float sa2 = as1[(h*4+2)*16 + c4], sa3 = as1[(h*4+3)*16 + c4];
    float da0 = ad1[(h*4+0)*16 + c4], da1 = ad1[(h*4+1)*16 + c4];
    float da2 = ad1[(h*4+2)*16 + c4], da3 = ad1[(h*4+3)*16 + c4];
#pragma unroll
    for (int i = 0; i < 4; ++i){
      float vs = acc[h*4+0][i]*sa0 + acc[h*4+1][i]*sa1 + acc[h*4+2][i]*sa2 + acc[h*4+3][i]*sa3;
      float vd = acc[h*4+0][i]*da0 + acc[h*4+1][i]*da1 + acc[h*4+2][i]*da2 + acc[h*4+3][i]*da3;
#pragma unroll
      for (int off = 1; off < 16; off <<= 1){
        vs += __shfl_xor(vs, off);
        vd += __shfl_xor(vd, off);
      }
      if (c4 == 0){
        int n = n0 + g4 * 4 + i;
        if (n < NN){ als[n*4 + h] = vs; ald[n*4 + h] = vd; }
      }
    }
  }
}

// ---------- layer-1 normalized edge weights (wave per node) ----------
__global__ void k_w1(const int* __restrict__ rs, const int* __restrict__ csr,
                     const float* __restrict__ als, const float* __restrict__ ald,
                     float* __restrict__ w1, float* __restrict__ wself){
  int t = threadIdx.x, wv = t >> 6, lane = t & 63;
  int n = blockIdx.x * 4 + wv;
  int e0 = rs[n], e1 = rs[n + 1];
  float4 ad = *(const float4*)(ald + n * 4);
  float d0 = 0.f, d1 = 0.f, d2 = 0.f, d3 = 0.f;
  for (int e = e0 + lane; e < e1; e += 64){
    int s = csr[e];
    float4 a = *(const float4*)(als + s * 4);
    float4 w;
    w.x = expf(lrelu(a.x + ad.x)); w.y = expf(lrelu(a.y + ad.y));
    w.z = expf(lrelu(a.z + ad.z)); w.w = expf(lrelu(a.w + ad.w));
    *(float4*)(w1 + e * 4) = w;           // unnormalized
    d0 += w.x; d1 += w.y; d2 += w.z; d3 += w.w;
  }
#pragma unroll
  for (int off = 32; off > 0; off >>= 1){
    d0 += __shfl_xor(d0, off); d1 += __shfl_xor(d1, off);
    d2 += __shfl_xor(d2, off); d3 += __shfl_xor(d3, off);
  }
  float4 as_ = *(const float4*)(als + n * 4);
  float s0 = expf(lrelu(as_.x + ad.x)), s1 = expf(lrelu(as_.y + ad.y));
  float s2 = expf(lrelu(as_.z + ad.z)), s3 = expf(lrelu(as_.w + ad.w));
  float i0 = 1.f / (d0 + s0 + 1e-16f), i1 = 1.f / (d1 + s1 + 1e-16f);
  float i2 = 1.f / (d2 + s2 + 1e-16f), i3 = 1.f / (d3 + s3 + 1e-16f);
  if (lane == 0){
    wself[n*4 + 0] = s0 * i0; wself[n*4 + 1] = s1 * i1;
    wself[n*4 + 2] = s2 * i2; wself[n*4 + 3] = s3 * i3;
  }
  for (int e = e0 + lane; e < e1; e += 64){
    float4 w = *(const float4*)(w1 + e * 4);
    w.x *= i0; w.y *= i1; w.z *= i2; w.w *= i3;
    *(float4*)(w1 + e * 4) = w;
  }
}

// ---------- layer-1 gather: wave per node, lane = 4 channels ----------
__global__ void k_agg1g(const int* __restrict__ rs, const int* __restrict__ csr,
                        const __half* __restrict__ h1h, const float* __restrict__ w1,
                        const float* __restrict__ wself, const float* __restrict__ b1,
                        __half* __restrict__ g1h){
  int t = threadIdx.x, wv = t >> 6, lane = t & 63;
  int head = lane >> 4;
  int n = blockIdx.x * 4 + wv;
  float a0, a1, a2, a3;
  { // self-loop term
    float w = wself[n*4 + head];
    float2 r = *(const float2*)(h1h + (size_t)n * HH + lane * 4);
    float f0,f1,f2,f3; unp4(r, f0,f1,f2,f3);
    a0 = w*f0; a1 = w*f1; a2 = w*f2; a3 = w*f3;
  }
  int e0 = rs[n], e1 = rs[n + 1];
  int e = e0;
  for (; e + 3 < e1; e += 4){
    int s0 = csr[e], s1 = csr[e+1], s2 = csr[e+2], s3 = csr[e+3];
    float wa = w1[e*4 + head], wb = w1[(e+1)*4 + head];
    float wc = w1[(e+2)*4 + head], wd = w1[(e+3)*4 + head];
    float2 r0 = *(const float2*)(h1h + (size_t)s0 * HH + lane * 4);
    float2 r1 = *(const float2*)(h1h + (size_t)s1 * HH + lane * 4);
    float2 r2 = *(const float2*)(h1h + (size_t)s2 * HH + lane * 4);
    float2 r3 = *(const float2*)(h1h + (size_t)s3 * HH + lane * 4);
    float f0,f1,f2,f3;
    unp4(r0, f0,f1,f2,f3); a0=fmaf(wa,f0,a0); a1=fmaf(wa,f1,a1); a2=fmaf(wa,f2,a2); a3=fmaf(wa,f3,a3);
    unp4(r1, f0,f1,f2,f3); a0=fmaf(wb,f0,a0); a1=fmaf(wb,f1,a1); a2=fmaf(wb,f2,a2); a3=fmaf(wb,f3,a3);
    unp4(r2, f0,f1,f2,f3); a0=fmaf(wc,f0,a0); a1=fmaf(wc,f1,a1); a2=fmaf(wc,f2,a2); a3=fmaf(wc,f3,a3);
    unp4(r3, f0,f1,f2,f3); a0=fmaf(wd,f0,a0); a1=fmaf(wd,f1,a1); a2=fmaf(wd,f2,a2); a3=fmaf(wd,f3,a3);
  }
  for (; e < e1; ++e){
    int s = csr[e];
    float w = w1[e*4 + head];
    float2 r = *(const float2*)(h1h + (size_t)s * HH + lane * 4);
    float f0,f1,f2,f3; unp4(r, f0,f1,f2,f3);
    a0=fmaf(w,f0,a0); a1=fmaf(w,f1,a1); a2=fmaf(w,f2,a2); a3=fmaf(w,f3,a3);
  }
  float4 b4 = *(const float4*)(b1 + lane * 4);
  __half2 p0 = __floats2half2_rn(elu_(a0 + b4.x), elu_(a1 + b4.y));
  __half2 p1 = __floats2half2_rn(elu_(a2 + b4.z), elu_(a3 + b4.w));
  float2 outv; ((__half2*)&outv)[0] = p0; ((__half2*)&outv)[1] = p1;
  *(float2*)(g1h + (size_t)n * HH + lane * 4) = outv;
}

// ---------- h2 = g1 @ W2 via MFMA 16x16x32_f16, fused alpha2 ----------
__global__ void k_gemm2m(const __half* __restrict__ g1h, const __half* __restrict__ Bp,
                         const float* __restrict__ as2, const float* __restrict__ ad2,
                         __half* __restrict__ h2h, float* __restrict__ als2, float* __restrict__ ald2){
  int t = threadIdx.x, wv = t >> 6, lane = t & 63;
  int n0 = blockIdx.x * 64 + wv * 16;    // 16 rows per wave
  int arow = n0 + (lane & 15);
  if (arow > NN - 1) arow = NN - 1;      // clamp for loads; stores guarded
  const _Float16* gbase = (const _Float16*)g1h + (size_t)arow * HH + (lane >> 4) * 8;
  const f16x8* bbase = (const f16x8*)Bp + lane;   // + (kt*4+ct)*64

  f32x4 acc0 = {0.f,0.f,0.f,0.f}, acc1 = {0.f,0.f,0.f,0.f};
  f32x4 acc2 = {0.f,0.f,0.f,0.f}, acc3 = {0.f,0.f,0.f,0.f};
#pragma unroll
  for (int kt = 0; kt < 8; ++kt){
    f16x8 a = *(const f16x8*)(gbase + kt * 32);
    acc0 = __builtin_amdgcn_mfma_f32_16x16x32_f16(a, bbase[(kt*4 + 0) * 64], acc0, 0, 0, 0);
    acc1 = __builtin_amdgcn_mfma_f32_16x16x32_f16(a, bbase[(kt*4 + 1) * 64], acc1, 0, 0, 0);
    acc2 = __builtin_amdgcn_mfma_f32_16x16x32_f16(a, bbase[(kt*4 + 2) * 64], acc2, 0, 0, 0);
    acc3 = __builtin_amdgcn_mfma_f32_16x16x32_f16(a, bbase[(kt*4 + 3) * 64], acc3, 0, 0, 0);
  }
  // C/D mapping: col = ct*16 + (lane&15), row = (lane>>4)*4 + i
  int c4 = lane & 15, g4 = lane >> 4;
  float as2v0 = as2[c4], as2v1 = as2[16 + c4], as2v2 = as2[32 + c4], as2v3 = as2[48 + c4];
  float ad2v0 = ad2[c4], ad2v1 = ad2[16 + c4], ad2v2 = ad2[32 + c4], ad2v3 = ad2[48 + c4];
  float vs[4], vd[4];
#pragma unroll
  for (int i = 0; i < 4; ++i){
    int n = n0 + g4 * 4 + i;
    if (n < NN){
      h2h[(size_t)n * HID + c4]      = (__half)acc0[i];
      h2h[(size_t)n * HID + 16 + c4] = (__half)acc1[i];
      h2h[(size_t)n * HID + 32 + c4] = (__half)acc2[i];
      h2h[(size_t)n * HID + 48 + c4] = (__half)acc3[i];
    }
    vs[i] = acc0[i]*as2v0 + acc1[i]*as2v1 + acc2[i]*as2v2 + acc3[i]*as2v3;
    vd[i] = acc0[i]*ad2v0 + acc1[i]*ad2v1 + acc2[i]*ad2v2 + acc3[i]*ad2v3;
  }
#pragma unroll
  for (int off = 1; off < 16; off <<= 1){
#pragma unroll
    for (int i = 0; i < 4; ++i){
      vs[i] += __shfl_xor(vs[i], off);
      vd[i] += __shfl_xor(vd[i], off);
    }
  }
  if (c4 == 0){
#pragma unroll
    for (int i = 0; i < 4; ++i){
      int n = n0 + g4 * 4 + i;
      if (n < NN){ als2[n] = vs[i]; ald2[n] = vd[i]; }
    }
  }
}

// ---------- layer-2 normalized edge weights (wave per node) ----------
__global__ void k_w2(const int* __restrict__ rs, const int* __restrict__ csr,
                     const float* __restrict__ als, const float* __restrict__ ald,
                     float* __restrict__ w2c, float* __restrict__ wself){
  int t = threadIdx.x, wv = t >> 6, lane = t & 63;
  int n = blockIdx.x * 4 + wv;
  int e0 = rs[n], e1 = rs[n + 1];
  float ad = ald[n];
  float den = 0.f;
  for (int e = e0 + lane; e < e1; e += 64){
    float w = expf(lrelu(als[csr[e]] + ad));
    w2c[e] = w;                          // unnormalized
    den += w;
  }
#pragma unroll
  for (int off = 32; off > 0; off >>= 1) den += __shfl_xor(den, off);
  float sw = expf(lrelu(als[n] + ad));
  float inv = 1.f / (den + sw + 1e-16f);
  if (lane == 0) wself[n] = sw * inv;
  for (int e = e0 + lane; e < e1; e += 64) w2c[e] *= inv;
}

// ---------- layer-2 gather (16-lane groups own a row) + ELU + hW ----------
__global__ void k_agg2f(const int* __restrict__ rs, const int* __restrict__ csr,
                        const __half* __restrict__ h2h, const float* __restrict__ w2c,
                        const float* __restrict__ wself, const float* __restrict__ b2,
                        const float* __restrict__ clW1, float* __restrict__ hW){
  __shared__ float os[4][64];
  int t = threadIdx.x, wv = t >> 6, lane = t & 63;
  int g16 = lane >> 4, c4 = lane & 15;
  int n = blockIdx.x * 4 + wv;
  int e0 = rs[n], e1 = rs[n + 1];
  float a0 = 0.f, a1 = 0.f, a2 = 0.f, a3 = 0.f;
  int e = e0 + g16;
  for (; e + 4 < e1; e += 8){
    int s0 = csr[e], s1 = csr[e + 4];
    float wa = w2c[e], wb = w2c[e + 4];
    float2 r0 = *(const float2*)(h2h + (size_t)s0 * HID + c4 * 4);
    float2 r1 = *(const float2*)(h2h + (size_t)s1 * HID + c4 * 4);
    float f0,f1,f2,f3;
    unp4(r0, f0,f1,f2,f3); a0=fmaf(wa,f0,a0); a1=fmaf(wa,f1,a1); a2=fmaf(wa,f2,a2); a3=fmaf(wa,f3,a3);
    unp4(r1, f0,f1,f2,f3); a0=fmaf(wb,f0,a0); a1=fmaf(wb,f1,a1); a2=fmaf(wb,f2,a2); a3=fmaf(wb,f3,a3);
  }
  if (e < e1){
    int s = csr[e];
    float w = w2c[e];
    float2 r = *(const float2*)(h2h + (size_t)s * HID + c4 * 4);
    float f0,f1,f2,f3; unp4(r, f0,f1,f2,f3);
    a0=fmaf(w,f0,a0); a1=fmaf(w,f1,a1); a2=fmaf(w,f2,a2); a3=fmaf(w,f3,a3);
  }
  a0 += __shfl_xor(a0, 16); a1 += __shfl_xor(a1, 16); a2 += __shfl_xor(a2, 16); a3 += __shfl_xor(a3, 16);
  a0 += __shfl_xor(a0, 32); a1 += __shfl_xor(a1, 32); a2 += __shfl_xor(a2, 32); a3 += __shfl_xor(a3, 32);
  if (lane < 16){
    float w = wself[n];
    float2 r = *(const float2*)(h2h + (size_t)n * HID + lane * 4);
    float f0,f1,f2,f3; unp4(r, f0,f1,f2,f3);
    a0 = fmaf(w, f0, a0); a1 = fmaf(w, f1, a1); a2 = fmaf(w, f2, a2); a3 = fmaf(w, f3, a3);
    float4 b4 = *(const float4*)(b2 + lane * 4);
    float4 o;
    o.x = elu_(a0 + b4.x); o.y = elu_(a1 + b4.y); o.z = elu_(a2 + b4.z); o.w = elu_(a3 + b4.w);
    *(float4*)(&os[wv][lane * 4]) = o;
  }
  __syncthreads();
  float acc = 0.f;
  const float* o = os[wv];
  for (int k = 0; k < HID; ++k) acc = fmaf(o[k], clW1[k * HID + lane], acc);
  hW[(size_t)n * HID + lane] = acc;
}

// ---------- task encoder + fold classifier bias ----------
__global__ void k_task(const float* __restrict__ task, const float* __restrict__ W1t,
                       const float* __restrict__ b1t, const float* __restrict__ W2t,
                       const float* __restrict__ b2t, const float* __restrict__ clW1,
                       const float* __restrict__ clb1, float* __restrict__ tWb){
  __shared__ float t1[16][64];
  __shared__ float t2[16][64];
  int t = threadIdx.x;
  for (int idx = t; idx < 1024; idx += 256){
    int b = idx >> 6, c = idx & 63;
    float acc = b1t[c];
    for (int k = 0; k < 128; ++k) acc = fmaf(task[b*128 + k], W1t[k*64 + c], acc);
    t1[b][c] = fmaxf(acc, 0.f);
  }
  __syncthreads();
  for (int idx = t; idx < 1024; idx += 256){
    int b = idx >> 6, c = idx & 63;
    float acc = b2t[c];
    for (int k = 0; k < 64; ++k) acc = fmaf(t1[b][k], W2t[k*64 + c], acc);
    t2[b][c] = acc;
  }
  __syncthreads();
  for (int idx = t; idx < 1024; idx += 256){
    int b = idx >> 6, c = idx & 63;
    float acc = clb1[c];
    for (int k = 0; k < 64; ++k) acc = fmaf(t2[b][k], clW1[(64 + k)*64 + c], acc);
    tWb[idx] = acc;
  }
}

// ---------- scores[b,n] = sum_k relu(hW[n,k] + tWb[b,k]) * w2[k] + cl_b2 ----------
__global__ void k_scores(const float* __restrict__ hW, const float* __restrict__ tWb,
                         const float* __restrict__ w2, const float* __restrict__ b2s,
                         float* __restrict__ out){
  __shared__ float tw[16][64];
  __shared__ float w2s[64];
  int t = threadIdx.x;
  for (int i = t; i < 1024; i += 256) tw[i >> 6][i & 63] = tWb[i];
  if (t < 64) w2s[t] = w2[t];
  __syncthreads();
  int wv = t >> 6, lane = t & 63;
  int n = blockIdx.x * 4 + wv;
  float hv = hW[n * 64 + lane];
  float bias = b2s[0];
  for (int b = 0; b < 16; ++b){
    float v = fmaxf(hv + tw[b][lane], 0.f) * w2s[lane];
#pragma unroll
    for (int off = 32; off > 0; off >>= 1) v += __shfl_xor(v, off);
    if (lane == b) out[b * NN + n] = v + bias;
  }
}

extern "C" void kernel_launch(void* const* d_in, const int* in_sizes, int n_in,
                              void* d_out, int out_size, void* d_ws, size_t ws_size,
                              hipStream_t stream){
  const float* x    = (const float*)d_in[0];
  const int*   ei   = (const int*)  d_in[1];
  const float* task = (const float*)d_in[2];
  const float* W1   = (const float*)d_in[3];
  const float* as1  = (const float*)d_in[4];
  const float* ad1  = (const float*)d_in[5];
  const float* b1   = (const float*)d_in[6];
  const float* W2   = (const float*)d_in[7];
  const float* as2  = (const float*)d_in[8];
  const float* ad2  = (const float*)d_in[9];
  const float* b2   = (const float*)d_in[10];
  const float* teW1 = (const float*)d_in[11];
  const float* teb1 = (const float*)d_in[12];
  const float* teW2 = (const float*)d_in[13];
  const float* teb2 = (const float*)d_in[14];
  const float* clW1 = (const float*)d_in[15];
  const float* clb1 = (const float*)d_in[16];
  const float* clW2 = (const float*)d_in[17];
  const float* clb2 = (const float*)d_in[18];
  float* out = (float*)d_out;
  float* ws  = (float*)d_ws;

  // workspace layout (float-sized slots)
  __half* h1h  = (__half*)ws;                 // 12.8M halfs -> 6.4M floats
  float* als1  = ws + 6400000;                // 200,000
  float* ald1  = als1 + 200000;               // 200,000
  float* w1    = ald1 + 200000;               // 3,200,000
  float* wself1= w1 + 3200000;                // 200,000
  __half* g1h  = (__half*)(wself1 + 200000);  // 12.8M halfs -> 6.4M floats
  __half* h2h  = (__half*)(wself1 + 200000 + 6400000); // 3.2M halfs -> 1.6M floats
  float* als2  = wself1 + 200000 + 6400000 + 1600000;  // 50,000
  float* ald2  = als2 + 50000;                // 50,000
  float* w2c   = ald2 + 50000;                // 800,000
  float* wself2= w2c + 800000;                // 50,000
  float* hW    = wself2 + 50000;              // 3,200,000
  float* tWb   = hW + 3200000;                // 1,024
  int*   deg   = (int*)(tWb + 1024);          // 50,000
  int*   rs    = deg + 50000;                 // 50,001 (+pad)
  int*   cur   = rs + 50004;                  // 50,000
  int*   csr   = cur + 50000;                 // 800,000
  int*   psum  = csr + 800000;                // 256
  int*   pofs  = psum + 256;                  // 256
  __half* Bp   = (__half*)(pofs + 256);       // 16,384 halfs (MFMA-ordered W2)
  __half* Bp1  = Bp + 16384;                  // 32,768 halfs (MFMA-ordered W1)

  // CSR build (parallel scan)
  hipMemsetAsync(deg, 0, 50000 * sizeof(int), stream);
  k_deg    <<<(NE + 255)/256, 256, 0, stream>>>(ei, deg);
  k_psum   <<<196, 256, 0, stream>>>(deg, psum);
  k_pscan  <<<1, 256, 0, stream>>>(psum, pofs);
  k_wroffs <<<196, 256, 0, stream>>>(deg, pofs, rs, cur);
  k_scatter<<<(NE + 255)/256, 256, 0, stream>>>(ei, cur, csr);

  // weight prep (both GEMM weight permutations)
  k_prep   <<<24, 256, 0, stream>>>(W2, W1, Bp, Bp1);

  // layer 1
  k_gemm1m<<<(NN + 63)/64, 256, 0, stream>>>(x, Bp1, as1, ad1, h1h, als1, ald1);
  k_w1    <<<12500, 256, 0, stream>>>(rs, csr, als1, ald1, w1, wself1);
  k_agg1g <<<12500, 256, 0, stream>>>(rs, csr, h1h, w1, wself1, b1, g1h);
  k_gemm2m<<<(NN + 63)/64, 256, 0, stream>>>(g1h, Bp, as2, ad2, h2h, als2, ald2);

  // layer 2
  k_w2    <<<12500, 256, 0, stream>>>(rs, csr, als2, ald2, w2c, wself2);
  k_agg2f <<<12500, 256, 0, stream>>>(rs, csr, h2h, w2c, wself2, b2, clW1, hW);

  // task encoder + classifier
  k_task  <<<1, 256, 0, stream>>>(task, teW1, teb1, teW2, teb2, clW1, clb1, tWb);
  k_scores<<<12500, 256, 0, stream>>>(hW, tWb, clW2, clb2, out);
}

// Round 8
// 326.720 us; speedup vs baseline: 4.1317x; 1.1185x over previous
//
#include <hip/hip_runtime.h>
#include <hip/hip_fp16.h>

#define NN 50000
#define NE 800000
#define FN 128
#define HH 256      // HEADS*HID
#define HID 64

typedef _Float16 f16x8 __attribute__((ext_vector_type(8)));
typedef float f32x4 __attribute__((ext_vector_type(4)));

__device__ __forceinline__ float lrelu(float v){ return v >= 0.f ? v : 0.2f * v; }
__device__ __forceinline__ float elu_(float v){ return v > 0.f ? v : expm1f(v); }

__device__ __forceinline__ void unp4(const float2 r, float& f0, float& f1, float& f2, float& f3){
  const __half2* hp = (const __half2*)&r;
  float2 a = __half22float2(hp[0]);
  float2 b = __half22float2(hp[1]);
  f0 = a.x; f1 = a.y; f2 = b.x; f3 = b.y;
}

// ---------- CSR build ----------
__global__ void k_deg(const int* __restrict__ ei, int* __restrict__ deg){
  int e = blockIdx.x * 256 + threadIdx.x;
  if (e >= NE) return;
  atomicAdd(deg + ei[NE + e], 1);
}

__global__ void k_psum(const int* __restrict__ deg, int* __restrict__ psum){
  int b = blockIdx.x, t = threadIdx.x;
  int idx = b * 256 + t;
  int v = (idx < NN) ? deg[idx] : 0;
#pragma unroll
  for (int off = 32; off > 0; off >>= 1) v += __shfl_down(v, off);
  __shared__ int wsum[4];
  if ((t & 63) == 0) wsum[t >> 6] = v;
  __syncthreads();
  if (t == 0) psum[b] = wsum[0] + wsum[1] + wsum[2] + wsum[3];
}

__global__ void k_pscan(const int* __restrict__ psum, int* __restrict__ pofs){
  int t = threadIdx.x;            // 256 threads
  int lane = t & 63, wv = t >> 6;
  int v = (t < 196) ? psum[t] : 0;
  int iv = v;
#pragma unroll
  for (int off = 1; off < 64; off <<= 1){
    int u = __shfl_up(iv, off);
    if (lane >= off) iv += u;
  }
  __shared__ int wsum[4];
  if (lane == 63) wsum[wv] = iv;
  __syncthreads();
  int add = 0;
  for (int w = 0; w < wv; ++w) add += wsum[w];
  iv += add;
  if (t < 196) pofs[t] = iv - v;  // exclusive
}

__global__ void k_wroffs(const int* __restrict__ deg, const int* __restrict__ pofs,
                         int* __restrict__ rs, int* __restrict__ cur){
  int b = blockIdx.x, t = threadIdx.x;
  int idx = b * 256 + t;
  int lane = t & 63, wv = t >> 6;
  int v = (idx < NN) ? deg[idx] : 0;
  int iv = v;
#pragma unroll
  for (int off = 1; off < 64; off <<= 1){
    int u = __shfl_up(iv, off);
    if (lane >= off) iv += u;
  }
  __shared__ int wsum[4];
  if (lane == 63) wsum[wv] = iv;
  __syncthreads();
  int add = pofs[b];
  for (int w = 0; w < wv; ++w) add += wsum[w];
  int excl = add + iv - v;
  if (idx < NN){ rs[idx] = excl; cur[idx] = excl; }
  if (idx == NN) rs[NN] = excl;
}

__global__ void k_scatter(const int* __restrict__ ei, int* __restrict__ cur, int* __restrict__ csr){
  int e = blockIdx.x * 256 + threadIdx.x;
  if (e >= NE) return;
  int s = ei[e], d = ei[NE + e];
  int pos = atomicAdd(cur + d, 1);
  csr[pos] = s;
}

// ---------- W1, W2 -> MFMA fragment-ordered fp16 ----------
__global__ void k_prep(const float* __restrict__ W2, const float* __restrict__ W1,
                       __half* __restrict__ Bp, __half* __restrict__ Bp1){
  int f = blockIdx.x * 256 + threadIdx.x;
  if (f < 2048){
    int lane = f & 63;
    int ct = (f >> 6) & 3, kt = f >> 8;
    int kbase = kt * 32 + (lane >> 4) * 8;
    int col = ct * 16 + (lane & 15);
#pragma unroll
    for (int i = 0; i < 8; ++i)
      Bp[(size_t)f * 8 + i] = (__half)W2[(kbase + i) * HID + col];
  } else if (f < 6144){
    int g = f - 2048;
    int lane = g & 63;
    int ct = (g >> 6) & 15, kt = g >> 10;
    int kbase = kt * 32 + (lane >> 4) * 8;
    int col = ct * 16 + (lane & 15);
#pragma unroll
    for (int i = 0; i < 8; ++i)
      Bp1[(size_t)g * 8 + i] = (__half)W1[(kbase + i) * HH + col];
  }
}

// ---------- h1 = x @ W1 via MFMA 16x16x32_f16, fused alpha1 ----------
__global__ void k_gemm1m(const float* __restrict__ x, const __half* __restrict__ Bp1,
                         const float* __restrict__ as1, const float* __restrict__ ad1,
                         __half* __restrict__ h1h, float* __restrict__ als, float* __restrict__ ald){
  int t = threadIdx.x, wv = t >> 6, lane = t & 63;
  int n0 = blockIdx.x * 64 + wv * 16;    // 16 rows per wave
  int arow = n0 + (lane & 15);
  if (arow > NN - 1) arow = NN - 1;      // clamp for loads; stores guarded
  const float* xbase = x + (size_t)arow * FN + (lane >> 4) * 8;
  const f16x8* bbase = (const f16x8*)Bp1 + lane;   // + (kt*16+ct)*64

  f32x4 acc[16];
#pragma unroll
  for (int ct = 0; ct < 16; ++ct) acc[ct] = (f32x4){0.f,0.f,0.f,0.f};

#pragma unroll
  for (int kt = 0; kt < 4; ++kt){
    float4 xa = *(const float4*)(xbase + kt * 32);
    float4 xb = *(const float4*)(xbase + kt * 32 + 4);
    f16x8 a;
    a[0] = (_Float16)xa.x; a[1] = (_Float16)xa.y; a[2] = (_Float16)xa.z; a[3] = (_Float16)xa.w;
    a[4] = (_Float16)xb.x; a[5] = (_Float16)xb.y; a[6] = (_Float16)xb.z; a[7] = (_Float16)xb.w;
#pragma unroll
    for (int ct = 0; ct < 16; ++ct)
      acc[ct] = __builtin_amdgcn_mfma_f32_16x16x32_f16(a, bbase[(kt*16 + ct) * 64], acc[ct], 0, 0, 0);
  }

  // C/D mapping: col = ct*16 + (lane&15), row = (lane>>4)*4 + i
  int c4 = lane & 15, g4 = lane >> 4;
#pragma unroll
  for (int ct = 0; ct < 16; ++ct){
#pragma unroll
    for (int i = 0; i < 4; ++i){
      int n = n0 + g4 * 4 + i;
      if (n < NN) h1h[(size_t)n * HH + ct * 16 + c4] = (__half)acc[ct][i];
    }
  }
  // fused alpha1: head h covers ct = 4h..4h+3
#pragma unroll
  for (int h = 0; h < 4; ++h){
    float sa0 = as1[(h*4+0)*16 + c4], sa1 = as1[(h*4+1)*16 + c4];
    float sa2 = as1[(h*4+2)*16 + c4], sa3 = as1[(h*4+3)*16 + c4];
    float da0 = ad1[(h*4+0)*16 + c4], da1 = ad1[(h*4+1)*16 + c4];
    float da2 = ad1[(h*4+2)*16 + c4], da3 = ad1[(h*4+3)*16 + c4];
#pragma unroll
    for (int i = 0; i < 4; ++i){
      float vs = acc[h*4+0][i]*sa0 + acc[h*4+1][i]*sa1 + acc[h*4+2][i]*sa2 + acc[h*4+3][i]*sa3;
      float vd = acc[h*4+0][i]*da0 + acc[h*4+1][i]*da1 + acc[h*4+2][i]*da2 + acc[h*4+3][i]*da3;
#pragma unroll
      for (int off = 1; off < 16; off <<= 1){
        vs += __shfl_xor(vs, off);
        vd += __shfl_xor(vd, off);
      }
      if (c4 == 0){
        int n = n0 + g4 * 4 + i;
        if (n < NN){ als[n*4 + h] = vs; ald[n*4 + h] = vd; }
      }
    }
  }
}

// ---------- fused layer-1 softmax weights + gather + ELU (wave per node) ----------
// phase A: lane (head=lane>>4, q=lane&15) computes exp-weight of edge e0+p*16+q for
// its head; <=64 edges live in 4 register pairs; deg>64 tail is recomputed.
// phase B: lane owns 4 channels (lane*4); weights broadcast from registers via shfl.
__global__ void k_agg1m(const int* __restrict__ rs, const int* __restrict__ csr,
                        const __half* __restrict__ h1h, const float* __restrict__ als,
                        const float* __restrict__ ald, const float* __restrict__ b1,
                        __half* __restrict__ g1h){
  int t = threadIdx.x, wv = t >> 6, lane = t & 63;
  int head = lane >> 4, q = lane & 15;
  int n = blockIdx.x * 4 + wv;
  int e0 = rs[n], e1 = rs[n + 1];
  int deg = e1 - e0;
  float adh = ald[n*4 + head];

  float w0r = 0.f, w1r = 0.f, w2r = 0.f, w3r = 0.f;
  int   s0r = 0,   s1r = 0,   s2r = 0,   s3r = 0;
  float den = 0.f;
  if (q      < deg){ s0r = csr[e0 + q];      w0r = expf(lrelu(als[s0r*4+head] + adh)); den += w0r; }
  if (q + 16 < deg){ s1r = csr[e0 + 16 + q]; w1r = expf(lrelu(als[s1r*4+head] + adh)); den += w1r; }
  if (q + 32 < deg){ s2r = csr[e0 + 32 + q]; w2r = expf(lrelu(als[s2r*4+head] + adh)); den += w2r; }
  if (q + 48 < deg){ s3r = csr[e0 + 48 + q]; w3r = expf(lrelu(als[s3r*4+head] + adh)); den += w3r; }
  for (int e = e0 + 64 + q; e < e1; e += 16) den += expf(lrelu(als[csr[e]*4+head] + adh));
  den += __shfl_xor(den, 1); den += __shfl_xor(den, 2);
  den += __shfl_xor(den, 4); den += __shfl_xor(den, 8);
  float selfw = expf(lrelu(als[n*4+head] + adh));
  float inv = 1.f / (den + selfw + 1e-16f);
  float wself = selfw * inv;

  float a0, a1, a2, a3;
  { float2 r = *(const float2*)(h1h + (size_t)n * HH + lane * 4);
    float f0,f1,f2,f3; unp4(r, f0,f1,f2,f3);
    a0 = wself*f0; a1 = wself*f1; a2 = wself*f2; a3 = wself*f3; }

  int hb = lane & 48;
  int cnt = deg < 64 ? deg : 64;
  auto pass = [&](float wp, int sp, int off){
    int lim = cnt - off; if (lim <= 0) return; if (lim > 16) lim = 16;
    for (int q2 = 0; q2 < lim; q2 += 2){
      bool two = (q2 + 1 < lim);                  // wave-uniform
      int  q3 = two ? q2 + 1 : q2;
      float wa = inv * __shfl(wp, hb + q2);
      int   sa = __shfl(sp, hb + q2);
      float wb = two ? inv * __shfl(wp, hb + q3) : 0.f;
      int   sb = __shfl(sp, hb + q3);
      float2 ra = *(const float2*)(h1h + (size_t)sa * HH + lane * 4);
      float2 rb = *(const float2*)(h1h + (size_t)sb * HH + lane * 4);
      float f0,f1,f2,f3;
      unp4(ra, f0,f1,f2,f3); a0=fmaf(wa,f0,a0); a1=fmaf(wa,f1,a1); a2=fmaf(wa,f2,a2); a3=fmaf(wa,f3,a3);
      unp4(rb, f0,f1,f2,f3); a0=fmaf(wb,f0,a0); a1=fmaf(wb,f1,a1); a2=fmaf(wb,f2,a2); a3=fmaf(wb,f3,a3);
    }
  };
  pass(w0r, s0r, 0); pass(w1r, s1r, 16); pass(w2r, s2r, 32); pass(w3r, s3r, 48);
  // rare tail: deg > 64, recompute weights directly (uniform loop)
  for (int e = e0 + 64; e < e1; ++e){
    int s = csr[e];
    float w = inv * expf(lrelu(als[s*4+head] + adh));
    float2 r = *(const float2*)(h1h + (size_t)s * HH + lane * 4);
    float f0,f1,f2,f3; unp4(r, f0,f1,f2,f3);
    a0=fmaf(w,f0,a0); a1=fmaf(w,f1,a1); a2=fmaf(w,f2,a2); a3=fmaf(w,f3,a3);
  }

  float4 b4 = *(const float4*)(b1 + lane * 4);
  __half2 p0 = __floats2half2_rn(elu_(a0 + b4.x), elu_(a1 + b4.y));
  __half2 p1 = __floats2half2_rn(elu_(a2 + b4.z), elu_(a3 + b4.w));
  float2 outv; ((__half2*)&outv)[0] = p0; ((__half2*)&outv)[1] = p1;
  *(float2*)(g1h + (size_t)n * HH + lane * 4) = outv;
}

// ---------- h2 = g1 @ W2 via MFMA 16x16x32_f16, fused alpha2 ----------
__global__ void k_gemm2m(const __half* __restrict__ g1h, const __half* __restrict__ Bp,
                         const float* __restrict__ as2, const float* __restrict__ ad2,
                         __half* __restrict__ h2h, float* __restrict__ als2, float* __restrict__ ald2){
  int t = threadIdx.x, wv = t >> 6, lane = t & 63;
  int n0 = blockIdx.x * 64 + wv * 16;    // 16 rows per wave
  int arow = n0 + (lane & 15);
  if (arow > NN - 1) arow = NN - 1;      // clamp for loads; stores guarded
  const _Float16* gbase = (const _Float16*)g1h + (size_t)arow * HH + (lane >> 4) * 8;
  const f16x8* bbase = (const f16x8*)Bp + lane;   // + (kt*4+ct)*64

  f32x4 acc0 = {0.f,0.f,0.f,0.f}, acc1 = {0.f,0.f,0.f,0.f};
  f32x4 acc2 = {0.f,0.f,0.f,0.f}, acc3 = {0.f,0.f,0.f,0.f};
#pragma unroll
  for (int kt = 0; kt < 8; ++kt){
    f16x8 a = *(const f16x8*)(gbase + kt * 32);
    acc0 = __builtin_amdgcn_mfma_f32_16x16x32_f16(a, bbase[(kt*4 + 0) * 64], acc0, 0, 0, 0);
    acc1 = __builtin_amdgcn_mfma_f32_16x16x32_f16(a, bbase[(kt*4 + 1) * 64], acc1, 0, 0, 0);
    acc2 = __builtin_amdgcn_mfma_f32_16x16x32_f16(a, bbase[(kt*4 + 2) * 64], acc2, 0, 0, 0);
    acc3 = __builtin_amdgcn_mfma_f32_16x16x32_f16(a, bbase[(kt*4 + 3) * 64], acc3, 0, 0, 0);
  }
  int c4 = lane & 15, g4 = lane >> 4;
  float as2v0 = as2[c4], as2v1 = as2[16 + c4], as2v2 = as2[32 + c4], as2v3 = as2[48 + c4];
  float ad2v0 = ad2[c4], ad2v1 = ad2[16 + c4], ad2v2 = ad2[32 + c4], ad2v3 = ad2[48 + c4];
  float vs[4], vd[4];
#pragma unroll
  for (int i = 0; i < 4; ++i){
    int n = n0 + g4 * 4 + i;
    if (n < NN){
      h2h[(size_t)n * HID + c4]      = (__half)acc0[i];
      h2h[(size_t)n * HID + 16 + c4] = (__half)acc1[i];
      h2h[(size_t)n * HID + 32 + c4] = (__half)acc2[i];
      h2h[(size_t)n * HID + 48 + c4] = (__half)acc3[i];
    }
    vs[i] = acc0[i]*as2v0 + acc1[i]*as2v1 + acc2[i]*as2v2 + acc3[i]*as2v3;
    vd[i] = acc0[i]*ad2v0 + acc1[i]*ad2v1 + acc2[i]*ad2v2 + acc3[i]*ad2v3;
  }
#pragma unroll
  for (int off = 1; off < 16; off <<= 1){
#pragma unroll
    for (int i = 0; i < 4; ++i){
      vs[i] += __shfl_xor(vs[i], off);
      vd[i] += __shfl_xor(vd[i], off);
    }
  }
  if (c4 == 0){
#pragma unroll
    for (int i = 0; i < 4; ++i){
      int n = n0 + g4 * 4 + i;
      if (n < NN){ als2[n] = vs[i]; ald2[n] = vd[i]; }
    }
  }
}

// ---------- fused layer-2 softmax weights + gather + ELU + hW (wave per node) ----------
__global__ void k_agg2m(const int* __restrict__ rs, const int* __restrict__ csr,
                        const __half* __restrict__ h2h, const float* __restrict__ als,
                        const float* __restrict__ ald, const float* __restrict__ b2,
                        const float* __restrict__ clW1, float* __restrict__ hW){
  __shared__ float os[4][64];
  int t = threadIdx.x, wv = t >> 6, lane = t & 63;
  int g16 = lane >> 4, c4 = lane & 15;
  int n = blockIdx.x * 4 + wv;
  int e0 = rs[n], e1 = rs[n + 1];
  int deg = e1 - e0;
  float adn = ald[n];

  float wr = 0.f; int sr = 0;
  float den = 0.f;
  if (lane < deg){ sr = csr[e0 + lane]; wr = expf(lrelu(als[sr] + adn)); den = wr; }
  for (int e = e0 + 64 + lane; e < e1; e += 64) den += expf(lrelu(als[csr[e]] + adn));
#pragma unroll
  for (int off = 1; off <= 32; off <<= 1) den += __shfl_xor(den, off);
  float selfw = expf(lrelu(als[n] + adn));
  float inv = 1.f / (den + selfw + 1e-16f);
  float wself = selfw * inv;

  float a0 = 0.f, a1 = 0.f, a2 = 0.f, a3 = 0.f;
  int cnt = deg < 64 ? deg : 64;
  for (int base = 0; base < cnt; base += 8){    // uniform trip count; shfl legal
    int idx = base + g16;
    int  i1 = (idx < cnt) ? idx : 0;
    float wa = ((idx < cnt) ? inv : 0.f) * __shfl(wr, i1);
    int   sa = __shfl(sr, i1);
    int idxb = idx + 4;
    int  i2 = (idxb < cnt) ? idxb : 0;
    float wb = ((idxb < cnt) ? inv : 0.f) * __shfl(wr, i2);
    int   sb = __shfl(sr, i2);
    float2 r0 = *(const float2*)(h2h + (size_t)sa * HID + c4 * 4);
    float2 r1 = *(const float2*)(h2h + (size_t)sb * HID + c4 * 4);
    float f0,f1,f2,f3;
    unp4(r0, f0,f1,f2,f3); a0=fmaf(wa,f0,a0); a1=fmaf(wa,f1,a1); a2=fmaf(wa,f2,a2); a3=fmaf(wa,f3,a3);
    unp4(r1, f0,f1,f2,f3); a0=fmaf(wb,f0,a0); a1=fmaf(wb,f1,a1); a2=fmaf(wb,f2,a2); a3=fmaf(wb,f3,a3);
  }
  // rare tail: deg > 64, recompute (no cross-lane ops -> divergence safe)
  for (int e = e0 + 64 + g16; e < e1; e += 4){
    int s = csr[e];
    float w = inv * expf(lrelu(als[s] + adn));
    float2 r = *(const float2*)(h2h + (size_t)s * HID + c4 * 4);
    float f0,f1,f2,f3; unp4(r, f0,f1,f2,f3);
    a0=fmaf(w,f0,a0); a1=fmaf(w,f1,a1); a2=fmaf(w,f2,a2); a3=fmaf(w,f3,a3);
  }

  a0 += __shfl_xor(a0, 16); a1 += __shfl_xor(a1, 16); a2 += __shfl_xor(a2, 16); a3 += __shfl_xor(a3, 16);
  a0 += __shfl_xor(a0, 32); a1 += __shfl_xor(a1, 32); a2 += __shfl_xor(a2, 32); a3 += __shfl_xor(a3, 32);
  if (lane < 16){
    float2 r = *(const float2*)(h2h + (size_t)n * HID + lane * 4);
    float f0,f1,f2,f3; unp4(r, f0,f1,f2,f3);
    a0 = fmaf(wself, f0, a0); a1 = fmaf(wself, f1, a1); a2 = fmaf(wself, f2, a2); a3 = fmaf(wself, f3, a3);
    float4 b4 = *(const float4*)(b2 + lane * 4);
    float4 o;
    o.x = elu_(a0 + b4.x); o.y = elu_(a1 + b4.y); o.z = elu_(a2 + b4.z); o.w = elu_(a3 + b4.w);
    *(float4*)(&os[wv][lane * 4]) = o;
  }
  __syncthreads();
  float acc = 0.f;
  const float* o = os[wv];
  for (int k = 0; k < HID; ++k) acc = fmaf(o[k], clW1[k * HID + lane], acc);
  hW[(size_t)n * HID + lane] = acc;
}

// ---------- task encoder + fold classifier bias ----------
__global__ void k_task(const float* __restrict__ task, const float* __restrict__ W1t,
                       const float* __restrict__ b1t, const float* __restrict__ W2t,
                       const float* __restrict__ b2t, const float* __restrict__ clW1,
                       const float* __restrict__ clb1, float* __restrict__ tWb){
  __shared__ float t1[16][64];
  __shared__ float t2[16][64];
  int t = threadIdx.x;
  for (int idx = t; idx < 1024; idx += 256){
    int b = idx >> 6, c = idx & 63;
    float acc = b1t[c];
    for (int k = 0; k < 128; ++k) acc = fmaf(task[b*128 + k], W1t[k*64 + c], acc);
    t1[b][c] = fmaxf(acc, 0.f);
  }
  __syncthreads();
  for (int idx = t; idx < 1024; idx += 256){
    int b = idx >> 6, c = idx & 63;
    float acc = b2t[c];
    for (int k = 0; k < 64; ++k) acc = fmaf(t1[b][k], W2t[k*64 + c], acc);
    t2[b][c] = acc;
  }
  __syncthreads();
  for (int idx = t; idx < 1024; idx += 256){
    int b = idx >> 6, c = idx & 63;
    float acc = clb1[c];
    for (int k = 0; k < 64; ++k) acc = fmaf(t2[b][k], clW1[(64 + k)*64 + c], acc);
    tWb[idx] = acc;
  }
}

// ---------- scores[b,n] = sum_k relu(hW[n,k] + tWb[b,k]) * w2[k] + cl_b2 ----------
__global__ void k_scores(const float* __restrict__ hW, const float* __restrict__ tWb,
                         const float* __restrict__ w2, const float* __restrict__ b2s,
                         float* __restrict__ out){
  __shared__ float tw[16][64];
  __shared__ float w2s[64];
  int t = threadIdx.x;
  for (int i = t; i < 1024; i += 256) tw[i >> 6][i & 63] = tWb[i];
  if (t < 64) w2s[t] = w2[t];
  __syncthreads();
  int wv = t >> 6, lane = t & 63;
  int n = blockIdx.x * 4 + wv;
  float hv = hW[n * 64 + lane];
  float bias = b2s[0];
  for (int b = 0; b < 16; ++b){
    float v = fmaxf(hv + tw[b][lane], 0.f) * w2s[lane];
#pragma unroll
    for (int off = 32; off > 0; off >>= 1) v += __shfl_xor(v, off);
    if (lane == b) out[b * NN + n] = v + bias;
  }
}

extern "C" void kernel_launch(void* const* d_in, const int* in_sizes, int n_in,
                              void* d_out, int out_size, void* d_ws, size_t ws_size,
                              hipStream_t stream){
  const float* x    = (const float*)d_in[0];
  const int*   ei   = (const int*)  d_in[1];
  const float* task = (const float*)d_in[2];
  const float* W1   = (const float*)d_in[3];
  const float* as1  = (const float*)d_in[4];
  const float* ad1  = (const float*)d_in[5];
  const float* b1   = (const float*)d_in[6];
  const float* W2   = (const float*)d_in[7];
  const float* as2  = (const float*)d_in[8];
  const float* ad2  = (const float*)d_in[9];
  const float* b2   = (const float*)d_in[10];
  const float* teW1 = (const float*)d_in[11];
  const float* teb1 = (const float*)d_in[12];
  const float* teW2 = (const float*)d_in[13];
  const float* teb2 = (const float*)d_in[14];
  const float* clW1 = (const float*)d_in[15];
  const float* clb1 = (const float*)d_in[16];
  const float* clW2 = (const float*)d_in[17];
  const float* clb2 = (const float*)d_in[18];
  float* out = (float*)d_out;
  float* ws  = (float*)d_ws;

  // workspace layout (float-sized slots; w1/wself regions retained but unused)
  __half* h1h  = (__half*)ws;                 // 12.8M halfs -> 6.4M floats
  float* als1  = ws + 6400000;                // 200,000
  float* ald1  = als1 + 200000;               // 200,000
  __half* g1h  = (__half*)(ws + 6400000 + 400000 + 3400000);  // after (unused) w1+wself1
  __half* h2h  = (__half*)(ws + 6400000 + 400000 + 3400000 + 6400000);
  float* als2  = ws + 6400000 + 400000 + 3400000 + 6400000 + 1600000;
  float* ald2  = als2 + 50000;                // 50,000
  float* hW    = ald2 + 50000 + 850000;       // after (unused) w2c+wself2
  float* tWb   = hW + 3200000;                // 1,024
  int*   deg   = (int*)(tWb + 1024);          // 50,000
  int*   rs    = deg + 50000;                 // 50,001 (+pad)
  int*   cur   = rs + 50004;                  // 50,000
  int*   csr   = cur + 50000;                 // 800,000
  int*   psum  = csr + 800000;                // 256
  int*   pofs  = psum + 256;                  // 256
  __half* Bp   = (__half*)(pofs + 256);       // 16,384 halfs (MFMA-ordered W2)
  __half* Bp1  = Bp + 16384;                  // 32,768 halfs (MFMA-ordered W1)

  // CSR build (parallel scan)
  hipMemsetAsync(deg, 0, 50000 * sizeof(int), stream);
  k_deg    <<<(NE + 255)/256, 256, 0, stream>>>(ei, deg);
  k_psum   <<<196, 256, 0, stream>>>(deg, psum);
  k_pscan  <<<1, 256, 0, stream>>>(psum, pofs);
  k_wroffs <<<196, 256, 0, stream>>>(deg, pofs, rs, cur);
  k_scatter<<<(NE + 255)/256, 256, 0, stream>>>(ei, cur, csr);

  // weight prep (both GEMM weight permutations)
  k_prep   <<<24, 256, 0, stream>>>(W2, W1, Bp, Bp1);

  // layer 1
  k_gemm1m<<<(NN + 63)/64, 256, 0, stream>>>(x, Bp1, as1, ad1, h1h, als1, ald1);
  k_agg1m <<<12500, 256, 0, stream>>>(rs, csr, h1h, als1, ald1, b1, g1h);
  k_gemm2m<<<(NN + 63)/64, 256, 0, stream>>>(g1h, Bp, as2, ad2, h2h, als2, ald2);

  // layer 2
  k_agg2m <<<12500, 256, 0, stream>>>(rs, csr, h2h, als2, ald2, b2, clW1, hW);

  // task encoder + classifier
  k_task  <<<1, 256, 0, stream>>>(task, teW1, teb1, teW2, teb2, clW1, clb1, tWb);
  k_scores<<<12500, 256, 0, stream>>>(hW, tWb, clW2, clb2, out);
}

// Round 9
// 311.927 us; speedup vs baseline: 4.3277x; 1.0474x over previous
//
#include <hip/hip_runtime.h>
#include <hip/hip_fp16.h>

#define NN 50000
#define NE 800000
#define FN 128
#define HH 256      // HEADS*HID
#define HID 64

typedef _Float16 f16x8 __attribute__((ext_vector_type(8)));
typedef float f32x4 __attribute__((ext_vector_type(4)));

__device__ __forceinline__ float lrelu(float v){ return v >= 0.f ? v : 0.2f * v; }
__device__ __forceinline__ float elu_(float v){ return v > 0.f ? v : expm1f(v); }

__device__ __forceinline__ void unp4(const float2 r, float& f0, float& f1, float& f2, float& f3){
  const __half2* hp = (const __half2*)&r;
  float2 a = __half22float2(hp[0]);
  float2 b = __half22float2(hp[1]);
  f0 = a.x; f1 = a.y; f2 = b.x; f3 = b.y;
}

// ---------- merged: deg histogram + weight prep + task encoder ----------
__global__ void k_misc(const int* __restrict__ ei, int* __restrict__ deg,
                       const float* __restrict__ W2, const float* __restrict__ W1,
                       __half* __restrict__ Bp, __half* __restrict__ Bp1,
                       const float* __restrict__ task, const float* __restrict__ W1t,
                       const float* __restrict__ b1t, const float* __restrict__ W2t,
                       const float* __restrict__ b2t, const float* __restrict__ clW1,
                       const float* __restrict__ clb1, float* __restrict__ tWb){
  int bid = blockIdx.x, t = threadIdx.x;
  if (bid < 3125){                       // k_deg: 3125*256 == NE
    int e = bid * 256 + t;
    atomicAdd(deg + ei[NE + e], 1);
  } else if (bid < 3149){                // k_prep: 24 blocks
    int f = (bid - 3125) * 256 + t;
    if (f < 2048){
      int lane = f & 63;
      int ct = (f >> 6) & 3, kt = f >> 8;
      int kbase = kt * 32 + (lane >> 4) * 8;
      int col = ct * 16 + (lane & 15);
#pragma unroll
      for (int i = 0; i < 8; ++i)
        Bp[(size_t)f * 8 + i] = (__half)W2[(kbase + i) * HID + col];
    } else if (f < 6144){
      int g = f - 2048;
      int lane = g & 63;
      int ct = (g >> 6) & 15, kt = g >> 10;
      int kbase = kt * 32 + (lane >> 4) * 8;
      int col = ct * 16 + (lane & 15);
#pragma unroll
      for (int i = 0; i < 8; ++i)
        Bp1[(size_t)g * 8 + i] = (__half)W1[(kbase + i) * HH + col];
    }
  } else {                               // k_task: 1 block
    __shared__ float t1[16][64];
    __shared__ float t2[16][64];
    for (int idx = t; idx < 1024; idx += 256){
      int b = idx >> 6, c = idx & 63;
      float acc = b1t[c];
      for (int k = 0; k < 128; ++k) acc = fmaf(task[b*128 + k], W1t[k*64 + c], acc);
      t1[b][c] = fmaxf(acc, 0.f);
    }
    __syncthreads();
    for (int idx = t; idx < 1024; idx += 256){
      int b = idx >> 6, c = idx & 63;
      float acc = b2t[c];
      for (int k = 0; k < 64; ++k) acc = fmaf(t1[b][k], W2t[k*64 + c], acc);
      t2[b][c] = acc;
    }
    __syncthreads();
    for (int idx = t; idx < 1024; idx += 256){
      int b = idx >> 6, c = idx & 63;
      float acc = clb1[c];
      for (int k = 0; k < 64; ++k) acc = fmaf(t2[b][k], clW1[(64 + k)*64 + c], acc);
      tWb[idx] = acc;
    }
  }
}

__global__ void k_psum(const int* __restrict__ deg, int* __restrict__ psum){
  int b = blockIdx.x, t = threadIdx.x;
  int idx = b * 256 + t;
  int v = (idx < NN) ? deg[idx] : 0;
#pragma unroll
  for (int off = 32; off > 0; off >>= 1) v += __shfl_down(v, off);
  __shared__ int wsum[4];
  if ((t & 63) == 0) wsum[t >> 6] = v;
  __syncthreads();
  if (t == 0) psum[b] = wsum[0] + wsum[1] + wsum[2] + wsum[3];
}

__global__ void k_pscan(const int* __restrict__ psum, int* __restrict__ pofs){
  int t = threadIdx.x;            // 256 threads
  int lane = t & 63, wv = t >> 6;
  int v = (t < 196) ? psum[t] : 0;
  int iv = v;
#pragma unroll
  for (int off = 1; off < 64; off <<= 1){
    int u = __shfl_up(iv, off);
    if (lane >= off) iv += u;
  }
  __shared__ int wsum[4];
  if (lane == 63) wsum[wv] = iv;
  __syncthreads();
  int add = 0;
  for (int w = 0; w < wv; ++w) add += wsum[w];
  iv += add;
  if (t < 196) pofs[t] = iv - v;  // exclusive
}

__global__ void k_wroffs(const int* __restrict__ deg, const int* __restrict__ pofs,
                         int* __restrict__ rs, int* __restrict__ cur){
  int b = blockIdx.x, t = threadIdx.x;
  int idx = b * 256 + t;
  int lane = t & 63, wv = t >> 6;
  int v = (idx < NN) ? deg[idx] : 0;
  int iv = v;
#pragma unroll
  for (int off = 1; off < 64; off <<= 1){
    int u = __shfl_up(iv, off);
    if (lane >= off) iv += u;
  }
  __shared__ int wsum[4];
  if (lane == 63) wsum[wv] = iv;
  __syncthreads();
  int add = pofs[b];
  for (int w = 0; w < wv; ++w) add += wsum[w];
  int excl = add + iv - v;
  if (idx < NN){ rs[idx] = excl; cur[idx] = excl; }
  if (idx == NN) rs[NN] = excl;
}

// ---------- merged: csr scatter + (h1 = x @ W1 MFMA, fused alpha1) ----------
__global__ void k_scatgemm(const int* __restrict__ ei, int* __restrict__ cur, int* __restrict__ csr,
                           const float* __restrict__ x, const __half* __restrict__ Bp1,
                           const float* __restrict__ as1, const float* __restrict__ ad1,
                           __half* __restrict__ h1h, float* __restrict__ als, float* __restrict__ ald){
  int bid = blockIdx.x, t = threadIdx.x;
  if (bid < 3125){                        // scatter: 3125*256 == NE
    int e = bid * 256 + t;
    int s = ei[e], d = ei[NE + e];
    int pos = atomicAdd(cur + d, 1);
    csr[pos] = s;
    return;
  }
  // gemm1m part
  int blk = bid - 3125;
  int wv = t >> 6, lane = t & 63;
  int n0 = blk * 64 + wv * 16;           // 16 rows per wave
  int arow = n0 + (lane & 15);
  if (arow > NN - 1) arow = NN - 1;      // clamp for loads; stores guarded
  const float* xbase = x + (size_t)arow * FN + (lane >> 4) * 8;
  const f16x8* bbase = (const f16x8*)Bp1 + lane;   // + (kt*16+ct)*64

  f32x4 acc[16];
#pragma unroll
  for (int ct = 0; ct < 16; ++ct) acc[ct] = (f32x4){0.f,0.f,0.f,0.f};

#pragma unroll
  for (int kt = 0; kt < 4; ++kt){
    float4 xa = *(const float4*)(xbase + kt * 32);
    float4 xb = *(const float4*)(xbase + kt * 32 + 4);
    f16x8 a;
    a[0] = (_Float16)xa.x; a[1] = (_Float16)xa.y; a[2] = (_Float16)xa.z; a[3] = (_Float16)xa.w;
    a[4] = (_Float16)xb.x; a[5] = (_Float16)xb.y; a[6] = (_Float16)xb.z; a[7] = (_Float16)xb.w;
#pragma unroll
    for (int ct = 0; ct < 16; ++ct)
      acc[ct] = __builtin_amdgcn_mfma_f32_16x16x32_f16(a, bbase[(kt*16 + ct) * 64], acc[ct], 0, 0, 0);
  }

  // C/D mapping: col = ct*16 + (lane&15), row = (lane>>4)*4 + i
  int c4 = lane & 15, g4 = lane >> 4;
#pragma unroll
  for (int ct = 0; ct < 16; ++ct){
#pragma unroll
    for (int i = 0; i < 4; ++i){
      int n = n0 + g4 * 4 + i;
      if (n < NN) h1h[(size_t)n * HH + ct * 16 + c4] = (__half)acc[ct][i];
    }
  }
#pragma unroll
  for (int h = 0; h < 4; ++h){
    float sa0 = as1[(h*4+0)*16 + c4], sa1 = as1[(h*4+1)*16 + c4];
    float sa2 = as1[(h*4+2)*16 + c4], sa3 = as1[(h*4+3)*16 + c4];
    float da0 = ad1[(h*4+0)*16 + c4], da1 = ad1[(h*4+1)*16 + c4];
    float da2 = ad1[(h*4+2)*16 + c4], da3 = ad1[(h*4+3)*16 + c4];
#pragma unroll
    for (int i = 0; i < 4; ++i){
      float vs = acc[h*4+0][i]*sa0 + acc[h*4+1][i]*sa1 + acc[h*4+2][i]*sa2 + acc[h*4+3][i]*sa3;
      float vd = acc[h*4+0][i]*da0 + acc[h*4+1][i]*da1 + acc[h*4+2][i]*da2 + acc[h*4+3][i]*da3;
#pragma unroll
      for (int off = 1; off < 16; off <<= 1){
        vs += __shfl_xor(vs, off);
        vd += __shfl_xor(vd, off);
      }
      if (c4 == 0){
        int n = n0 + g4 * 4 + i;
        if (n < NN){ als[n*4 + h] = vs; ald[n*4 + h] = vd; }
      }
    }
  }
}

// ---------- fused layer-1 softmax weights + gather + ELU (wave per node) ----------
__global__ void k_agg1m(const int* __restrict__ rs, const int* __restrict__ csr,
                        const __half* __restrict__ h1h, const float* __restrict__ als,
                        const float* __restrict__ ald, const float* __restrict__ b1,
                        __half* __restrict__ g1h){
  int t = threadIdx.x, wv = t >> 6, lane = t & 63;
  int head = lane >> 4, q = lane & 15;
  int n = blockIdx.x * 4 + wv;
  int e0 = rs[n], e1 = rs[n + 1];
  int deg = e1 - e0;
  float adh = ald[n*4 + head];

  float w0r = 0.f, w1r = 0.f, w2r = 0.f, w3r = 0.f;
  int   s0r = 0,   s1r = 0,   s2r = 0,   s3r = 0;
  float den = 0.f;
  if (q      < deg){ s0r = csr[e0 + q];      w0r = expf(lrelu(als[s0r*4+head] + adh)); den += w0r; }
  if (q + 16 < deg){ s1r = csr[e0 + 16 + q]; w1r = expf(lrelu(als[s1r*4+head] + adh)); den += w1r; }
  if (q + 32 < deg){ s2r = csr[e0 + 32 + q]; w2r = expf(lrelu(als[s2r*4+head] + adh)); den += w2r; }
  if (q + 48 < deg){ s3r = csr[e0 + 48 + q]; w3r = expf(lrelu(als[s3r*4+head] + adh)); den += w3r; }
  for (int e = e0 + 64 + q; e < e1; e += 16) den += expf(lrelu(als[csr[e]*4+head] + adh));
  den += __shfl_xor(den, 1); den += __shfl_xor(den, 2);
  den += __shfl_xor(den, 4); den += __shfl_xor(den, 8);
  float selfw = expf(lrelu(als[n*4+head] + adh));
  float inv = 1.f / (den + selfw + 1e-16f);
  float wself = selfw * inv;

  float a0, a1, a2, a3;
  { float2 r = *(const float2*)(h1h + (size_t)n * HH + lane * 4);
    float f0,f1,f2,f3; unp4(r, f0,f1,f2,f3);
    a0 = wself*f0; a1 = wself*f1; a2 = wself*f2; a3 = wself*f3; }

  int hb = lane & 48;
  int cnt = deg < 64 ? deg : 64;
  auto pass = [&](float wp, int sp, int off){
    int lim = cnt - off; if (lim <= 0) return; if (lim > 16) lim = 16;
    for (int q2 = 0; q2 < lim; q2 += 4){          // wave-uniform trip count
      int j1 = q2 + 1, j2 = q2 + 2, j3 = q2 + 3;
      float m1 = (j1 < lim) ? inv : 0.f; if (j1 >= lim) j1 = q2;
      float m2 = (j2 < lim) ? inv : 0.f; if (j2 >= lim) j2 = q2;
      float m3 = (j3 < lim) ? inv : 0.f; if (j3 >= lim) j3 = q2;
      float wa = inv * __shfl(wp, hb + q2); int sa = __shfl(sp, hb + q2);
      float wb = m1  * __shfl(wp, hb + j1); int sb = __shfl(sp, hb + j1);
      float wc = m2  * __shfl(wp, hb + j2); int sc = __shfl(sp, hb + j2);
      float wd = m3  * __shfl(wp, hb + j3); int sd = __shfl(sp, hb + j3);
      float2 ra = *(const float2*)(h1h + (size_t)sa * HH + lane * 4);
      float2 rb = *(const float2*)(h1h + (size_t)sb * HH + lane * 4);
      float2 rc = *(const float2*)(h1h + (size_t)sc * HH + lane * 4);
      float2 rd = *(const float2*)(h1h + (size_t)sd * HH + lane * 4);
      float f0,f1,f2,f3;
      unp4(ra, f0,f1,f2,f3); a0=fmaf(wa,f0,a0); a1=fmaf(wa,f1,a1); a2=fmaf(wa,f2,a2); a3=fmaf(wa,f3,a3);
      unp4(rb, f0,f1,f2,f3); a0=fmaf(wb,f0,a0); a1=fmaf(wb,f1,a1); a2=fmaf(wb,f2,a2); a3=fmaf(wb,f3,a3);
      unp4(rc, f0,f1,f2,f3); a0=fmaf(wc,f0,a0); a1=fmaf(wc,f1,a1); a2=fmaf(wc,f2,a2); a3=fmaf(wc,f3,a3);
      unp4(rd, f0,f1,f2,f3); a0=fmaf(wd,f0,a0); a1=fmaf(wd,f1,a1); a2=fmaf(wd,f2,a2); a3=fmaf(wd,f3,a3);
    }
  };
  pass(w0r, s0r, 0); pass(w1r, s1r, 16); pass(w2r, s2r, 32); pass(w3r, s3r, 48);
  // rare tail: deg > 64, recompute weights directly (uniform loop)
  for (int e = e0 + 64; e < e1; ++e){
    int s = csr[e];
    float w = inv * expf(lrelu(als[s*4+head] + adh));
    float2 r = *(const float2*)(h1h + (size_t)s * HH + lane * 4);
    float f0,f1,f2,f3; unp4(r, f0,f1,f2,f3);
    a0=fmaf(w,f0,a0); a1=fmaf(w,f1,a1); a2=fmaf(w,f2,a2); a3=fmaf(w,f3,a3);
  }

  float4 b4 = *(const float4*)(b1 + lane * 4);
  __half2 p0 = __floats2half2_rn(elu_(a0 + b4.x), elu_(a1 + b4.y));
  __half2 p1 = __floats2half2_rn(elu_(a2 + b4.z), elu_(a3 + b4.w));
  float2 outv; ((__half2*)&outv)[0] = p0; ((__half2*)&outv)[1] = p1;
  *(float2*)(g1h + (size_t)n * HH + lane * 4) = outv;
}

// ---------- h2 = g1 @ W2 via MFMA 16x16x32_f16, fused alpha2 ----------
__global__ void k_gemm2m(const __half* __restrict__ g1h, const __half* __restrict__ Bp,
                         const float* __restrict__ as2, const float* __restrict__ ad2,
                         __half* __restrict__ h2h, float* __restrict__ als2, float* __restrict__ ald2){
  int t = threadIdx.x, wv = t >> 6, lane = t & 63;
  int n0 = blockIdx.x * 64 + wv * 16;    // 16 rows per wave
  int arow = n0 + (lane & 15);
  if (arow > NN - 1) arow = NN - 1;      // clamp for loads; stores guarded
  const _Float16* gbase = (const _Float16*)g1h + (size_t)arow * HH + (lane >> 4) * 8;
  const f16x8* bbase = (const f16x8*)Bp + lane;   // + (kt*4+ct)*64

  f32x4 acc0 = {0.f,0.f,0.f,0.f}, acc1 = {0.f,0.f,0.f,0.f};
  f32x4 acc2 = {0.f,0.f,0.f,0.f}, acc3 = {0.f,0.f,0.f,0.f};
#pragma unroll
  for (int kt = 0; kt < 8; ++kt){
    f16x8 a = *(const f16x8*)(gbase + kt * 32);
    acc0 = __builtin_amdgcn_mfma_f32_16x16x32_f16(a, bbase[(kt*4 + 0) * 64], acc0, 0, 0, 0);
    acc1 = __builtin_amdgcn_mfma_f32_16x16x32_f16(a, bbase[(kt*4 + 1) * 64], acc1, 0, 0, 0);
    acc2 = __builtin_amdgcn_mfma_f32_16x16x32_f16(a, bbase[(kt*4 + 2) * 64], acc2, 0, 0, 0);
    acc3 = __builtin_amdgcn_mfma_f32_16x16x32_f16(a, bbase[(kt*4 + 3) * 64], acc3, 0, 0, 0);
  }
  int c4 = lane & 15, g4 = lane >> 4;
  float as2v0 = as2[c4], as2v1 = as2[16 + c4], as2v2 = as2[32 + c4], as2v3 = as2[48 + c4];
  float ad2v0 = ad2[c4], ad2v1 = ad2[16 + c4], ad2v2 = ad2[32 + c4], ad2v3 = ad2[48 + c4];
  float vs[4], vd[4];
#pragma unroll
  for (int i = 0; i < 4; ++i){
    int n = n0 + g4 * 4 + i;
    if (n < NN){
      h2h[(size_t)n * HID + c4]      = (__half)acc0[i];
      h2h[(size_t)n * HID + 16 + c4] = (__half)acc1[i];
      h2h[(size_t)n * HID + 32 + c4] = (__half)acc2[i];
      h2h[(size_t)n * HID + 48 + c4] = (__half)acc3[i];
    }
    vs[i] = acc0[i]*as2v0 + acc1[i]*as2v1 + acc2[i]*as2v2 + acc3[i]*as2v3;
    vd[i] = acc0[i]*ad2v0 + acc1[i]*ad2v1 + acc2[i]*ad2v2 + acc3[i]*ad2v3;
  }
#pragma unroll
  for (int off = 1; off < 16; off <<= 1){
#pragma unroll
    for (int i = 0; i < 4; ++i){
      vs[i] += __shfl_xor(vs[i], off);
      vd[i] += __shfl_xor(vd[i], off);
    }
  }
  if (c4 == 0){
#pragma unroll
    for (int i = 0; i < 4; ++i){
      int n = n0 + g4 * 4 + i;
      if (n < NN){ als2[n] = vs[i]; ald2[n] = vd[i]; }
    }
  }
}

// ---------- fused layer-2 weights + gather + ELU + hW + SCORES (wave per node) ----------
__global__ void k_agg2s(const int* __restrict__ rs, const int* __restrict__ csr,
                        const __half* __restrict__ h2h, const float* __restrict__ als,
                        const float* __restrict__ ald, const float* __restrict__ b2,
                        const float* __restrict__ clW1, const float* __restrict__ tWb,
                        const float* __restrict__ w2, const float* __restrict__ b2s,
                        float* __restrict__ out){
  __shared__ float os[4][64];
  __shared__ float tw[16][64];
  __shared__ float w2s[64];
  int t = threadIdx.x, wv = t >> 6, lane = t & 63;
  for (int i = t; i < 1024; i += 256) tw[i >> 6][i & 63] = tWb[i];
  if (t < 64) w2s[t] = w2[t];

  int g16 = lane >> 4, c4 = lane & 15;
  int n = blockIdx.x * 4 + wv;
  int e0 = rs[n], e1 = rs[n + 1];
  int deg = e1 - e0;
  float adn = ald[n];

  float wr = 0.f; int sr = 0;
  float den = 0.f;
  if (lane < deg){ sr = csr[e0 + lane]; wr = expf(lrelu(als[sr] + adn)); den = wr; }
  for (int e = e0 + 64 + lane; e < e1; e += 64) den += expf(lrelu(als[csr[e]] + adn));
#pragma unroll
  for (int off = 1; off <= 32; off <<= 1) den += __shfl_xor(den, off);
  float selfw = expf(lrelu(als[n] + adn));
  float inv = 1.f / (den + selfw + 1e-16f);
  float wself = selfw * inv;

  float a0 = 0.f, a1 = 0.f, a2 = 0.f, a3 = 0.f;
  int cnt = deg < 64 ? deg : 64;
  for (int base = 0; base < cnt; base += 8){    // uniform trip count; shfl legal
    int idx = base + g16;
    int  i1 = (idx < cnt) ? idx : 0;
    float wa = ((idx < cnt) ? inv : 0.f) * __shfl(wr, i1);
    int   sa = __shfl(sr, i1);
    int idxb = idx + 4;
    int  i2 = (idxb < cnt) ? idxb : 0;
    float wb = ((idxb < cnt) ? inv : 0.f) * __shfl(wr, i2);
    int   sb = __shfl(sr, i2);
    float2 r0 = *(const float2*)(h2h + (size_t)sa * HID + c4 * 4);
    float2 r1 = *(const float2*)(h2h + (size_t)sb * HID + c4 * 4);
    float f0,f1,f2,f3;
    unp4(r0, f0,f1,f2,f3); a0=fmaf(wa,f0,a0); a1=fmaf(wa,f1,a1); a2=fmaf(wa,f2,a2); a3=fmaf(wa,f3,a3);
    unp4(r1, f0,f1,f2,f3); a0=fmaf(wb,f0,a0); a1=fmaf(wb,f1,a1); a2=fmaf(wb,f2,a2); a3=fmaf(wb,f3,a3);
  }
  // rare tail: deg > 64, recompute (no cross-lane ops -> divergence safe)
  for (int e = e0 + 64 + g16; e < e1; e += 4){
    int s = csr[e];
    float w = inv * expf(lrelu(als[s] + adn));
    float2 r = *(const float2*)(h2h + (size_t)s * HID + c4 * 4);
    float f0,f1,f2,f3; unp4(r, f0,f1,f2,f3);
    a0=fmaf(w,f0,a0); a1=fmaf(w,f1,a1); a2=fmaf(w,f2,a2); a3=fmaf(w,f3,a3);
  }

  a0 += __shfl_xor(a0, 16); a1 += __shfl_xor(a1, 16); a2 += __shfl_xor(a2, 16); a3 += __shfl_xor(a3, 16);
  a0 += __shfl_xor(a0, 32); a1 += __shfl_xor(a1, 32); a2 += __shfl_xor(a2, 32); a3 += __shfl_xor(a3, 32);
  if (lane < 16){
    float2 r = *(const float2*)(h2h + (size_t)n * HID + lane * 4);
    float f0,f1,f2,f3; unp4(r, f0,f1,f2,f3);
    a0 = fmaf(wself, f0, a0); a1 = fmaf(wself, f1, a1); a2 = fmaf(wself, f2, a2); a3 = fmaf(wself, f3, a3);
    float4 b4 = *(const float4*)(b2 + lane * 4);
    float4 o;
    o.x = elu_(a0 + b4.x); o.y = elu_(a1 + b4.y); o.z = elu_(a2 + b4.z); o.w = elu_(a3 + b4.w);
    *(float4*)(&os[wv][lane * 4]) = o;
  }
  __syncthreads();   // covers os AND tw/w2s
  // hW row in register: hv = sum_k o[k]*clW1[k][lane]
  float hv = 0.f;
  const float* o = os[wv];
  for (int k = 0; k < HID; ++k) hv = fmaf(o[k], clW1[k * HID + lane], hv);
  // fused scores
  float bias = b2s[0];
  for (int b = 0; b < 16; ++b){
    float v = fmaxf(hv + tw[b][lane], 0.f) * w2s[lane];
#pragma unroll
    for (int off = 32; off > 0; off >>= 1) v += __shfl_xor(v, off);
    if (lane == b) out[b * NN + n] = v + bias;
  }
}

extern "C" void kernel_launch(void* const* d_in, const int* in_sizes, int n_in,
                              void* d_out, int out_size, void* d_ws, size_t ws_size,
                              hipStream_t stream){
  const float* x    = (const float*)d_in[0];
  const int*   ei   = (const int*)  d_in[1];
  const float* task = (const float*)d_in[2];
  const float* W1   = (const float*)d_in[3];
  const float* as1  = (const float*)d_in[4];
  const float* ad1  = (const float*)d_in[5];
  const float* b1   = (const float*)d_in[6];
  const float* W2   = (const float*)d_in[7];
  const float* as2  = (const float*)d_in[8];
  const float* ad2  = (const float*)d_in[9];
  const float* b2   = (const float*)d_in[10];
  const float* teW1 = (const float*)d_in[11];
  const float* teb1 = (const float*)d_in[12];
  const float* teW2 = (const float*)d_in[13];
  const float* teb2 = (const float*)d_in[14];
  const float* clW1 = (const float*)d_in[15];
  const float* clb1 = (const float*)d_in[16];
  const float* clW2 = (const float*)d_in[17];
  const float* clb2 = (const float*)d_in[18];
  float* out = (float*)d_out;
  float* ws  = (float*)d_ws;

  // workspace layout (float-sized slots)
  __half* h1h  = (__half*)ws;                 // 12.8M halfs -> 6.4M floats
  float* als1  = ws + 6400000;                // 200,000
  float* ald1  = als1 + 200000;               // 200,000
  __half* g1h  = (__half*)(ws + 6400000 + 400000 + 3400000);
  __half* h2h  = (__half*)(ws + 6400000 + 400000 + 3400000 + 6400000);
  float* als2  = ws + 6400000 + 400000 + 3400000 + 6400000 + 1600000;
  float* ald2  = als2 + 50000;                // 50,000
  float* hW    = ald2 + 50000 + 850000;       // (unused slot kept for layout)
  float* tWb   = hW + 3200000;                // 1,024
  int*   deg   = (int*)(tWb + 1024);          // 50,000
  int*   rs    = deg + 50000;                 // 50,001 (+pad)
  int*   cur   = rs + 50004;                  // 50,000
  int*   csr   = cur + 50000;                 // 800,000
  int*   psum  = csr + 800000;                // 256
  int*   pofs  = psum + 256;                  // 256
  __half* Bp   = (__half*)(pofs + 256);       // 16,384 halfs (MFMA-ordered W2)
  __half* Bp1  = Bp + 16384;                  // 32,768 halfs (MFMA-ordered W1)

  hipMemsetAsync(deg, 0, 50000 * sizeof(int), stream);
  // deg histogram + weight prep + task encoder (independent work, one launch)
  k_misc   <<<3150, 256, 0, stream>>>(ei, deg, W2, W1, Bp, Bp1,
                                      task, teW1, teb1, teW2, teb2, clW1, clb1, tWb);
  k_psum   <<<196, 256, 0, stream>>>(deg, psum);
  k_pscan  <<<1, 256, 0, stream>>>(psum, pofs);
  k_wroffs <<<196, 256, 0, stream>>>(deg, pofs, rs, cur);
  // csr scatter + layer-1 GEMM (independent, one launch)
  k_scatgemm<<<3125 + (NN + 63)/64, 256, 0, stream>>>(ei, cur, csr, x, Bp1,
                                                      as1, ad1, h1h, als1, ald1);
  // layer 1 aggregate
  k_agg1m  <<<12500, 256, 0, stream>>>(rs, csr, h1h, als1, ald1, b1, g1h);
  // layer 2 GEMM
  k_gemm2m <<<(NN + 63)/64, 256, 0, stream>>>(g1h, Bp, as2, ad2, h2h, als2, ald2);
  // layer 2 aggregate + classifier scores
  k_agg2s  <<<12500, 256, 0, stream>>>(rs, csr, h2h, als2, ald2, b2, clW1,
                                       tWb, clW2, clb2, out);
}

// Round 10
// 255.756 us; speedup vs baseline: 5.2782x; 1.2196x over previous
//
#include <hip/hip_runtime.h>
#include <hip/hip_fp16.h>

#define NN 50000
#define NE 800000
#define FN 128
#define HH 256      // HEADS*HID
#define HID 64
#define NBKT 196    // 256-node buckets
#define CHUNK 4000  // edges per bin block; 200*4000 == NE

typedef _Float16 f16x8 __attribute__((ext_vector_type(8)));
typedef float f32x4 __attribute__((ext_vector_type(4)));

__device__ __forceinline__ float lrelu(float v){ return v >= 0.f ? v : 0.2f * v; }
__device__ __forceinline__ float elu_(float v){ return v > 0.f ? v : expm1f(v); }

__device__ __forceinline__ void unp4(const float2 r, float& f0, float& f1, float& f2, float& f3){
  const __half2* hp = (const __half2*)&r;
  float2 a = __half22float2(hp[0]);
  float2 b = __half22float2(hp[1]);
  f0 = a.x; f1 = a.y; f2 = b.x; f3 = b.y;
}

// ---------- merged: deg histogram + weight prep + task encoder ----------
__global__ void k_misc(const int* __restrict__ ei, int* __restrict__ deg,
                       const float* __restrict__ W2, const float* __restrict__ W1,
                       __half* __restrict__ Bp, __half* __restrict__ Bp1,
                       const float* __restrict__ task, const float* __restrict__ W1t,
                       const float* __restrict__ b1t, const float* __restrict__ W2t,
                       const float* __restrict__ b2t, const float* __restrict__ clW1,
                       const float* __restrict__ clb1, float* __restrict__ tWb){
  int bid = blockIdx.x, t = threadIdx.x;
  if (bid < 3125){                       // k_deg: 3125*256 == NE
    int e = bid * 256 + t;
    atomicAdd(deg + ei[NE + e], 1);
  } else if (bid < 3149){                // k_prep: 24 blocks
    int f = (bid - 3125) * 256 + t;
    if (f < 2048){
      int lane = f & 63;
      int ct = (f >> 6) & 3, kt = f >> 8;
      int kbase = kt * 32 + (lane >> 4) * 8;
      int col = ct * 16 + (lane & 15);
#pragma unroll
      for (int i = 0; i < 8; ++i)
        Bp[(size_t)f * 8 + i] = (__half)W2[(kbase + i) * HID + col];
    } else if (f < 6144){
      int g = f - 2048;
      int lane = g & 63;
      int ct = (g >> 6) & 15, kt = g >> 10;
      int kbase = kt * 32 + (lane >> 4) * 8;
      int col = ct * 16 + (lane & 15);
#pragma unroll
      for (int i = 0; i < 8; ++i)
        Bp1[(size_t)g * 8 + i] = (__half)W1[(kbase + i) * HH + col];
    }
  } else {                               // k_task: 1 block
    __shared__ float t1[16][64];
    __shared__ float t2[16][64];
    for (int idx = t; idx < 1024; idx += 256){
      int b = idx >> 6, c = idx & 63;
      float acc = b1t[c];
      for (int k = 0; k < 128; ++k) acc = fmaf(task[b*128 + k], W1t[k*64 + c], acc);
      t1[b][c] = fmaxf(acc, 0.f);
    }
    __syncthreads();
    for (int idx = t; idx < 1024; idx += 256){
      int b = idx >> 6, c = idx & 63;
      float acc = b2t[c];
      for (int k = 0; k < 64; ++k) acc = fmaf(t1[b][k], W2t[k*64 + c], acc);
      t2[b][c] = acc;
    }
    __syncthreads();
    for (int idx = t; idx < 1024; idx += 256){
      int b = idx >> 6, c = idx & 63;
      float acc = clb1[c];
      for (int k = 0; k < 64; ++k) acc = fmaf(t2[b][k], clW1[(64 + k)*64 + c], acc);
      tWb[idx] = acc;
    }
  }
}

__global__ void k_psum(const int* __restrict__ deg, int* __restrict__ psum){
  int b = blockIdx.x, t = threadIdx.x;
  int idx = b * 256 + t;
  int v = (idx < NN) ? deg[idx] : 0;
#pragma unroll
  for (int off = 32; off > 0; off >>= 1) v += __shfl_down(v, off);
  __shared__ int wsum[4];
  if ((t & 63) == 0) wsum[t >> 6] = v;
  __syncthreads();
  if (t == 0) psum[b] = wsum[0] + wsum[1] + wsum[2] + wsum[3];
}

__global__ void k_pscan(const int* __restrict__ psum, int* __restrict__ pofs){
  int t = threadIdx.x;            // 256 threads
  int lane = t & 63, wv = t >> 6;
  int v = (t < 196) ? psum[t] : 0;
  int iv = v;
#pragma unroll
  for (int off = 1; off < 64; off <<= 1){
    int u = __shfl_up(iv, off);
    if (lane >= off) iv += u;
  }
  __shared__ int wsum[4];
  if (lane == 63) wsum[wv] = iv;
  __syncthreads();
  int add = 0;
  for (int w = 0; w < wv; ++w) add += wsum[w];
  iv += add;
  if (t < 196) pofs[t] = iv - v;  // exclusive
}

__global__ void k_wroffs(const int* __restrict__ deg, const int* __restrict__ pofs,
                         int* __restrict__ rs, int* __restrict__ bcur){
  int b = blockIdx.x, t = threadIdx.x;
  int idx = b * 256 + t;
  int lane = t & 63, wv = t >> 6;
  int v = (idx < NN) ? deg[idx] : 0;
  int iv = v;
#pragma unroll
  for (int off = 1; off < 64; off <<= 1){
    int u = __shfl_up(iv, off);
    if (lane >= off) iv += u;
  }
  __shared__ int wsum[4];
  if (lane == 63) wsum[wv] = iv;
  __syncthreads();
  int add = pofs[b];
  for (int w = 0; w < wv; ++w) add += wsum[w];
  int excl = add + iv - v;
  if (idx < NN){
    rs[idx] = excl;
    if ((idx & 255) == 0) bcur[idx >> 8] = excl;   // bucket append cursor
  }
  if (idx == NN) rs[NN] = excl;
}

// ---------- merged: LDS-binned edge partition + (h1 = x @ W1 MFMA, fused alpha1) ----------
__global__ void k_binGemm(const int* __restrict__ ei, int* __restrict__ bcur, int2* __restrict__ pr,
                          const float* __restrict__ x, const __half* __restrict__ Bp1,
                          const float* __restrict__ as1, const float* __restrict__ ad1,
                          __half* __restrict__ h1h, float* __restrict__ als, float* __restrict__ ald){
  __shared__ int hist[NBKT];
  __shared__ int lstart[NBKT];
  __shared__ int gpos[NBKT];
  __shared__ int cnt[NBKT];
  __shared__ int2 stage[CHUNK];          // 32 KB
  int bid = blockIdx.x, t = threadIdx.x;
  if (bid < 200){                        // bin: 200*4000 == NE
    int e_base = bid * CHUNK;
    if (t < NBKT){ hist[t] = 0; cnt[t] = 0; }
    __syncthreads();
    for (int i = t; i < CHUNK; i += 256)
      atomicAdd(&hist[ei[NE + e_base + i] >> 8], 1);
    __syncthreads();
    // exclusive scan of hist (196 values over 4 waves)
    {
      int lane = t & 63, wvi = t >> 6;
      int v = (t < NBKT) ? hist[t] : 0;
      int iv = v;
#pragma unroll
      for (int off = 1; off < 64; off <<= 1){
        int u = __shfl_up(iv, off);
        if (lane >= off) iv += u;
      }
      __shared__ int wsum[4];
      if (lane == 63) wsum[wvi] = iv;
      __syncthreads();
      int add = 0;
      for (int w = 0; w < wvi; ++w) add += wsum[w];
      iv += add;
      if (t < NBKT){
        lstart[t] = iv - v;
        gpos[t] = (v > 0) ? atomicAdd(&bcur[t], v) : 0;
      }
    }
    __syncthreads();
    for (int i = t; i < CHUNK; i += 256){
      int e = e_base + i;
      int s = ei[e], d = ei[NE + e];
      int bb = d >> 8;
      int r = atomicAdd(&cnt[bb], 1);
      stage[lstart[bb] + r] = make_int2(s, d);
    }
    __syncthreads();
    for (int i = t; i < CHUNK; i += 256){
      int2 p = stage[i];
      int bb = p.y >> 8;
      pr[gpos[bb] + (i - lstart[bb])] = p;
    }
    return;
  }
  // gemm1m part
  int blk = bid - 200;
  int wv = t >> 6, lane = t & 63;
  int n0 = blk * 64 + wv * 16;           // 16 rows per wave
  int arow = n0 + (lane & 15);
  if (arow > NN - 1) arow = NN - 1;      // clamp for loads; stores guarded
  const float* xbase = x + (size_t)arow * FN + (lane >> 4) * 8;
  const f16x8* bbase = (const f16x8*)Bp1 + lane;   // + (kt*16+ct)*64

  f32x4 acc[16];
#pragma unroll
  for (int ct = 0; ct < 16; ++ct) acc[ct] = (f32x4){0.f,0.f,0.f,0.f};

#pragma unroll
  for (int kt = 0; kt < 4; ++kt){
    float4 xa = *(const float4*)(xbase + kt * 32);
    float4 xb = *(const float4*)(xbase + kt * 32 + 4);
    f16x8 a;
    a[0] = (_Float16)xa.x; a[1] = (_Float16)xa.y; a[2] = (_Float16)xa.z; a[3] = (_Float16)xa.w;
    a[4] = (_Float16)xb.x; a[5] = (_Float16)xb.y; a[6] = (_Float16)xb.z; a[7] = (_Float16)xb.w;
#pragma unroll
    for (int ct = 0; ct < 16; ++ct)
      acc[ct] = __builtin_amdgcn_mfma_f32_16x16x32_f16(a, bbase[(kt*16 + ct) * 64], acc[ct], 0, 0, 0);
  }

  // C/D mapping: col = ct*16 + (lane&15), row = (lane>>4)*4 + i
  int c4 = lane & 15, g4 = lane >> 4;
#pragma unroll
  for (int ct = 0; ct < 16; ++ct){
#pragma unroll
    for (int i = 0; i < 4; ++i){
      int n = n0 + g4 * 4 + i;
      if (n < NN) h1h[(size_t)n * HH + ct * 16 + c4] = (__half)acc[ct][i];
    }
  }
#pragma unroll
  for (int h = 0; h < 4; ++h){
    float sa0 = as1[(h*4+0)*16 + c4], sa1 = as1[(h*4+1)*16 + c4];
    float sa2 = as1[(h*4+2)*16 + c4], sa3 = as1[(h*4+3)*16 + c4];
    float da0 = ad1[(h*4+0)*16 + c4], da1 = ad1[(h*4+1)*16 + c4];
    float da2 = ad1[(h*4+2)*16 + c4], da3 = ad1[(h*4+3)*16 + c4];
#pragma unroll
    for (int i = 0; i < 4; ++i){
      float vs = acc[h*4+0][i]*sa0 + acc[h*4+1][i]*sa1 + acc[h*4+2][i]*sa2 + acc[h*4+3][i]*sa3;
      float vd = acc[h*4+0][i]*da0 + acc[h*4+1][i]*da1 + acc[h*4+2][i]*da2 + acc[h*4+3][i]*da3;
#pragma unroll
      for (int off = 1; off < 16; off <<= 1){
        vs += __shfl_xor(vs, off);
        vd += __shfl_xor(vd, off);
      }
      if (c4 == 0){
        int n = n0 + g4 * 4 + i;
        if (n < NN){ als[n*4 + h] = vs; ald[n*4 + h] = vd; }
      }
    }
  }
}

// ---------- place: block b owns nodes [256b,256b+256) -> exclusive csr region ----------
__global__ void k_place(const int* __restrict__ rs, const int2* __restrict__ pr,
                        int* __restrict__ csr){
  __shared__ int lcur[256];
  int b = blockIdx.x, t = threadIdx.x;
  int nb = b * 256 + t;
  lcur[t] = (nb < NN) ? rs[nb] : 0;
  int base = rs[b * 256];
  int endn = (b + 1) * 256; if (endn > NN) endn = NN;
  int end = rs[endn];
  __syncthreads();
  for (int i = base + t; i < end; i += 256){
    int2 p = pr[i];
    int pos = atomicAdd(&lcur[p.y - b * 256], 1);
    csr[pos] = p.x;
  }
}

// ---------- fused layer-1 softmax weights + gather + ELU (wave per node) ----------
__global__ void k_agg1m(const int* __restrict__ rs, const int* __restrict__ csr,
                        const __half* __restrict__ h1h, const float* __restrict__ als,
                        const float* __restrict__ ald, const float* __restrict__ b1,
                        __half* __restrict__ g1h){
  int t = threadIdx.x, wv = t >> 6, lane = t & 63;
  int head = lane >> 4, q = lane & 15;
  int n = blockIdx.x * 4 + wv;
  int e0 = rs[n], e1 = rs[n + 1];
  int deg = e1 - e0;
  float adh = ald[n*4 + head];

  float w0r = 0.f, w1r = 0.f, w2r = 0.f, w3r = 0.f;
  int   s0r = 0,   s1r = 0,   s2r = 0,   s3r = 0;
  float den = 0.f;
  if (q      < deg){ s0r = csr[e0 + q];      w0r = expf(lrelu(als[s0r*4+head] + adh)); den += w0r; }
  if (q + 16 < deg){ s1r = csr[e0 + 16 + q]; w1r = expf(lrelu(als[s1r*4+head] + adh)); den += w1r; }
  if (q + 32 < deg){ s2r = csr[e0 + 32 + q]; w2r = expf(lrelu(als[s2r*4+head] + adh)); den += w2r; }
  if (q + 48 < deg){ s3r = csr[e0 + 48 + q]; w3r = expf(lrelu(als[s3r*4+head] + adh)); den += w3r; }
  for (int e = e0 + 64 + q; e < e1; e += 16) den += expf(lrelu(als[csr[e]*4+head] + adh));
  den += __shfl_xor(den, 1); den += __shfl_xor(den, 2);
  den += __shfl_xor(den, 4); den += __shfl_xor(den, 8);
  float selfw = expf(lrelu(als[n*4+head] + adh));
  float inv = 1.f / (den + selfw + 1e-16f);
  float wself = selfw * inv;

  float a0, a1, a2, a3;
  { float2 r = *(const float2*)(h1h + (size_t)n * HH + lane * 4);
    float f0,f1,f2,f3; unp4(r, f0,f1,f2,f3);
    a0 = wself*f0; a1 = wself*f1; a2 = wself*f2; a3 = wself*f3; }

  int hb = lane & 48;
  int cnt = deg < 64 ? deg : 64;
  auto pass = [&](float wp, int sp, int off){
    int lim = cnt - off; if (lim <= 0) return; if (lim > 16) lim = 16;
    for (int q2 = 0; q2 < lim; q2 += 4){          // wave-uniform trip count
      int j1 = q2 + 1, j2 = q2 + 2, j3 = q2 + 3;
      float m1 = (j1 < lim) ? inv : 0.f; if (j1 >= lim) j1 = q2;
      float m2 = (j2 < lim) ? inv : 0.f; if (j2 >= lim) j2 = q2;
      float m3 = (j3 < lim) ? inv : 0.f; if (j3 >= lim) j3 = q2;
      float wa = inv * __shfl(wp, hb + q2); int sa = __shfl(sp, hb + q2);
      float wb = m1  * __shfl(wp, hb + j1); int sb = __shfl(sp, hb + j1);
      float wc = m2  * __shfl(wp, hb + j2); int sc = __shfl(sp, hb + j2);
      float wd = m3  * __shfl(wp, hb + j3); int sd = __shfl(sp, hb + j3);
      float2 ra = *(const float2*)(h1h + (size_t)sa * HH + lane * 4);
      float2 rb = *(const float2*)(h1h + (size_t)sb * HH + lane * 4);
      float2 rc = *(const float2*)(h1h + (size_t)sc * HH + lane * 4);
      float2 rd = *(const float2*)(h1h + (size_t)sd * HH + lane * 4);
      float f0,f1,f2,f3;
      unp4(ra, f0,f1,f2,f3); a0=fmaf(wa,f0,a0); a1=fmaf(wa,f1,a1); a2=fmaf(wa,f2,a2); a3=fmaf(wa,f3,a3);
      unp4(rb, f0,f1,f2,f3); a0=fmaf(wb,f0,a0); a1=fmaf(wb,f1,a1); a2=fmaf(wb,f2,a2); a3=fmaf(wb,f3,a3);
      unp4(rc, f0,f1,f2,f3); a0=fmaf(wc,f0,a0); a1=fmaf(wc,f1,a1); a2=fmaf(wc,f2,a2); a3=fmaf(wc,f3,a3);
      unp4(rd, f0,f1,f2,f3); a0=fmaf(wd,f0,a0); a1=fmaf(wd,f1,a1); a2=fmaf(wd,f2,a2); a3=fmaf(wd,f3,a3);
    }
  };
  pass(w0r, s0r, 0); pass(w1r, s1r, 16); pass(w2r, s2r, 32); pass(w3r, s3r, 48);
  // rare tail: deg > 64, recompute weights directly (uniform loop)
  for (int e = e0 + 64; e < e1; ++e){
    int s = csr[e];
    float w = inv * expf(lrelu(als[s*4+head] + adh));
    float2 r = *(const float2*)(h1h + (size_t)s * HH + lane * 4);
    float f0,f1,f2,f3; unp4(r, f0,f1,f2,f3);
    a0=fmaf(w,f0,a0); a1=fmaf(w,f1,a1); a2=fmaf(w,f2,a2); a3=fmaf(w,f3,a3);
  }

  float4 b4 = *(const float4*)(b1 + lane * 4);
  __half2 p0 = __floats2half2_rn(elu_(a0 + b4.x), elu_(a1 + b4.y));
  __half2 p1 = __floats2half2_rn(elu_(a2 + b4.z), elu_(a3 + b4.w));
  float2 outv; ((__half2*)&outv)[0] = p0; ((__half2*)&outv)[1] = p1;
  *(float2*)(g1h + (size_t)n * HH + lane * 4) = outv;
}

// ---------- h2 = g1 @ W2 via MFMA 16x16x32_f16, fused alpha2 ----------
__global__ void k_gemm2m(const __half* __restrict__ g1h, const __half* __restrict__ Bp,
                         const float* __restrict__ as2, const float* __restrict__ ad2,
                         __half* __restrict__ h2h, float* __restrict__ als2, float* __restrict__ ald2){
  int t = threadIdx.x, wv = t >> 6, lane = t & 63;
  int n0 = blockIdx.x * 64 + wv * 16;    // 16 rows per wave
  int arow = n0 + (lane & 15);
  if (arow > NN - 1) arow = NN - 1;      // clamp for loads; stores guarded
  const _Float16* gbase = (const _Float16*)g1h + (size_t)arow * HH + (lane >> 4) * 8;
  const f16x8* bbase = (const f16x8*)Bp + lane;   // + (kt*4+ct)*64

  f32x4 acc0 = {0.f,0.f,0.f,0.f}, acc1 = {0.f,0.f,0.f,0.f};
  f32x4 acc2 = {0.f,0.f,0.f,0.f}, acc3 = {0.f,0.f,0.f,0.f};
#pragma unroll
  for (int kt = 0; kt < 8; ++kt){
    f16x8 a = *(const f16x8*)(gbase + kt * 32);
    acc0 = __builtin_amdgcn_mfma_f32_16x16x32_f16(a, bbase[(kt*4 + 0) * 64], acc0, 0, 0, 0);
    acc1 = __builtin_amdgcn_mfma_f32_16x16x32_f16(a, bbase[(kt*4 + 1) * 64], acc1, 0, 0, 0);
    acc2 = __builtin_amdgcn_mfma_f32_16x16x32_f16(a, bbase[(kt*4 + 2) * 64], acc2, 0, 0, 0);
    acc3 = __builtin_amdgcn_mfma_f32_16x16x32_f16(a, bbase[(kt*4 + 3) * 64], acc3, 0, 0, 0);
  }
  int c4 = lane & 15, g4 = lane >> 4;
  float as2v0 = as2[c4], as2v1 = as2[16 + c4], as2v2 = as2[32 + c4], as2v3 = as2[48 + c4];
  float ad2v0 = ad2[c4], ad2v1 = ad2[16 + c4], ad2v2 = ad2[32 + c4], ad2v3 = ad2[48 + c4];
  float vs[4], vd[4];
#pragma unroll
  for (int i = 0; i < 4; ++i){
    int n = n0 + g4 * 4 + i;
    if (n < NN){
      h2h[(size_t)n * HID + c4]      = (__half)acc0[i];
      h2h[(size_t)n * HID + 16 + c4] = (__half)acc1[i];
      h2h[(size_t)n * HID + 32 + c4] = (__half)acc2[i];
      h2h[(size_t)n * HID + 48 + c4] = (__half)acc3[i];
    }
    vs[i] = acc0[i]*as2v0 + acc1[i]*as2v1 + acc2[i]*as2v2 + acc3[i]*as2v3;
    vd[i] = acc0[i]*ad2v0 + acc1[i]*ad2v1 + acc2[i]*ad2v2 + acc3[i]*ad2v3;
  }
#pragma unroll
  for (int off = 1; off < 16; off <<= 1){
#pragma unroll
    for (int i = 0; i < 4; ++i){
      vs[i] += __shfl_xor(vs[i], off);
      vd[i] += __shfl_xor(vd[i], off);
    }
  }
  if (c4 == 0){
#pragma unroll
    for (int i = 0; i < 4; ++i){
      int n = n0 + g4 * 4 + i;
      if (n < NN){ als2[n] = vs[i]; ald2[n] = vd[i]; }
    }
  }
}

// ---------- fused layer-2 weights + gather + ELU + hW + scores (wave per node) ----------
__global__ void k_agg2s(const int* __restrict__ rs, const int* __restrict__ csr,
                        const __half* __restrict__ h2h, const float* __restrict__ als,
                        const float* __restrict__ ald, const float* __restrict__ b2,
                        const float* __restrict__ clW1, const float* __restrict__ tWb,
                        const float* __restrict__ w2, const float* __restrict__ b2s,
                        float* __restrict__ out){
  __shared__ float os[4][64];
  __shared__ float tw[16][64];
  __shared__ float w2s[64];
  int t = threadIdx.x, wv = t >> 6, lane = t & 63;
  for (int i = t; i < 1024; i += 256) tw[i >> 6][i & 63] = tWb[i];
  if (t < 64) w2s[t] = w2[t];

  int g16 = lane >> 4, c4 = lane & 15;
  int n = blockIdx.x * 4 + wv;
  int e0 = rs[n], e1 = rs[n + 1];
  int deg = e1 - e0;
  float adn = ald[n];

  float wr = 0.f; int sr = 0;
  float den = 0.f;
  if (lane < deg){ sr = csr[e0 + lane]; wr = expf(lrelu(als[sr] + adn)); den = wr; }
  for (int e = e0 + 64 + lane; e < e1; e += 64) den += expf(lrelu(als[csr[e]] + adn));
#pragma unroll
  for (int off = 1; off <= 32; off <<= 1) den += __shfl_xor(den, off);
  float selfw = expf(lrelu(als[n] + adn));
  float inv = 1.f / (den + selfw + 1e-16f);
  float wself = selfw * inv;

  float a0 = 0.f, a1 = 0.f, a2 = 0.f, a3 = 0.f;
  int cnt = deg < 64 ? deg : 64;
  for (int base = 0; base < cnt; base += 8){    // uniform trip count; shfl legal
    int idx = base + g16;
    int  i1 = (idx < cnt) ? idx : 0;
    float wa = ((idx < cnt) ? inv : 0.f) * __shfl(wr, i1);
    int   sa = __shfl(sr, i1);
    int idxb = idx + 4;
    int  i2 = (idxb < cnt) ? idxb : 0;
    float wb = ((idxb < cnt) ? inv : 0.f) * __shfl(wr, i2);
    int   sb = __shfl(sr, i2);
    float2 r0 = *(const float2*)(h2h + (size_t)sa * HID + c4 * 4);
    float2 r1 = *(const float2*)(h2h + (size_t)sb * HID + c4 * 4);
    float f0,f1,f2,f3;
    unp4(r0, f0,f1,f2,f3); a0=fmaf(wa,f0,a0); a1=fmaf(wa,f1,a1); a2=fmaf(wa,f2,a2); a3=fmaf(wa,f3,a3);
    unp4(r1, f0,f1,f2,f3); a0=fmaf(wb,f0,a0); a1=fmaf(wb,f1,a1); a2=fmaf(wb,f2,a2); a3=fmaf(wb,f3,a3);
  }
  // rare tail: deg > 64, recompute (no cross-lane ops -> divergence safe)
  for (int e = e0 + 64 + g16; e < e1; e += 4){
    int s = csr[e];
    float w = inv * expf(lrelu(als[s] + adn));
    float2 r = *(const float2*)(h2h + (size_t)s * HID + c4 * 4);
    float f0,f1,f2,f3; unp4(r, f0,f1,f2,f3);
    a0=fmaf(w,f0,a0); a1=fmaf(w,f1,a1); a2=fmaf(w,f2,a2); a3=fmaf(w,f3,a3);
  }

  a0 += __shfl_xor(a0, 16); a1 += __shfl_xor(a1, 16); a2 += __shfl_xor(a2, 16); a3 += __shfl_xor(a3, 16);
  a0 += __shfl_xor(a0, 32); a1 += __shfl_xor(a1, 32); a2 += __shfl_xor(a2, 32); a3 += __shfl_xor(a3, 32);
  if (lane < 16){
    float2 r = *(const float2*)(h2h + (size_t)n * HID + lane * 4);
    float f0,f1,f2,f3; unp4(r, f0,f1,f2,f3);
    a0 = fmaf(wself, f0, a0); a1 = fmaf(wself, f1, a1); a2 = fmaf(wself, f2, a2); a3 = fmaf(wself, f3, a3);
    float4 b4 = *(const float4*)(b2 + lane * 4);
    float4 o;
    o.x = elu_(a0 + b4.x); o.y = elu_(a1 + b4.y); o.z = elu_(a2 + b4.z); o.w = elu_(a3 + b4.w);
    *(float4*)(&os[wv][lane * 4]) = o;
  }
  __syncthreads();   // covers os AND tw/w2s
  float hv = 0.f;
  const float* o = os[wv];
  for (int k = 0; k < HID; ++k) hv = fmaf(o[k], clW1[k * HID + lane], hv);
  float bias = b2s[0];
  for (int b = 0; b < 16; ++b){
    float v = fmaxf(hv + tw[b][lane], 0.f) * w2s[lane];
#pragma unroll
    for (int off = 32; off > 0; off >>= 1) v += __shfl_xor(v, off);
    if (lane == b) out[b * NN + n] = v + bias;
  }
}

extern "C" void kernel_launch(void* const* d_in, const int* in_sizes, int n_in,
                              void* d_out, int out_size, void* d_ws, size_t ws_size,
                              hipStream_t stream){
  const float* x    = (const float*)d_in[0];
  const int*   ei   = (const int*)  d_in[1];
  const float* task = (const float*)d_in[2];
  const float* W1   = (const float*)d_in[3];
  const float* as1  = (const float*)d_in[4];
  const float* ad1  = (const float*)d_in[5];
  const float* b1   = (const float*)d_in[6];
  const float* W2   = (const float*)d_in[7];
  const float* as2  = (const float*)d_in[8];
  const float* ad2  = (const float*)d_in[9];
  const float* b2   = (const float*)d_in[10];
  const float* teW1 = (const float*)d_in[11];
  const float* teb1 = (const float*)d_in[12];
  const float* teW2 = (const float*)d_in[13];
  const float* teb2 = (const float*)d_in[14];
  const float* clW1 = (const float*)d_in[15];
  const float* clb1 = (const float*)d_in[16];
  const float* clW2 = (const float*)d_in[17];
  const float* clb2 = (const float*)d_in[18];
  float* out = (float*)d_out;
  float* ws  = (float*)d_ws;

  // workspace layout (float-sized slots)
  __half* h1h  = (__half*)ws;                    // 12.8M halfs -> 6.4M floats
  float* als1  = ws + 6400000;                   // 200,000
  float* ald1  = als1 + 200000;                  // 200,000
  __half* g1h  = (__half*)(ald1 + 200000);       // 12.8M halfs -> 6.4M floats
  __half* h2h  = (__half*)(ald1 + 200000 + 6400000);  // 3.2M halfs -> 1.6M floats
  float* als2  = ald1 + 200000 + 6400000 + 1600000;   // 50,000
  float* ald2  = als2 + 50000;                   // 50,000
  float* tWb   = ald2 + 50000;                   // 1,024
  int*   deg   = (int*)(tWb + 1024);             // 50,000
  int*   rs    = deg + 50000;                    // 50,001 (+pad)
  int*   csr   = rs + 50004;                     // 800,000
  int*   psum  = csr + 800000;                   // 256
  int*   pofs  = psum + 256;                     // 256
  int*   bcur  = pofs + 256;                     // 256
  __half* Bp   = (__half*)(bcur + 256);          // 16,384 halfs (MFMA-ordered W2)
  __half* Bp1  = Bp + 16384;                     // 32,768 halfs (MFMA-ordered W1)
  int2*  pr    = (int2*)(Bp1 + 32768);           // 800,000 pairs (6.4 MB)

  hipMemsetAsync(deg, 0, 50000 * sizeof(int), stream);
  // deg histogram + weight prep + task encoder (independent work, one launch)
  k_misc   <<<3150, 256, 0, stream>>>(ei, deg, W2, W1, Bp, Bp1,
                                      task, teW1, teb1, teW2, teb2, clW1, clb1, tWb);
  k_psum   <<<196, 256, 0, stream>>>(deg, psum);
  k_pscan  <<<1, 256, 0, stream>>>(psum, pofs);
  k_wroffs <<<196, 256, 0, stream>>>(deg, pofs, rs, bcur);
  // LDS-binned edge partition + layer-1 GEMM (independent, one launch)
  k_binGemm<<<200 + (NN + 63)/64, 256, 0, stream>>>(ei, bcur, pr, x, Bp1,
                                                    as1, ad1, h1h, als1, ald1);
  // exclusive-region CSR placement
  k_place  <<<196, 256, 0, stream>>>(rs, pr, csr);
  // layer 1 aggregate
  k_agg1m  <<<12500, 256, 0, stream>>>(rs, csr, h1h, als1, ald1, b1, g1h);
  // layer 2 GEMM
  k_gemm2m <<<(NN + 63)/64, 256, 0, stream>>>(g1h, Bp, as2, ad2, h2h, als2, ald2);
  // layer 2 aggregate + classifier scores
  k_agg2s  <<<12500, 256, 0, stream>>>(rs, csr, h2h, als2, ald2, b2, clW1,
                                       tWb, clW2, clb2, out);
}

// Round 11
// 234.840 us; speedup vs baseline: 5.7482x; 1.0891x over previous
//
#include <hip/hip_runtime.h>
#include <hip/hip_fp16.h>

#define NN 50000
#define NE 800000
#define FN 128
#define HH 256      // HEADS*HID
#define HID 64
#define NBKT 196    // 256-node buckets
#define CHUNK 4000  // edges per bin block; 200*4000 == NE

typedef _Float16 f16x8 __attribute__((ext_vector_type(8)));
typedef float f32x4 __attribute__((ext_vector_type(4)));

__device__ __forceinline__ float lrelu(float v){ return v >= 0.f ? v : 0.2f * v; }
__device__ __forceinline__ float elu_(float v){ return v > 0.f ? v : expm1f(v); }

__device__ __forceinline__ void unp4(const float2 r, float& f0, float& f1, float& f2, float& f3){
  const __half2* hp = (const __half2*)&r;
  float2 a = __half22float2(hp[0]);
  float2 b = __half22float2(hp[1]);
  f0 = a.x; f1 = a.y; f2 = b.x; f3 = b.y;
}

// ---------- merged: deg histogram + weight prep + task encoder ----------
__global__ void k_misc(const int* __restrict__ ei, int* __restrict__ deg,
                       const float* __restrict__ W2, const float* __restrict__ W1,
                       __half* __restrict__ Bp, __half* __restrict__ Bp1,
                       const float* __restrict__ task, const float* __restrict__ W1t,
                       const float* __restrict__ b1t, const float* __restrict__ W2t,
                       const float* __restrict__ b2t, const float* __restrict__ clW1,
                       const float* __restrict__ clb1, float* __restrict__ tWb){
  int bid = blockIdx.x, t = threadIdx.x;
  if (bid < 3125){                       // k_deg: 3125*256 == NE
    int e = bid * 256 + t;
    atomicAdd(deg + ei[NE + e], 1);
  } else if (bid < 3149){                // k_prep: 24 blocks
    int f = (bid - 3125) * 256 + t;
    if (f < 2048){
      int lane = f & 63;
      int ct = (f >> 6) & 3, kt = f >> 8;
      int kbase = kt * 32 + (lane >> 4) * 8;
      int col = ct * 16 + (lane & 15);
#pragma unroll
      for (int i = 0; i < 8; ++i)
        Bp[(size_t)f * 8 + i] = (__half)W2[(kbase + i) * HID + col];
    } else if (f < 6144){
      int g = f - 2048;
      int lane = g & 63;
      int ct = (g >> 6) & 15, kt = g >> 10;
      int kbase = kt * 32 + (lane >> 4) * 8;
      int col = ct * 16 + (lane & 15);
#pragma unroll
      for (int i = 0; i < 8; ++i)
        Bp1[(size_t)g * 8 + i] = (__half)W1[(kbase + i) * HH + col];
    }
  } else {                               // k_task: 1 block
    __shared__ float t1[16][64];
    __shared__ float t2[16][64];
    for (int idx = t; idx < 1024; idx += 256){
      int b = idx >> 6, c = idx & 63;
      float acc = b1t[c];
      for (int k = 0; k < 128; ++k) acc = fmaf(task[b*128 + k], W1t[k*64 + c], acc);
      t1[b][c] = fmaxf(acc, 0.f);
    }
    __syncthreads();
    for (int idx = t; idx < 1024; idx += 256){
      int b = idx >> 6, c = idx & 63;
      float acc = b2t[c];
      for (int k = 0; k < 64; ++k) acc = fmaf(t1[b][k], W2t[k*64 + c], acc);
      t2[b][c] = acc;
    }
    __syncthreads();
    for (int idx = t; idx < 1024; idx += 256){
      int b = idx >> 6, c = idx & 63;
      float acc = clb1[c];
      for (int k = 0; k < 64; ++k) acc = fmaf(t2[b][k], clW1[(64 + k)*64 + c], acc);
      tWb[idx] = acc;
    }
  }
}

__global__ void k_psum(const int* __restrict__ deg, int* __restrict__ psum){
  int b = blockIdx.x, t = threadIdx.x;
  int idx = b * 256 + t;
  int v = (idx < NN) ? deg[idx] : 0;
#pragma unroll
  for (int off = 32; off > 0; off >>= 1) v += __shfl_down(v, off);
  __shared__ int wsum[4];
  if ((t & 63) == 0) wsum[t >> 6] = v;
  __syncthreads();
  if (t == 0) psum[b] = wsum[0] + wsum[1] + wsum[2] + wsum[3];
}

__global__ void k_pscan(const int* __restrict__ psum, int* __restrict__ pofs){
  int t = threadIdx.x;            // 256 threads
  int lane = t & 63, wv = t >> 6;
  int v = (t < 196) ? psum[t] : 0;
  int iv = v;
#pragma unroll
  for (int off = 1; off < 64; off <<= 1){
    int u = __shfl_up(iv, off);
    if (lane >= off) iv += u;
  }
  __shared__ int wsum[4];
  if (lane == 63) wsum[wv] = iv;
  __syncthreads();
  int add = 0;
  for (int w = 0; w < wv; ++w) add += wsum[w];
  iv += add;
  if (t < 196) pofs[t] = iv - v;  // exclusive
}

__global__ void k_wroffs(const int* __restrict__ deg, const int* __restrict__ pofs,
                         int* __restrict__ rs, int* __restrict__ bcur){
  int b = blockIdx.x, t = threadIdx.x;
  int idx = b * 256 + t;
  int lane = t & 63, wv = t >> 6;
  int v = (idx < NN) ? deg[idx] : 0;
  int iv = v;
#pragma unroll
  for (int off = 1; off < 64; off <<= 1){
    int u = __shfl_up(iv, off);
    if (lane >= off) iv += u;
  }
  __shared__ int wsum[4];
  if (lane == 63) wsum[wv] = iv;
  __syncthreads();
  int add = pofs[b];
  for (int w = 0; w < wv; ++w) add += wsum[w];
  int excl = add + iv - v;
  if (idx < NN){
    rs[idx] = excl;
    if ((idx & 255) == 0) bcur[idx >> 8] = excl;   // bucket append cursor
  }
  if (idx == NN) rs[NN] = excl;
}

// ---------- merged: LDS-binned edge partition + (h1 = x @ W1 MFMA, fused alpha1) ----------
__global__ void k_binGemm(const int* __restrict__ ei, int* __restrict__ bcur, int2* __restrict__ pr,
                          const float* __restrict__ x, const __half* __restrict__ Bp1,
                          const float* __restrict__ as1, const float* __restrict__ ad1,
                          __half* __restrict__ h1h, float* __restrict__ als, float* __restrict__ ald){
  __shared__ int hist[NBKT];
  __shared__ int lstart[NBKT];
  __shared__ int gpos[NBKT];
  __shared__ int cnt[NBKT];
  __shared__ int2 stage[CHUNK];          // 32 KB
  int bid = blockIdx.x, t = threadIdx.x;
  if (bid < 200){                        // bin: 200*4000 == NE
    int e_base = bid * CHUNK;
    if (t < NBKT){ hist[t] = 0; cnt[t] = 0; }
    __syncthreads();
    for (int i = t; i < CHUNK; i += 256)
      atomicAdd(&hist[ei[NE + e_base + i] >> 8], 1);
    __syncthreads();
    {
      int lane = t & 63, wvi = t >> 6;
      int v = (t < NBKT) ? hist[t] : 0;
      int iv = v;
#pragma unroll
      for (int off = 1; off < 64; off <<= 1){
        int u = __shfl_up(iv, off);
        if (lane >= off) iv += u;
      }
      __shared__ int wsum[4];
      if (lane == 63) wsum[wvi] = iv;
      __syncthreads();
      int add = 0;
      for (int w = 0; w < wvi; ++w) add += wsum[w];
      iv += add;
      if (t < NBKT){
        lstart[t] = iv - v;
        gpos[t] = (v > 0) ? atomicAdd(&bcur[t], v) : 0;
      }
    }
    __syncthreads();
    for (int i = t; i < CHUNK; i += 256){
      int e = e_base + i;
      int s = ei[e], d = ei[NE + e];
      int bb = d >> 8;
      int r = atomicAdd(&cnt[bb], 1);
      stage[lstart[bb] + r] = make_int2(s, d);
    }
    __syncthreads();
    for (int i = t; i < CHUNK; i += 256){
      int2 p = stage[i];
      int bb = p.y >> 8;
      pr[gpos[bb] + (i - lstart[bb])] = p;
    }
    return;
  }
  // gemm1m part
  int blk = bid - 200;
  int wv = t >> 6, lane = t & 63;
  int n0 = blk * 64 + wv * 16;           // 16 rows per wave
  int arow = n0 + (lane & 15);
  if (arow > NN - 1) arow = NN - 1;      // clamp for loads; stores guarded
  const float* xbase = x + (size_t)arow * FN + (lane >> 4) * 8;
  const f16x8* bbase = (const f16x8*)Bp1 + lane;   // + (kt*16+ct)*64

  f32x4 acc[16];
#pragma unroll
  for (int ct = 0; ct < 16; ++ct) acc[ct] = (f32x4){0.f,0.f,0.f,0.f};

#pragma unroll
  for (int kt = 0; kt < 4; ++kt){
    float4 xa = *(const float4*)(xbase + kt * 32);
    float4 xb = *(const float4*)(xbase + kt * 32 + 4);
    f16x8 a;
    a[0] = (_Float16)xa.x; a[1] = (_Float16)xa.y; a[2] = (_Float16)xa.z; a[3] = (_Float16)xa.w;
    a[4] = (_Float16)xb.x; a[5] = (_Float16)xb.y; a[6] = (_Float16)xb.z; a[7] = (_Float16)xb.w;
#pragma unroll
    for (int ct = 0; ct < 16; ++ct)
      acc[ct] = __builtin_amdgcn_mfma_f32_16x16x32_f16(a, bbase[(kt*16 + ct) * 64], acc[ct], 0, 0, 0);
  }

  // C/D mapping: col = ct*16 + (lane&15), row = (lane>>4)*4 + i
  int c4 = lane & 15, g4 = lane >> 4;
#pragma unroll
  for (int ct = 0; ct < 16; ++ct){
#pragma unroll
    for (int i = 0; i < 4; ++i){
      int n = n0 + g4 * 4 + i;
      if (n < NN) h1h[(size_t)n * HH + ct * 16 + c4] = (__half)acc[ct][i];
    }
  }
#pragma unroll
  for (int h = 0; h < 4; ++h){
    float sa0 = as1[(h*4+0)*16 + c4], sa1 = as1[(h*4+1)*16 + c4];
    float sa2 = as1[(h*4+2)*16 + c4], sa3 = as1[(h*4+3)*16 + c4];
    float da0 = ad1[(h*4+0)*16 + c4], da1 = ad1[(h*4+1)*16 + c4];
    float da2 = ad1[(h*4+2)*16 + c4], da3 = ad1[(h*4+3)*16 + c4];
#pragma unroll
    for (int i = 0; i < 4; ++i){
      float vs = acc[h*4+0][i]*sa0 + acc[h*4+1][i]*sa1 + acc[h*4+2][i]*sa2 + acc[h*4+3][i]*sa3;
      float vd = acc[h*4+0][i]*da0 + acc[h*4+1][i]*da1 + acc[h*4+2][i]*da2 + acc[h*4+3][i]*da3;
#pragma unroll
      for (int off = 1; off < 16; off <<= 1){
        vs += __shfl_xor(vs, off);
        vd += __shfl_xor(vd, off);
      }
      if (c4 == 0){
        int n = n0 + g4 * 4 + i;
        if (n < NN){ als[n*4 + h] = vs; ald[n*4 + h] = vd; }
      }
    }
  }
}

// ---------- place: block b owns nodes [256b,256b+256) -> exclusive csr region ----------
__global__ void k_place(const int* __restrict__ rs, const int2* __restrict__ pr,
                        int* __restrict__ csr){
  __shared__ int lcur[256];
  int b = blockIdx.x, t = threadIdx.x;
  int nb = b * 256 + t;
  lcur[t] = (nb < NN) ? rs[nb] : 0;
  int base = rs[b * 256];
  int endn = (b + 1) * 256; if (endn > NN) endn = NN;
  int end = rs[endn];
  __syncthreads();
  for (int i = base + t; i < end; i += 256){
    int2 p = pr[i];
    int pos = atomicAdd(&lcur[p.y - b * 256], 1);
    csr[pos] = p.x;
  }
}

// ---------- fused layer-1 softmax weights + gather + ELU (wave per node) ----------
__global__ void k_agg1m(const int* __restrict__ rs, const int* __restrict__ csr,
                        const __half* __restrict__ h1h, const float* __restrict__ als,
                        const float* __restrict__ ald, const float* __restrict__ b1,
                        __half* __restrict__ g1h){
  int t = threadIdx.x, wv = t >> 6, lane = t & 63;
  int head = lane >> 4, q = lane & 15;
  int n = blockIdx.x * 4 + wv;
  int e0 = rs[n], e1 = rs[n + 1];
  int deg = e1 - e0;
  float adh = ald[n*4 + head];

  float w0r = 0.f, w1r = 0.f, w2r = 0.f, w3r = 0.f;
  int   s0r = 0,   s1r = 0,   s2r = 0,   s3r = 0;
  float den = 0.f;
  if (q      < deg){ s0r = csr[e0 + q];      w0r = expf(lrelu(als[s0r*4+head] + adh)); den += w0r; }
  if (q + 16 < deg){ s1r = csr[e0 + 16 + q]; w1r = expf(lrelu(als[s1r*4+head] + adh)); den += w1r; }
  if (q + 32 < deg){ s2r = csr[e0 + 32 + q]; w2r = expf(lrelu(als[s2r*4+head] + adh)); den += w2r; }
  if (q + 48 < deg){ s3r = csr[e0 + 48 + q]; w3r = expf(lrelu(als[s3r*4+head] + adh)); den += w3r; }
  for (int e = e0 + 64 + q; e < e1; e += 16) den += expf(lrelu(als[csr[e]*4+head] + adh));
  den += __shfl_xor(den, 1); den += __shfl_xor(den, 2);
  den += __shfl_xor(den, 4); den += __shfl_xor(den, 8);
  float selfw = expf(lrelu(als[n*4+head] + adh));
  float inv = 1.f / (den + selfw + 1e-16f);
  float wself = selfw * inv;

  float a0, a1, a2, a3;
  { float2 r = *(const float2*)(h1h + (size_t)n * HH + lane * 4);
    float f0,f1,f2,f3; unp4(r, f0,f1,f2,f3);
    a0 = wself*f0; a1 = wself*f1; a2 = wself*f2; a3 = wself*f3; }

  int hb = lane & 48;
  int cnt = deg < 64 ? deg : 64;
  auto pass = [&](float wp, int sp, int off){
    int lim = cnt - off; if (lim <= 0) return; if (lim > 16) lim = 16;
    for (int q2 = 0; q2 < lim; q2 += 4){          // wave-uniform trip count
      int j1 = q2 + 1, j2 = q2 + 2, j3 = q2 + 3;
      float m1 = (j1 < lim) ? inv : 0.f; if (j1 >= lim) j1 = q2;
      float m2 = (j2 < lim) ? inv : 0.f; if (j2 >= lim) j2 = q2;
      float m3 = (j3 < lim) ? inv : 0.f; if (j3 >= lim) j3 = q2;
      float wa = inv * __shfl(wp, hb + q2); int sa = __shfl(sp, hb + q2);
      float wb = m1  * __shfl(wp, hb + j1); int sb = __shfl(sp, hb + j1);
      float wc = m2  * __shfl(wp, hb + j2); int sc = __shfl(sp, hb + j2);
      float wd = m3  * __shfl(wp, hb + j3); int sd = __shfl(sp, hb + j3);
      float2 ra = *(const float2*)(h1h + (size_t)sa * HH + lane * 4);
      float2 rb = *(const float2*)(h1h + (size_t)sb * HH + lane * 4);
      float2 rc = *(const float2*)(h1h + (size_t)sc * HH + lane * 4);
      float2 rd = *(const float2*)(h1h + (size_t)sd * HH + lane * 4);
      float f0,f1,f2,f3;
      unp4(ra, f0,f1,f2,f3); a0=fmaf(wa,f0,a0); a1=fmaf(wa,f1,a1); a2=fmaf(wa,f2,a2); a3=fmaf(wa,f3,a3);
      unp4(rb, f0,f1,f2,f3); a0=fmaf(wb,f0,a0); a1=fmaf(wb,f1,a1); a2=fmaf(wb,f2,a2); a3=fmaf(wb,f3,a3);
      unp4(rc, f0,f1,f2,f3); a0=fmaf(wc,f0,a0); a1=fmaf(wc,f1,a1); a2=fmaf(wc,f2,a2); a3=fmaf(wc,f3,a3);
      unp4(rd, f0,f1,f2,f3); a0=fmaf(wd,f0,a0); a1=fmaf(wd,f1,a1); a2=fmaf(wd,f2,a2); a3=fmaf(wd,f3,a3);
    }
  };
  pass(w0r, s0r, 0); pass(w1r, s1r, 16); pass(w2r, s2r, 32); pass(w3r, s3r, 48);
  // rare tail: deg > 64, recompute weights directly (uniform loop)
  for (int e = e0 + 64; e < e1; ++e){
    int s = csr[e];
    float w = inv * expf(lrelu(als[s*4+head] + adh));
    float2 r = *(const float2*)(h1h + (size_t)s * HH + lane * 4);
    float f0,f1,f2,f3; unp4(r, f0,f1,f2,f3);
    a0=fmaf(w,f0,a0); a1=fmaf(w,f1,a1); a2=fmaf(w,f2,a2); a3=fmaf(w,f3,a3);
  }

  float4 b4 = *(const float4*)(b1 + lane * 4);
  __half2 p0 = __floats2half2_rn(elu_(a0 + b4.x), elu_(a1 + b4.y));
  __half2 p1 = __floats2half2_rn(elu_(a2 + b4.z), elu_(a3 + b4.w));
  float2 outv; ((__half2*)&outv)[0] = p0; ((__half2*)&outv)[1] = p1;
  *(float2*)(g1h + (size_t)n * HH + lane * 4) = outv;
}

// ---------- h2 = g1 @ W2 via MFMA 16x16x32_f16, fused alpha2 ----------
__global__ void k_gemm2m(const __half* __restrict__ g1h, const __half* __restrict__ Bp,
                         const float* __restrict__ as2, const float* __restrict__ ad2,
                         __half* __restrict__ h2h, float* __restrict__ als2, float* __restrict__ ald2){
  int t = threadIdx.x, wv = t >> 6, lane = t & 63;
  int n0 = blockIdx.x * 64 + wv * 16;    // 16 rows per wave
  int arow = n0 + (lane & 15);
  if (arow > NN - 1) arow = NN - 1;      // clamp for loads; stores guarded
  const _Float16* gbase = (const _Float16*)g1h + (size_t)arow * HH + (lane >> 4) * 8;
  const f16x8* bbase = (const f16x8*)Bp + lane;   // + (kt*4+ct)*64

  f32x4 acc0 = {0.f,0.f,0.f,0.f}, acc1 = {0.f,0.f,0.f,0.f};
  f32x4 acc2 = {0.f,0.f,0.f,0.f}, acc3 = {0.f,0.f,0.f,0.f};
#pragma unroll
  for (int kt = 0; kt < 8; ++kt){
    f16x8 a = *(const f16x8*)(gbase + kt * 32);
    acc0 = __builtin_amdgcn_mfma_f32_16x16x32_f16(a, bbase[(kt*4 + 0) * 64], acc0, 0, 0, 0);
    acc1 = __builtin_amdgcn_mfma_f32_16x16x32_f16(a, bbase[(kt*4 + 1) * 64], acc1, 0, 0, 0);
    acc2 = __builtin_amdgcn_mfma_f32_16x16x32_f16(a, bbase[(kt*4 + 2) * 64], acc2, 0, 0, 0);
    acc3 = __builtin_amdgcn_mfma_f32_16x16x32_f16(a, bbase[(kt*4 + 3) * 64], acc3, 0, 0, 0);
  }
  int c4 = lane & 15, g4 = lane >> 4;
  float as2v0 = as2[c4], as2v1 = as2[16 + c4], as2v2 = as2[32 + c4], as2v3 = as2[48 + c4];
  float ad2v0 = ad2[c4], ad2v1 = ad2[16 + c4], ad2v2 = ad2[32 + c4], ad2v3 = ad2[48 + c4];
  float vs[4], vd[4];
#pragma unroll
  for (int i = 0; i < 4; ++i){
    int n = n0 + g4 * 4 + i;
    if (n < NN){
      h2h[(size_t)n * HID + c4]      = (__half)acc0[i];
      h2h[(size_t)n * HID + 16 + c4] = (__half)acc1[i];
      h2h[(size_t)n * HID + 32 + c4] = (__half)acc2[i];
      h2h[(size_t)n * HID + 48 + c4] = (__half)acc3[i];
    }
    vs[i] = acc0[i]*as2v0 + acc1[i]*as2v1 + acc2[i]*as2v2 + acc3[i]*as2v3;
    vd[i] = acc0[i]*ad2v0 + acc1[i]*ad2v1 + acc2[i]*ad2v2 + acc3[i]*ad2v3;
  }
#pragma unroll
  for (int off = 1; off < 16; off <<= 1){
#pragma unroll
    for (int i = 0; i < 4; ++i){
      vs[i] += __shfl_xor(vs[i], off);
      vd[i] += __shfl_xor(vd[i], off);
    }
  }
  if (c4 == 0){
#pragma unroll
    for (int i = 0; i < 4; ++i){
      int n = n0 + g4 * 4 + i;
      if (n < NN){ als2[n] = vs[i]; ald2[n] = vd[i]; }
    }
  }
}

// ---------- fused layer-2 weights + gather + ELU + hW + scores (wave per node) ----------
__global__ void k_agg2s(const int* __restrict__ rs, const int* __restrict__ csr,
                        const __half* __restrict__ h2h, const float* __restrict__ als,
                        const float* __restrict__ ald, const float* __restrict__ b2,
                        const float* __restrict__ clW1, const float* __restrict__ tWb,
                        const float* __restrict__ w2, const float* __restrict__ b2s,
                        float* __restrict__ out){
  __shared__ float os[4][64];
  __shared__ float tw[16][64];
  __shared__ float w2s[64];
  int t = threadIdx.x, wv = t >> 6, lane = t & 63;
  for (int i = t; i < 1024; i += 256) tw[i >> 6][i & 63] = tWb[i];
  if (t < 64) w2s[t] = w2[t];

  int g16 = lane >> 4, c4 = lane & 15;
  int n = blockIdx.x * 4 + wv;
  int e0 = rs[n], e1 = rs[n + 1];
  int deg = e1 - e0;
  float adn = ald[n];

  float wr = 0.f; int sr = 0;
  float den = 0.f;
  if (lane < deg){ sr = csr[e0 + lane]; wr = expf(lrelu(als[sr] + adn)); den = wr; }
  for (int e = e0 + 64 + lane; e < e1; e += 64) den += expf(lrelu(als[csr[e]] + adn));
#pragma unroll
  for (int off = 1; off <= 32; off <<= 1) den += __shfl_xor(den, off);
  float selfw = expf(lrelu(als[n] + adn));
  float inv = 1.f / (den + selfw + 1e-16f);
  float wself = selfw * inv;

  float a0 = 0.f, a1 = 0.f, a2 = 0.f, a3 = 0.f;
  int cnt = deg < 64 ? deg : 64;
  for (int base = 0; base < cnt; base += 8){    // uniform trip count; shfl legal
    int idx = base + g16;
    int  i1 = (idx < cnt) ? idx : 0;
    float wa = ((idx < cnt) ? inv : 0.f) * __shfl(wr, i1);
    int   sa = __shfl(sr, i1);
    int idxb = idx + 4;
    int  i2 = (idxb < cnt) ? idxb : 0;
    float wb = ((idxb < cnt) ? inv : 0.f) * __shfl(wr, i2);
    int   sb = __shfl(sr, i2);
    float2 r0 = *(const float2*)(h2h + (size_t)sa * HID + c4 * 4);
    float2 r1 = *(const float2*)(h2h + (size_t)sb * HID + c4 * 4);
    float f0,f1,f2,f3;
    unp4(r0, f0,f1,f2,f3); a0=fmaf(wa,f0,a0); a1=fmaf(wa,f1,a1); a2=fmaf(wa,f2,a2); a3=fmaf(wa,f3,a3);
    unp4(r1, f0,f1,f2,f3); a0=fmaf(wb,f0,a0); a1=fmaf(wb,f1,a1); a2=fmaf(wb,f2,a2); a3=fmaf(wb,f3,a3);
  }
  // rare tail: deg > 64, recompute (no cross-lane ops -> divergence safe)
  for (int e = e0 + 64 + g16; e < e1; e += 4){
    int s = csr[e];
    float w = inv * expf(lrelu(als[s] + adn));
    float2 r = *(const float2*)(h2h + (size_t)s * HID + c4 * 4);
    float f0,f1,f2,f3; unp4(r, f0,f1,f2,f3);
    a0=fmaf(w,f0,a0); a1=fmaf(w,f1,a1); a2=fmaf(w,f2,a2); a3=fmaf(w,f3,a3);
  }

  a0 += __shfl_xor(a0, 16); a1 += __shfl_xor(a1, 16); a2 += __shfl_xor(a2, 16); a3 += __shfl_xor(a3, 16);
  a0 += __shfl_xor(a0, 32); a1 += __shfl_xor(a1, 32); a2 += __shfl_xor(a2, 32); a3 += __shfl_xor(a3, 32);
  if (lane < 16){
    float2 r = *(const float2*)(h2h + (size_t)n * HID + lane * 4);
    float f0,f1,f2,f3; unp4(r, f0,f1,f2,f3);
    a0 = fmaf(wself, f0, a0); a1 = fmaf(wself, f1, a1); a2 = fmaf(wself, f2, a2); a3 = fmaf(wself, f3, a3);
    float4 b4 = *(const float4*)(b2 + lane * 4);
    float4 o;
    o.x = elu_(a0 + b4.x); o.y = elu_(a1 + b4.y); o.z = elu_(a2 + b4.z); o.w = elu_(a3 + b4.w);
    *(float4*)(&os[wv][lane * 4]) = o;
  }
  __syncthreads();   // covers os AND tw/w2s
  float hv = 0.f;
  const float* o = os[wv];
  for (int k = 0; k < HID; ++k) hv = fmaf(o[k], clW1[k * HID + lane], hv);

  // scores: butterfly multi-value reduction (17 shfls instead of 96)
  float w2v = w2s[lane];
  float v[16];
#pragma unroll
  for (int b = 0; b < 16; ++b) v[b] = fmaxf(hv + tw[b][lane], 0.f) * w2v;
  bool h5 = (lane & 32) != 0;
  float tA[8];
#pragma unroll
  for (int j = 0; j < 8; ++j){
    float keep = h5 ? v[j+8] : v[j];
    float send = h5 ? v[j]   : v[j+8];
    tA[j] = keep + __shfl_xor(send, 32);
  }                                   // idx = j + 8*l5
  bool h4 = (lane & 16) != 0;
  float tB[4];
#pragma unroll
  for (int j = 0; j < 4; ++j){
    float keep = h4 ? tA[j+4] : tA[j];
    float send = h4 ? tA[j]   : tA[j+4];
    tB[j] = keep + __shfl_xor(send, 16);
  }                                   // idx = j + 4*l4 + 8*l5
  bool h3 = (lane & 8) != 0;
  float tC[2];
#pragma unroll
  for (int j = 0; j < 2; ++j){
    float keep = h3 ? tB[j+2] : tB[j];
    float send = h3 ? tB[j]   : tB[j+2];
    tC[j] = keep + __shfl_xor(send, 8);
  }                                   // idx = j + 2*l3 + 4*l4 + 8*l5
  bool h2f = (lane & 4) != 0;
  float z;
  {
    float keep = h2f ? tC[1] : tC[0];
    float send = h2f ? tC[0] : tC[1];
    z = keep + __shfl_xor(send, 4);
  }                                   // idx = l2 + 2*l3 + 4*l4 + 8*l5 = (lane>>2)&15
  z += __shfl_xor(z, 1);
  z += __shfl_xor(z, 2);
  if ((lane & 3) == 0)
    out[(size_t)((lane >> 2) & 15) * NN + n] = z + b2s[0];
}

extern "C" void kernel_launch(void* const* d_in, const int* in_sizes, int n_in,
                              void* d_out, int out_size, void* d_ws, size_t ws_size,
                              hipStream_t stream){
  const float* x    = (const float*)d_in[0];
  const int*   ei   = (const int*)  d_in[1];
  const float* task = (const float*)d_in[2];
  const float* W1   = (const float*)d_in[3];
  const float* as1  = (const float*)d_in[4];
  const float* ad1  = (const float*)d_in[5];
  const float* b1   = (const float*)d_in[6];
  const float* W2   = (const float*)d_in[7];
  const float* as2  = (const float*)d_in[8];
  const float* ad2  = (const float*)d_in[9];
  const float* b2   = (const float*)d_in[10];
  const float* teW1 = (const float*)d_in[11];
  const float* teb1 = (const float*)d_in[12];
  const float* teW2 = (const float*)d_in[13];
  const float* teb2 = (const float*)d_in[14];
  const float* clW1 = (const float*)d_in[15];
  const float* clb1 = (const float*)d_in[16];
  const float* clW2 = (const float*)d_in[17];
  const float* clb2 = (const float*)d_in[18];
  float* out = (float*)d_out;
  float* ws  = (float*)d_ws;

  // workspace layout (float-sized slots)
  __half* h1h  = (__half*)ws;                    // 12.8M halfs -> 6.4M floats
  float* als1  = ws + 6400000;                   // 200,000
  float* ald1  = als1 + 200000;                  // 200,000
  __half* g1h  = (__half*)(ald1 + 200000);       // 12.8M halfs -> 6.4M floats
  __half* h2h  = (__half*)(ald1 + 200000 + 6400000);  // 3.2M halfs -> 1.6M floats
  float* als2  = ald1 + 200000 + 6400000 + 1600000;   // 50,000
  float* ald2  = als2 + 50000;                   // 50,000
  float* tWb   = ald2 + 50000;                   // 1,024
  int*   deg   = (int*)(tWb + 1024);             // 50,000
  int*   rs    = deg + 50000;                    // 50,001 (+pad)
  int*   csr   = rs + 50004;                     // 800,000
  int*   psum  = csr + 800000;                   // 256
  int*   pofs  = psum + 256;                     // 256
  int*   bcur  = pofs + 256;                     // 256
  __half* Bp   = (__half*)(bcur + 256);          // 16,384 halfs (MFMA-ordered W2)
  __half* Bp1  = Bp + 16384;                     // 32,768 halfs (MFMA-ordered W1)
  int2*  pr    = (int2*)(Bp1 + 32768);           // 800,000 pairs (6.4 MB)

  hipMemsetAsync(deg, 0, 50000 * sizeof(int), stream);
  // deg histogram + weight prep + task encoder (independent work, one launch)
  k_misc   <<<3150, 256, 0, stream>>>(ei, deg, W2, W1, Bp, Bp1,
                                      task, teW1, teb1, teW2, teb2, clW1, clb1, tWb);
  k_psum   <<<196, 256, 0, stream>>>(deg, psum);
  k_pscan  <<<1, 256, 0, stream>>>(psum, pofs);
  k_wroffs <<<196, 256, 0, stream>>>(deg, pofs, rs, bcur);
  // LDS-binned edge partition + layer-1 GEMM (independent, one launch)
  k_binGemm<<<200 + (NN + 63)/64, 256, 0, stream>>>(ei, bcur, pr, x, Bp1,
                                                    as1, ad1, h1h, als1, ald1);
  // exclusive-region CSR placement
  k_place  <<<196, 256, 0, stream>>>(rs, pr, csr);
  // layer 1 aggregate
  k_agg1m  <<<12500, 256, 0, stream>>>(rs, csr, h1h, als1, ald1, b1, g1h);
  // layer 2 GEMM
  k_gemm2m <<<(NN + 63)/64, 256, 0, stream>>>(g1h, Bp, as2, ad2, h2h, als2, ald2);
  // layer 2 aggregate + classifier scores
  k_agg2s  <<<12500, 256, 0, stream>>>(rs, csr, h2h, als2, ald2, b2, clW1,
                                       tWb, clW2, clb2, out);
}

// Round 12
// 217.398 us; speedup vs baseline: 6.2094x; 1.0802x over previous
//
#include <hip/hip_runtime.h>
#include <hip/hip_fp16.h>

#define NN 50000
#define NE 800000
#define FN 128
#define HH 256      // HEADS*HID
#define HID 64
#define NBKT 196    // 256-node buckets
#define CHUNK 4000  // edges per bin block; 200*4000 == NE

typedef _Float16 f16x8 __attribute__((ext_vector_type(8)));
typedef float f32x4 __attribute__((ext_vector_type(4)));

__device__ __forceinline__ float lrelu(float v){ return v >= 0.f ? v : 0.2f * v; }
__device__ __forceinline__ float elu_(float v){ return v > 0.f ? v : expm1f(v); }

__device__ __forceinline__ void unp4(const float2 r, float& f0, float& f1, float& f2, float& f3){
  const __half2* hp = (const __half2*)&r;
  float2 a = __half22float2(hp[0]);
  float2 b = __half22float2(hp[1]);
  f0 = a.x; f1 = a.y; f2 = b.x; f3 = b.y;
}

// ---------- merged: deg histogram + weight prep (W1,W2,Wh) + task encoder ----------
__global__ void k_misc(const int* __restrict__ ei, int* __restrict__ deg,
                       const float* __restrict__ W2, const float* __restrict__ W1,
                       __half* __restrict__ Bp, __half* __restrict__ Bp1, __half* __restrict__ Bwh,
                       const float* __restrict__ task, const float* __restrict__ W1t,
                       const float* __restrict__ b1t, const float* __restrict__ W2t,
                       const float* __restrict__ b2t, const float* __restrict__ clW1,
                       const float* __restrict__ clb1, float* __restrict__ tWb){
  int bid = blockIdx.x, t = threadIdx.x;
  if (bid < 3125){                       // k_deg: 3125*256 == NE
    int e = bid * 256 + t;
    atomicAdd(deg + ei[NE + e], 1);
  } else if (bid < 3151){                // prep: 26 blocks cover f<6656
    int f = (bid - 3125) * 256 + t;
    if (f < 2048){
      int lane = f & 63;
      int ct = (f >> 6) & 3, kt = f >> 8;
      int kbase = kt * 32 + (lane >> 4) * 8;
      int col = ct * 16 + (lane & 15);
#pragma unroll
      for (int i = 0; i < 8; ++i)
        Bp[(size_t)f * 8 + i] = (__half)W2[(kbase + i) * HID + col];
    } else if (f < 6144){
      int g = f - 2048;
      int lane = g & 63;
      int ct = (g >> 6) & 15, kt = g >> 10;
      int kbase = kt * 32 + (lane >> 4) * 8;
      int col = ct * 16 + (lane & 15);
#pragma unroll
      for (int i = 0; i < 8; ++i)
        Bp1[(size_t)g * 8 + i] = (__half)W1[(kbase + i) * HH + col];
    } else if (f < 6656){
      int g = f - 6144;                  // (kt*4+ct)*64+lane, kt<2, ct<4
      int lane = g & 63;
      int ct = (g >> 6) & 3, kt = g >> 8;
      int kbase = kt * 32 + (lane >> 4) * 8;
      int col = ct * 16 + (lane & 15);
#pragma unroll
      for (int i = 0; i < 8; ++i)
        Bwh[(size_t)g * 8 + i] = (__half)clW1[(kbase + i) * HID + col];
    }
  } else {                               // k_task: 1 block
    __shared__ float t1[16][64];
    __shared__ float t2[16][64];
    for (int idx = t; idx < 1024; idx += 256){
      int b = idx >> 6, c = idx & 63;
      float acc = b1t[c];
      for (int k = 0; k < 128; ++k) acc = fmaf(task[b*128 + k], W1t[k*64 + c], acc);
      t1[b][c] = fmaxf(acc, 0.f);
    }
    __syncthreads();
    for (int idx = t; idx < 1024; idx += 256){
      int b = idx >> 6, c = idx & 63;
      float acc = b2t[c];
      for (int k = 0; k < 64; ++k) acc = fmaf(t1[b][k], W2t[k*64 + c], acc);
      t2[b][c] = acc;
    }
    __syncthreads();
    for (int idx = t; idx < 1024; idx += 256){
      int b = idx >> 6, c = idx & 63;
      float acc = clb1[c];
      for (int k = 0; k < 64; ++k) acc = fmaf(t2[b][k], clW1[(64 + k)*64 + c], acc);
      tWb[idx] = acc;
    }
  }
}

__global__ void k_psum(const int* __restrict__ deg, int* __restrict__ psum){
  int b = blockIdx.x, t = threadIdx.x;
  int idx = b * 256 + t;
  int v = (idx < NN) ? deg[idx] : 0;
#pragma unroll
  for (int off = 32; off > 0; off >>= 1) v += __shfl_down(v, off);
  __shared__ int wsum[4];
  if ((t & 63) == 0) wsum[t >> 6] = v;
  __syncthreads();
  if (t == 0) psum[b] = wsum[0] + wsum[1] + wsum[2] + wsum[3];
}

__global__ void k_pscan(const int* __restrict__ psum, int* __restrict__ pofs){
  int t = threadIdx.x;            // 256 threads
  int lane = t & 63, wv = t >> 6;
  int v = (t < 196) ? psum[t] : 0;
  int iv = v;
#pragma unroll
  for (int off = 1; off < 64; off <<= 1){
    int u = __shfl_up(iv, off);
    if (lane >= off) iv += u;
  }
  __shared__ int wsum[4];
  if (lane == 63) wsum[wv] = iv;
  __syncthreads();
  int add = 0;
  for (int w = 0; w < wv; ++w) add += wsum[w];
  iv += add;
  if (t < 196) pofs[t] = iv - v;  // exclusive
}

__global__ void k_wroffs(const int* __restrict__ deg, const int* __restrict__ pofs,
                         int* __restrict__ rs, int* __restrict__ bcur){
  int b = blockIdx.x, t = threadIdx.x;
  int idx = b * 256 + t;
  int lane = t & 63, wv = t >> 6;
  int v = (idx < NN) ? deg[idx] : 0;
  int iv = v;
#pragma unroll
  for (int off = 1; off < 64; off <<= 1){
    int u = __shfl_up(iv, off);
    if (lane >= off) iv += u;
  }
  __shared__ int wsum[4];
  if (lane == 63) wsum[wv] = iv;
  __syncthreads();
  int add = pofs[b];
  for (int w = 0; w < wv; ++w) add += wsum[w];
  int excl = add + iv - v;
  if (idx < NN){
    rs[idx] = excl;
    if ((idx & 255) == 0) bcur[idx >> 8] = excl;   // bucket append cursor
  }
  if (idx == NN) rs[NN] = excl;
}

// ---------- merged: LDS-binned edge partition + (h1 = x @ W1 MFMA, fused alpha1) ----------
__global__ void k_binGemm(const int* __restrict__ ei, int* __restrict__ bcur, int2* __restrict__ pr,
                          const float* __restrict__ x, const __half* __restrict__ Bp1,
                          const float* __restrict__ as1, const float* __restrict__ ad1,
                          __half* __restrict__ h1h, float* __restrict__ als, float* __restrict__ ald){
  __shared__ int hist[NBKT];
  __shared__ int lstart[NBKT];
  __shared__ int gpos[NBKT];
  __shared__ int cnt[NBKT];
  __shared__ int2 stage[CHUNK];          // 32 KB
  int bid = blockIdx.x, t = threadIdx.x;
  if (bid < 200){                        // bin: 200*4000 == NE
    int e_base = bid * CHUNK;
    if (t < NBKT){ hist[t] = 0; cnt[t] = 0; }
    __syncthreads();
    for (int i = t; i < CHUNK; i += 256)
      atomicAdd(&hist[ei[NE + e_base + i] >> 8], 1);
    __syncthreads();
    {
      int lane = t & 63, wvi = t >> 6;
      int v = (t < NBKT) ? hist[t] : 0;
      int iv = v;
#pragma unroll
      for (int off = 1; off < 64; off <<= 1){
        int u = __shfl_up(iv, off);
        if (lane >= off) iv += u;
      }
      __shared__ int wsum[4];
      if (lane == 63) wsum[wvi] = iv;
      __syncthreads();
      int add = 0;
      for (int w = 0; w < wvi; ++w) add += wsum[w];
      iv += add;
      if (t < NBKT){
        lstart[t] = iv - v;
        gpos[t] = (v > 0) ? atomicAdd(&bcur[t], v) : 0;
      }
    }
    __syncthreads();
    for (int i = t; i < CHUNK; i += 256){
      int e = e_base + i;
      int s = ei[e], d = ei[NE + e];
      int bb = d >> 8;
      int r = atomicAdd(&cnt[bb], 1);
      stage[lstart[bb] + r] = make_int2(s, d);
    }
    __syncthreads();
    for (int i = t; i < CHUNK; i += 256){
      int2 p = stage[i];
      int bb = p.y >> 8;
      pr[gpos[bb] + (i - lstart[bb])] = p;
    }
    return;
  }
  // gemm1m part
  int blk = bid - 200;
  int wv = t >> 6, lane = t & 63;
  int n0 = blk * 64 + wv * 16;           // 16 rows per wave
  int arow = n0 + (lane & 15);
  if (arow > NN - 1) arow = NN - 1;      // clamp for loads; stores guarded
  const float* xbase = x + (size_t)arow * FN + (lane >> 4) * 8;
  const f16x8* bbase = (const f16x8*)Bp1 + lane;   // + (kt*16+ct)*64

  f32x4 acc[16];
#pragma unroll
  for (int ct = 0; ct < 16; ++ct) acc[ct] = (f32x4){0.f,0.f,0.f,0.f};

#pragma unroll
  for (int kt = 0; kt < 4; ++kt){
    float4 xa = *(const float4*)(xbase + kt * 32);
    float4 xb = *(const float4*)(xbase + kt * 32 + 4);
    f16x8 a;
    a[0] = (_Float16)xa.x; a[1] = (_Float16)xa.y; a[2] = (_Float16)xa.z; a[3] = (_Float16)xa.w;
    a[4] = (_Float16)xb.x; a[5] = (_Float16)xb.y; a[6] = (_Float16)xb.z; a[7] = (_Float16)xb.w;
#pragma unroll
    for (int ct = 0; ct < 16; ++ct)
      acc[ct] = __builtin_amdgcn_mfma_f32_16x16x32_f16(a, bbase[(kt*16 + ct) * 64], acc[ct], 0, 0, 0);
  }

  // C/D mapping: col = ct*16 + (lane&15), row = (lane>>4)*4 + i
  int c4 = lane & 15, g4 = lane >> 4;
#pragma unroll
  for (int ct = 0; ct < 16; ++ct){
#pragma unroll
    for (int i = 0; i < 4; ++i){
      int n = n0 + g4 * 4 + i;
      if (n < NN) h1h[(size_t)n * HH + ct * 16 + c4] = (__half)acc[ct][i];
    }
  }
#pragma unroll
  for (int h = 0; h < 4; ++h){
    float sa0 = as1[(h*4+0)*16 + c4], sa1 = as1[(h*4+1)*16 + c4];
    float sa2 = as1[(h*4+2)*16 + c4], sa3 = as1[(h*4+3)*16 + c4];
    float da0 = ad1[(h*4+0)*16 + c4], da1 = ad1[(h*4+1)*16 + c4];
    float da2 = ad1[(h*4+2)*16 + c4], da3 = ad1[(h*4+3)*16 + c4];
#pragma unroll
    for (int i = 0; i < 4; ++i){
      float vs = acc[h*4+0][i]*sa0 + acc[h*4+1][i]*sa1 + acc[h*4+2][i]*sa2 + acc[h*4+3][i]*sa3;
      float vd = acc[h*4+0][i]*da0 + acc[h*4+1][i]*da1 + acc[h*4+2][i]*da2 + acc[h*4+3][i]*da3;
#pragma unroll
      for (int off = 1; off < 16; off <<= 1){
        vs += __shfl_xor(vs, off);
        vd += __shfl_xor(vd, off);
      }
      if (c4 == 0){
        int n = n0 + g4 * 4 + i;
        if (n < NN){ als[n*4 + h] = vs; ald[n*4 + h] = vd; }
      }
    }
  }
}

// ---------- place: block b owns nodes [256b,256b+256) -> exclusive csr region ----------
__global__ void k_place(const int* __restrict__ rs, const int2* __restrict__ pr,
                        int* __restrict__ csr){
  __shared__ int lcur[256];
  int b = blockIdx.x, t = threadIdx.x;
  int nb = b * 256 + t;
  lcur[t] = (nb < NN) ? rs[nb] : 0;
  int base = rs[b * 256];
  int endn = (b + 1) * 256; if (endn > NN) endn = NN;
  int end = rs[endn];
  __syncthreads();
  for (int i = base + t; i < end; i += 256){
    int2 p = pr[i];
    int pos = atomicAdd(&lcur[p.y - b * 256], 1);
    csr[pos] = p.x;
  }
}

// ---------- fused layer-1 softmax weights + gather + ELU (wave per node) ----------
__global__ void k_agg1m(const int* __restrict__ rs, const int* __restrict__ csr,
                        const __half* __restrict__ h1h, const float* __restrict__ als,
                        const float* __restrict__ ald, const float* __restrict__ b1,
                        __half* __restrict__ g1h){
  int t = threadIdx.x, wv = t >> 6, lane = t & 63;
  int head = lane >> 4, q = lane & 15;
  int n = blockIdx.x * 4 + wv;
  int e0 = rs[n], e1 = rs[n + 1];
  int deg = e1 - e0;
  float adh = ald[n*4 + head];

  float w0r = 0.f, w1r = 0.f, w2r = 0.f, w3r = 0.f;
  int   s0r = 0,   s1r = 0,   s2r = 0,   s3r = 0;
  float den = 0.f;
  if (q      < deg){ s0r = csr[e0 + q];      w0r = expf(lrelu(als[s0r*4+head] + adh)); den += w0r; }
  if (q + 16 < deg){ s1r = csr[e0 + 16 + q]; w1r = expf(lrelu(als[s1r*4+head] + adh)); den += w1r; }
  if (q + 32 < deg){ s2r = csr[e0 + 32 + q]; w2r = expf(lrelu(als[s2r*4+head] + adh)); den += w2r; }
  if (q + 48 < deg){ s3r = csr[e0 + 48 + q]; w3r = expf(lrelu(als[s3r*4+head] + adh)); den += w3r; }
  for (int e = e0 + 64 + q; e < e1; e += 16) den += expf(lrelu(als[csr[e]*4+head] + adh));
  den += __shfl_xor(den, 1); den += __shfl_xor(den, 2);
  den += __shfl_xor(den, 4); den += __shfl_xor(den, 8);
  float selfw = expf(lrelu(als[n*4+head] + adh));
  float inv = 1.f / (den + selfw + 1e-16f);
  float wself = selfw * inv;

  float a0, a1, a2, a3;
  { float2 r = *(const float2*)(h1h + (size_t)n * HH + lane * 4);
    float f0,f1,f2,f3; unp4(r, f0,f1,f2,f3);
    a0 = wself*f0; a1 = wself*f1; a2 = wself*f2; a3 = wself*f3; }

  int hb = lane & 48;
  int cnt = deg < 64 ? deg : 64;
  auto pass = [&](float wp, int sp, int off){
    int lim = cnt - off; if (lim <= 0) return; if (lim > 16) lim = 16;
    for (int q2 = 0; q2 < lim; q2 += 4){          // wave-uniform trip count
      int j1 = q2 + 1, j2 = q2 + 2, j3 = q2 + 3;
      float m1 = (j1 < lim) ? inv : 0.f; if (j1 >= lim) j1 = q2;
      float m2 = (j2 < lim) ? inv : 0.f; if (j2 >= lim) j2 = q2;
      float m3 = (j3 < lim) ? inv : 0.f; if (j3 >= lim) j3 = q2;
      float wa = inv * __shfl(wp, hb + q2); int sa = __shfl(sp, hb + q2);
      float wb = m1  * __shfl(wp, hb + j1); int sb = __shfl(sp, hb + j1);
      float wc = m2  * __shfl(wp, hb + j2); int sc = __shfl(sp, hb + j2);
      float wd = m3  * __shfl(wp, hb + j3); int sd = __shfl(sp, hb + j3);
      float2 ra = *(const float2*)(h1h + (size_t)sa * HH + lane * 4);
      float2 rb = *(const float2*)(h1h + (size_t)sb * HH + lane * 4);
      float2 rc = *(const float2*)(h1h + (size_t)sc * HH + lane * 4);
      float2 rd = *(const float2*)(h1h + (size_t)sd * HH + lane * 4);
      float f0,f1,f2,f3;
      unp4(ra, f0,f1,f2,f3); a0=fmaf(wa,f0,a0); a1=fmaf(wa,f1,a1); a2=fmaf(wa,f2,a2); a3=fmaf(wa,f3,a3);
      unp4(rb, f0,f1,f2,f3); a0=fmaf(wb,f0,a0); a1=fmaf(wb,f1,a1); a2=fmaf(wb,f2,a2); a3=fmaf(wb,f3,a3);
      unp4(rc, f0,f1,f2,f3); a0=fmaf(wc,f0,a0); a1=fmaf(wc,f1,a1); a2=fmaf(wc,f2,a2); a3=fmaf(wc,f3,a3);
      unp4(rd, f0,f1,f2,f3); a0=fmaf(wd,f0,a0); a1=fmaf(wd,f1,a1); a2=fmaf(wd,f2,a2); a3=fmaf(wd,f3,a3);
    }
  };
  pass(w0r, s0r, 0); pass(w1r, s1r, 16); pass(w2r, s2r, 32); pass(w3r, s3r, 48);
  // rare tail: deg > 64, recompute weights directly (uniform loop)
  for (int e = e0 + 64; e < e1; ++e){
    int s = csr[e];
    float w = inv * expf(lrelu(als[s*4+head] + adh));
    float2 r = *(const float2*)(h1h + (size_t)s * HH + lane * 4);
    float f0,f1,f2,f3; unp4(r, f0,f1,f2,f3);
    a0=fmaf(w,f0,a0); a1=fmaf(w,f1,a1); a2=fmaf(w,f2,a2); a3=fmaf(w,f3,a3);
  }

  float4 b4 = *(const float4*)(b1 + lane * 4);
  __half2 p0 = __floats2half2_rn(elu_(a0 + b4.x), elu_(a1 + b4.y));
  __half2 p1 = __floats2half2_rn(elu_(a2 + b4.z), elu_(a3 + b4.w));
  float2 outv; ((__half2*)&outv)[0] = p0; ((__half2*)&outv)[1] = p1;
  *(float2*)(g1h + (size_t)n * HH + lane * 4) = outv;
}

// ---------- h2 = g1 @ W2 via MFMA 16x16x32_f16, fused alpha2 ----------
__global__ void k_gemm2m(const __half* __restrict__ g1h, const __half* __restrict__ Bp,
                         const float* __restrict__ as2, const float* __restrict__ ad2,
                         __half* __restrict__ h2h, float* __restrict__ als2, float* __restrict__ ald2){
  int t = threadIdx.x, wv = t >> 6, lane = t & 63;
  int n0 = blockIdx.x * 64 + wv * 16;    // 16 rows per wave
  int arow = n0 + (lane & 15);
  if (arow > NN - 1) arow = NN - 1;      // clamp for loads; stores guarded
  const _Float16* gbase = (const _Float16*)g1h + (size_t)arow * HH + (lane >> 4) * 8;
  const f16x8* bbase = (const f16x8*)Bp + lane;   // + (kt*4+ct)*64

  f32x4 acc0 = {0.f,0.f,0.f,0.f}, acc1 = {0.f,0.f,0.f,0.f};
  f32x4 acc2 = {0.f,0.f,0.f,0.f}, acc3 = {0.f,0.f,0.f,0.f};
#pragma unroll
  for (int kt = 0; kt < 8; ++kt){
    f16x8 a = *(const f16x8*)(gbase + kt * 32);
    acc0 = __builtin_amdgcn_mfma_f32_16x16x32_f16(a, bbase[(kt*4 + 0) * 64], acc0, 0, 0, 0);
    acc1 = __builtin_amdgcn_mfma_f32_16x16x32_f16(a, bbase[(kt*4 + 1) * 64], acc1, 0, 0, 0);
    acc2 = __builtin_amdgcn_mfma_f32_16x16x32_f16(a, bbase[(kt*4 + 2) * 64], acc2, 0, 0, 0);
    acc3 = __builtin_amdgcn_mfma_f32_16x16x32_f16(a, bbase[(kt*4 + 3) * 64], acc3, 0, 0, 0);
  }
  int c4 = lane & 15, g4 = lane >> 4;
  float as2v0 = as2[c4], as2v1 = as2[16 + c4], as2v2 = as2[32 + c4], as2v3 = as2[48 + c4];
  float ad2v0 = ad2[c4], ad2v1 = ad2[16 + c4], ad2v2 = ad2[32 + c4], ad2v3 = ad2[48 + c4];
  float vs[4], vd[4];
#pragma unroll
  for (int i = 0; i < 4; ++i){
    int n = n0 + g4 * 4 + i;
    if (n < NN){
      h2h[(size_t)n * HID + c4]      = (__half)acc0[i];
      h2h[(size_t)n * HID + 16 + c4] = (__half)acc1[i];
      h2h[(size_t)n * HID + 32 + c4] = (__half)acc2[i];
      h2h[(size_t)n * HID + 48 + c4] = (__half)acc3[i];
    }
    vs[i] = acc0[i]*as2v0 + acc1[i]*as2v1 + acc2[i]*as2v2 + acc3[i]*as2v3;
    vd[i] = acc0[i]*ad2v0 + acc1[i]*ad2v1 + acc2[i]*ad2v2 + acc3[i]*ad2v3;
  }
#pragma unroll
  for (int off = 1; off < 16; off <<= 1){
#pragma unroll
    for (int i = 0; i < 4; ++i){
      vs[i] += __shfl_xor(vs[i], off);
      vd[i] += __shfl_xor(vd[i], off);
    }
  }
  if (c4 == 0){
#pragma unroll
    for (int i = 0; i < 4; ++i){
      int n = n0 + g4 * 4 + i;
      if (n < NN){ als2[n] = vs[i]; ald2[n] = vd[i]; }
    }
  }
}

// ---------- fused layer-2 weights + gather + ELU -> o2 fp16 (wave per node) ----------
__global__ void k_agg2(const int* __restrict__ rs, const int* __restrict__ csr,
                       const __half* __restrict__ h2h, const float* __restrict__ als,
                       const float* __restrict__ ald, const float* __restrict__ b2,
                       __half* __restrict__ o2h){
  int t = threadIdx.x, wv = t >> 6, lane = t & 63;
  int g16 = lane >> 4, c4 = lane & 15;
  int n = blockIdx.x * 4 + wv;
  int e0 = rs[n], e1 = rs[n + 1];
  int deg = e1 - e0;
  float adn = ald[n];

  float wr = 0.f; int sr = 0;
  float den = 0.f;
  if (lane < deg){ sr = csr[e0 + lane]; wr = expf(lrelu(als[sr] + adn)); den = wr; }
  for (int e = e0 + 64 + lane; e < e1; e += 64) den += expf(lrelu(als[csr[e]] + adn));
#pragma unroll
  for (int off = 1; off <= 32; off <<= 1) den += __shfl_xor(den, off);
  float selfw = expf(lrelu(als[n] + adn));
  float inv = 1.f / (den + selfw + 1e-16f);
  float wself = selfw * inv;

  float a0 = 0.f, a1 = 0.f, a2 = 0.f, a3 = 0.f;
  int cnt = deg < 64 ? deg : 64;
  for (int base = 0; base < cnt; base += 8){    // uniform trip count; shfl legal
    int idx = base + g16;
    int  i1 = (idx < cnt) ? idx : 0;
    float wa = ((idx < cnt) ? inv : 0.f) * __shfl(wr, i1);
    int   sa = __shfl(sr, i1);
    int idxb = idx + 4;
    int  i2 = (idxb < cnt) ? idxb : 0;
    float wb = ((idxb < cnt) ? inv : 0.f) * __shfl(wr, i2);
    int   sb = __shfl(sr, i2);
    float2 r0 = *(const float2*)(h2h + (size_t)sa * HID + c4 * 4);
    float2 r1 = *(const float2*)(h2h + (size_t)sb * HID + c4 * 4);
    float f0,f1,f2,f3;
    unp4(r0, f0,f1,f2,f3); a0=fmaf(wa,f0,a0); a1=fmaf(wa,f1,a1); a2=fmaf(wa,f2,a2); a3=fmaf(wa,f3,a3);
    unp4(r1, f0,f1,f2,f3); a0=fmaf(wb,f0,a0); a1=fmaf(wb,f1,a1); a2=fmaf(wb,f2,a2); a3=fmaf(wb,f3,a3);
  }
  // rare tail: deg > 64, recompute (no cross-lane ops -> divergence safe)
  for (int e = e0 + 64 + g16; e < e1; e += 4){
    int s = csr[e];
    float w = inv * expf(lrelu(als[s] + adn));
    float2 r = *(const float2*)(h2h + (size_t)s * HID + c4 * 4);
    float f0,f1,f2,f3; unp4(r, f0,f1,f2,f3);
    a0=fmaf(w,f0,a0); a1=fmaf(w,f1,a1); a2=fmaf(w,f2,a2); a3=fmaf(w,f3,a3);
  }

  a0 += __shfl_xor(a0, 16); a1 += __shfl_xor(a1, 16); a2 += __shfl_xor(a2, 16); a3 += __shfl_xor(a3, 16);
  a0 += __shfl_xor(a0, 32); a1 += __shfl_xor(a1, 32); a2 += __shfl_xor(a2, 32); a3 += __shfl_xor(a3, 32);
  if (lane < 16){
    float2 r = *(const float2*)(h2h + (size_t)n * HID + lane * 4);
    float f0,f1,f2,f3; unp4(r, f0,f1,f2,f3);
    a0 = fmaf(wself, f0, a0); a1 = fmaf(wself, f1, a1); a2 = fmaf(wself, f2, a2); a3 = fmaf(wself, f3, a3);
    float4 b4 = *(const float4*)(b2 + lane * 4);
    __half2 p0 = __floats2half2_rn(elu_(a0 + b4.x), elu_(a1 + b4.y));
    __half2 p1 = __floats2half2_rn(elu_(a2 + b4.z), elu_(a3 + b4.w));
    float2 outv; ((__half2*)&outv)[0] = p0; ((__half2*)&outv)[1] = p1;
    *(float2*)(o2h + (size_t)n * HID + lane * 4) = outv;
  }
}

// ---------- hW = o2 @ Wh via MFMA + fused scores (16 nodes/wave) ----------
__global__ void k_hws(const __half* __restrict__ o2h, const __half* __restrict__ Bwh,
                      const float* __restrict__ tWb, const float* __restrict__ w2,
                      const float* __restrict__ b2s, float* __restrict__ out){
  __shared__ float tws[1024];
  __shared__ float w2s[64];
  int t = threadIdx.x, wv = t >> 6, lane = t & 63;
  for (int i = t; i < 1024; i += 256) tws[i] = tWb[i];
  if (t < 64) w2s[t] = w2[t];
  __syncthreads();

  int n0 = blockIdx.x * 64 + wv * 16;    // 16 rows per wave
  int arow = n0 + (lane & 15);
  if (arow > NN - 1) arow = NN - 1;
  const _Float16* obase = (const _Float16*)o2h + (size_t)arow * HID + (lane >> 4) * 8;
  const f16x8* bbase = (const f16x8*)Bwh + lane;   // + (kt*4+ct)*64

  f32x4 acc[4];
#pragma unroll
  for (int ct = 0; ct < 4; ++ct) acc[ct] = (f32x4){0.f,0.f,0.f,0.f};
#pragma unroll
  for (int kt = 0; kt < 2; ++kt){
    f16x8 a = *(const f16x8*)(obase + kt * 32);
#pragma unroll
    for (int ct = 0; ct < 4; ++ct)
      acc[ct] = __builtin_amdgcn_mfma_f32_16x16x32_f16(a, bbase[(kt*4 + ct) * 64], acc[ct], 0, 0, 0);
  }
  // C layout: col = ct*16 + c4, row = g4*4 + i   (16 nodes n0+row)
  int c4 = lane & 15, g4 = lane >> 4;
  float wv0 = w2s[c4], wv1 = w2s[16 + c4], wv2 = w2s[32 + c4], wv3 = w2s[48 + c4];
  float bias = b2s[0];
#pragma unroll
  for (int i = 0; i < 4; ++i){
    int n = n0 + g4 * 4 + i;
    float v[16];
#pragma unroll
    for (int b = 0; b < 16; ++b){
      const float* twb = tws + b * 64;
      v[b] = fmaxf(acc[0][i] + twb[c4], 0.f)      * wv0
           + fmaxf(acc[1][i] + twb[16 + c4], 0.f) * wv1
           + fmaxf(acc[2][i] + twb[32 + c4], 0.f) * wv2
           + fmaxf(acc[3][i] + twb[48 + c4], 0.f) * wv3;
    }
    // 16-value butterfly over the 16-lane group (masks 8,4,2,1)
    bool h3 = (lane & 8) != 0;
    float u[8];
#pragma unroll
    for (int j = 0; j < 8; ++j){
      float keep = h3 ? v[j+8] : v[j];
      float send = h3 ? v[j]   : v[j+8];
      u[j] = keep + __shfl_xor(send, 8);
    }
    bool h2b = (lane & 4) != 0;
    float p[4];
#pragma unroll
    for (int j = 0; j < 4; ++j){
      float keep = h2b ? u[j+2+2] : u[j];
      float send = h2b ? u[j]     : u[j+4];
      p[j] = keep + __shfl_xor(send, 4);
    }
    bool h1b = (lane & 2) != 0;
    float qq[2];
#pragma unroll
    for (int j = 0; j < 2; ++j){
      float keep = h1b ? p[j+2] : p[j];
      float send = h1b ? p[j]   : p[j+2];
      qq[j] = keep + __shfl_xor(send, 2);
    }
    bool h0 = (lane & 1) != 0;
    float keep = h0 ? qq[1] : qq[0];
    float send = h0 ? qq[0] : qq[1];
    float z = keep + __shfl_xor(send, 1);
    // lane holds score for batch b = c4, node n
    if (n < NN) out[(size_t)c4 * NN + n] = z + bias;
  }
}

extern "C" void kernel_launch(void* const* d_in, const int* in_sizes, int n_in,
                              void* d_out, int out_size, void* d_ws, size_t ws_size,
                              hipStream_t stream){
  const float* x    = (const float*)d_in[0];
  const int*   ei   = (const int*)  d_in[1];
  const float* task = (const float*)d_in[2];
  const float* W1   = (const float*)d_in[3];
  const float* as1  = (const float*)d_in[4];
  const float* ad1  = (const float*)d_in[5];
  const float* b1   = (const float*)d_in[6];
  const float* W2   = (const float*)d_in[7];
  const float* as2  = (const float*)d_in[8];
  const float* ad2  = (const float*)d_in[9];
  const float* b2   = (const float*)d_in[10];
  const float* teW1 = (const float*)d_in[11];
  const float* teb1 = (const float*)d_in[12];
  const float* teW2 = (const float*)d_in[13];
  const float* teb2 = (const float*)d_in[14];
  const float* clW1 = (const float*)d_in[15];
  const float* clb1 = (const float*)d_in[16];
  const float* clW2 = (const float*)d_in[17];
  const float* clb2 = (const float*)d_in[18];
  float* out = (float*)d_out;
  float* ws  = (float*)d_ws;

  // workspace layout (float-sized slots)
  __half* h1h  = (__half*)ws;                    // 12.8M halfs -> 6.4M floats
  float* als1  = ws + 6400000;                   // 200,000
  float* ald1  = als1 + 200000;                  // 200,000
  __half* g1h  = (__half*)(ald1 + 200000);       // 12.8M halfs -> 6.4M floats
  __half* h2h  = (__half*)(ald1 + 200000 + 6400000);  // 3.2M halfs -> 1.6M floats
  float* als2  = ald1 + 200000 + 6400000 + 1600000;   // 50,000
  float* ald2  = als2 + 50000;                   // 50,000
  float* tWb   = ald2 + 50000;                   // 1,024
  int*   deg   = (int*)(tWb + 1024);             // 50,000
  int*   rs    = deg + 50000;                    // 50,001 (+pad)
  int*   csr   = rs + 50004;                     // 800,000
  int*   psum  = csr + 800000;                   // 256
  int*   pofs  = psum + 256;                     // 256
  int*   bcur  = pofs + 256;                     // 256
  __half* Bp   = (__half*)(bcur + 256);          // 16,384 halfs (MFMA-ordered W2)
  __half* Bp1  = Bp + 16384;                     // 32,768 halfs (MFMA-ordered W1)
  __half* Bwh  = Bp1 + 32768;                    // 4,096 halfs (MFMA-ordered Wh)
  int2*  pr    = (int2*)(Bwh + 4096);            // 800,000 pairs (6.4 MB)
  __half* o2h  = (__half*)(pr + 800000);         // 3.2M halfs (o2, fp16)

  hipMemsetAsync(deg, 0, 50000 * sizeof(int), stream);
  // deg histogram + weight prep + task encoder (independent work, one launch)
  k_misc   <<<3152, 256, 0, stream>>>(ei, deg, W2, W1, Bp, Bp1, Bwh,
                                      task, teW1, teb1, teW2, teb2, clW1, clb1, tWb);
  k_psum   <<<196, 256, 0, stream>>>(deg, psum);
  k_pscan  <<<1, 256, 0, stream>>>(psum, pofs);
  k_wroffs <<<196, 256, 0, stream>>>(deg, pofs, rs, bcur);
  // LDS-binned edge partition + layer-1 GEMM (independent, one launch)
  k_binGemm<<<200 + (NN + 63)/64, 256, 0, stream>>>(ei, bcur, pr, x, Bp1,
                                                    as1, ad1, h1h, als1, ald1);
  // exclusive-region CSR placement
  k_place  <<<196, 256, 0, stream>>>(rs, pr, csr);
  // layer 1 aggregate
  k_agg1m  <<<12500, 256, 0, stream>>>(rs, csr, h1h, als1, ald1, b1, g1h);
  // layer 2 GEMM
  k_gemm2m <<<(NN + 63)/64, 256, 0, stream>>>(g1h, Bp, as2, ad2, h2h, als2, ald2);
  // layer 2 aggregate -> o2 (fp16)
  k_agg2   <<<12500, 256, 0, stream>>>(rs, csr, h2h, als2, ald2, b2, o2h);
  // hW MFMA + fused scores
  k_hws    <<<(NN + 63)/64, 256, 0, stream>>>(o2h, Bwh, tWb, clW2, clb2, out);
}

// Round 13
// 210.372 us; speedup vs baseline: 6.4168x; 1.0334x over previous
//
#include <hip/hip_runtime.h>
#include <hip/hip_fp16.h>

#define NN 50000
#define NE 800000
#define FN 128
#define HH 256      // HEADS*HID
#define HID 64
#define NBKT 196    // 256-node buckets
#define CHUNK 4000  // edges per bin block; 200*4000 == NE

typedef _Float16 f16x8 __attribute__((ext_vector_type(8)));
typedef float f32x4 __attribute__((ext_vector_type(4)));

__device__ __forceinline__ float lrelu(float v){ return v >= 0.f ? v : 0.2f * v; }
__device__ __forceinline__ float elu_(float v){ return v > 0.f ? v : expm1f(v); }

__device__ __forceinline__ void unp4(const float2 r, float& f0, float& f1, float& f2, float& f3){
  const __half2* hp = (const __half2*)&r;
  float2 a = __half22float2(hp[0]);
  float2 b = __half22float2(hp[1]);
  f0 = a.x; f1 = a.y; f2 = b.x; f3 = b.y;
}

// ---------- merged: deg histogram + weight prep (W1,W2,Wh) + task encoder ----------
__global__ void k_misc(const int* __restrict__ ei, int* __restrict__ deg,
                       const float* __restrict__ W2, const float* __restrict__ W1,
                       __half* __restrict__ Bp, __half* __restrict__ Bp1, __half* __restrict__ Bwh,
                       const float* __restrict__ task, const float* __restrict__ W1t,
                       const float* __restrict__ b1t, const float* __restrict__ W2t,
                       const float* __restrict__ b2t, const float* __restrict__ clW1,
                       const float* __restrict__ clb1, float* __restrict__ tWb){
  int bid = blockIdx.x, t = threadIdx.x;
  if (bid < 3125){                       // k_deg: 3125*256 == NE
    int e = bid * 256 + t;
    atomicAdd(deg + ei[NE + e], 1);
  } else if (bid < 3151){                // prep: 26 blocks cover f<6656
    int f = (bid - 3125) * 256 + t;
    if (f < 2048){
      int lane = f & 63;
      int ct = (f >> 6) & 3, kt = f >> 8;
      int kbase = kt * 32 + (lane >> 4) * 8;
      int col = ct * 16 + (lane & 15);
#pragma unroll
      for (int i = 0; i < 8; ++i)
        Bp[(size_t)f * 8 + i] = (__half)W2[(kbase + i) * HID + col];
    } else if (f < 6144){
      int g = f - 2048;
      int lane = g & 63;
      int ct = (g >> 6) & 15, kt = g >> 10;
      int kbase = kt * 32 + (lane >> 4) * 8;
      int col = ct * 16 + (lane & 15);
#pragma unroll
      for (int i = 0; i < 8; ++i)
        Bp1[(size_t)g * 8 + i] = (__half)W1[(kbase + i) * HH + col];
    } else if (f < 6656){
      int g = f - 6144;                  // (kt*4+ct)*64+lane, kt<2, ct<4
      int lane = g & 63;
      int ct = (g >> 6) & 3, kt = g >> 8;
      int kbase = kt * 32 + (lane >> 4) * 8;
      int col = ct * 16 + (lane & 15);
#pragma unroll
      for (int i = 0; i < 8; ++i)
        Bwh[(size_t)g * 8 + i] = (__half)clW1[(kbase + i) * HID + col];
    }
  } else {                               // k_task: 1 block
    __shared__ float t1[16][64];
    __shared__ float t2[16][64];
    for (int idx = t; idx < 1024; idx += 256){
      int b = idx >> 6, c = idx & 63;
      float acc = b1t[c];
      for (int k = 0; k < 128; ++k) acc = fmaf(task[b*128 + k], W1t[k*64 + c], acc);
      t1[b][c] = fmaxf(acc, 0.f);
    }
    __syncthreads();
    for (int idx = t; idx < 1024; idx += 256){
      int b = idx >> 6, c = idx & 63;
      float acc = b2t[c];
      for (int k = 0; k < 64; ++k) acc = fmaf(t1[b][k], W2t[k*64 + c], acc);
      t2[b][c] = acc;
    }
    __syncthreads();
    for (int idx = t; idx < 1024; idx += 256){
      int b = idx >> 6, c = idx & 63;
      float acc = clb1[c];
      for (int k = 0; k < 64; ++k) acc = fmaf(t2[b][k], clW1[(64 + k)*64 + c], acc);
      tWb[idx] = acc;
    }
  }
}

__global__ void k_psum(const int* __restrict__ deg, int* __restrict__ psum){
  int b = blockIdx.x, t = threadIdx.x;
  int idx = b * 256 + t;
  int v = (idx < NN) ? deg[idx] : 0;
#pragma unroll
  for (int off = 32; off > 0; off >>= 1) v += __shfl_down(v, off);
  __shared__ int wsum[4];
  if ((t & 63) == 0) wsum[t >> 6] = v;
  __syncthreads();
  if (t == 0) psum[b] = wsum[0] + wsum[1] + wsum[2] + wsum[3];
}

// wroffs with inlined chunk-scan (replaces k_pscan): every block redundantly
// scans the 196 chunk sums, then does its own 256-node exclusive scan.
__global__ void k_wroffs(const int* __restrict__ deg, const int* __restrict__ psum,
                         int* __restrict__ rs, int* __restrict__ bcur){
  __shared__ int wsA[4];
  __shared__ int wsB[4];
  __shared__ int pofsArr[256];
  int b = blockIdx.x, t = threadIdx.x;
  int lane = t & 63, wv = t >> 6;
  {
    int v = (t < NBKT) ? psum[t] : 0;
    int iv = v;
#pragma unroll
    for (int off = 1; off < 64; off <<= 1){
      int u = __shfl_up(iv, off);
      if (lane >= off) iv += u;
    }
    if (lane == 63) wsA[wv] = iv;
    __syncthreads();
    int add = 0;
    for (int w = 0; w < wv; ++w) add += wsA[w];
    pofsArr[t] = iv + add - v;           // exclusive chunk prefix
  }
  __syncthreads();
  int idx = b * 256 + t;
  int v = (idx < NN) ? deg[idx] : 0;
  int iv = v;
#pragma unroll
  for (int off = 1; off < 64; off <<= 1){
    int u = __shfl_up(iv, off);
    if (lane >= off) iv += u;
  }
  if (lane == 63) wsB[wv] = iv;
  __syncthreads();
  int add = pofsArr[b];
  for (int w = 0; w < wv; ++w) add += wsB[w];
  int excl = add + iv - v;
  if (idx < NN){
    rs[idx] = excl;
    if ((idx & 255) == 0) bcur[idx >> 8] = excl;   // bucket append cursor
  }
  if (idx == NN) rs[NN] = excl;
}

// ---------- merged: LDS-binned edge partition (packed u32) + (h1 = x @ W1 MFMA) ----------
// packed pair: src(16b) | dlocal(8b)<<16 | bucket(8b)<<24
__global__ void k_binGemm(const int* __restrict__ ei, int* __restrict__ bcur,
                          unsigned* __restrict__ pr,
                          const float* __restrict__ x, const __half* __restrict__ Bp1,
                          const float* __restrict__ as1, const float* __restrict__ ad1,
                          __half* __restrict__ h1h, float* __restrict__ als, float* __restrict__ ald){
  __shared__ int hist[NBKT];
  __shared__ int lstart[NBKT];
  __shared__ int gpos[NBKT];
  __shared__ int cnt[NBKT];
  __shared__ unsigned stage[CHUNK];      // 16 KB
  int bid = blockIdx.x, t = threadIdx.x;
  if (bid < 200){                        // bin: 200*4000 == NE
    int e_base = bid * CHUNK;
    if (t < NBKT){ hist[t] = 0; cnt[t] = 0; }
    __syncthreads();
    for (int i = t; i < CHUNK; i += 256)
      atomicAdd(&hist[ei[NE + e_base + i] >> 8], 1);
    __syncthreads();
    {
      int lane = t & 63, wvi = t >> 6;
      int v = (t < NBKT) ? hist[t] : 0;
      int iv = v;
#pragma unroll
      for (int off = 1; off < 64; off <<= 1){
        int u = __shfl_up(iv, off);
        if (lane >= off) iv += u;
      }
      __shared__ int wsum[4];
      if (lane == 63) wsum[wvi] = iv;
      __syncthreads();
      int add = 0;
      for (int w = 0; w < wvi; ++w) add += wsum[w];
      iv += add;
      if (t < NBKT){
        lstart[t] = iv - v;
        gpos[t] = (v > 0) ? atomicAdd(&bcur[t], v) : 0;
      }
    }
    __syncthreads();
    for (int i = t; i < CHUNK; i += 256){
      int e = e_base + i;
      int s = ei[e], d = ei[NE + e];
      int bb = d >> 8;
      int r = atomicAdd(&cnt[bb], 1);
      stage[lstart[bb] + r] = (unsigned)s | ((unsigned)(d & 255) << 16) | ((unsigned)bb << 24);
    }
    __syncthreads();
    for (int i = t; i < CHUNK; i += 256){
      unsigned p = stage[i];
      int bb = p >> 24;
      pr[gpos[bb] + (i - lstart[bb])] = p;
    }
    return;
  }
  // gemm1m part
  int blk = bid - 200;
  int wv = t >> 6, lane = t & 63;
  int n0 = blk * 64 + wv * 16;           // 16 rows per wave
  int arow = n0 + (lane & 15);
  if (arow > NN - 1) arow = NN - 1;      // clamp for loads; stores guarded
  const float* xbase = x + (size_t)arow * FN + (lane >> 4) * 8;
  const f16x8* bbase = (const f16x8*)Bp1 + lane;   // + (kt*16+ct)*64

  f32x4 acc[16];
#pragma unroll
  for (int ct = 0; ct < 16; ++ct) acc[ct] = (f32x4){0.f,0.f,0.f,0.f};

#pragma unroll
  for (int kt = 0; kt < 4; ++kt){
    float4 xa = *(const float4*)(xbase + kt * 32);
    float4 xb = *(const float4*)(xbase + kt * 32 + 4);
    f16x8 a;
    a[0] = (_Float16)xa.x; a[1] = (_Float16)xa.y; a[2] = (_Float16)xa.z; a[3] = (_Float16)xa.w;
    a[4] = (_Float16)xb.x; a[5] = (_Float16)xb.y; a[6] = (_Float16)xb.z; a[7] = (_Float16)xb.w;
#pragma unroll
    for (int ct = 0; ct < 16; ++ct)
      acc[ct] = __builtin_amdgcn_mfma_f32_16x16x32_f16(a, bbase[(kt*16 + ct) * 64], acc[ct], 0, 0, 0);
  }

  // C/D mapping: col = ct*16 + (lane&15), row = (lane>>4)*4 + i
  int c4 = lane & 15, g4 = lane >> 4;
#pragma unroll
  for (int ct = 0; ct < 16; ++ct){
#pragma unroll
    for (int i = 0; i < 4; ++i){
      int n = n0 + g4 * 4 + i;
      if (n < NN) h1h[(size_t)n * HH + ct * 16 + c4] = (__half)acc[ct][i];
    }
  }
#pragma unroll
  for (int h = 0; h < 4; ++h){
    float sa0 = as1[(h*4+0)*16 + c4], sa1 = as1[(h*4+1)*16 + c4];
    float sa2 = as1[(h*4+2)*16 + c4], sa3 = as1[(h*4+3)*16 + c4];
    float da0 = ad1[(h*4+0)*16 + c4], da1 = ad1[(h*4+1)*16 + c4];
    float da2 = ad1[(h*4+2)*16 + c4], da3 = ad1[(h*4+3)*16 + c4];
#pragma unroll
    for (int i = 0; i < 4; ++i){
      float vs = acc[h*4+0][i]*sa0 + acc[h*4+1][i]*sa1 + acc[h*4+2][i]*sa2 + acc[h*4+3][i]*sa3;
      float vd = acc[h*4+0][i]*da0 + acc[h*4+1][i]*da1 + acc[h*4+2][i]*da2 + acc[h*4+3][i]*da3;
#pragma unroll
      for (int off = 1; off < 16; off <<= 1){
        vs += __shfl_xor(vs, off);
        vd += __shfl_xor(vd, off);
      }
      if (c4 == 0){
        int n = n0 + g4 * 4 + i;
        if (n < NN){ als[n*4 + h] = vs; ald[n*4 + h] = vd; }
      }
    }
  }
}

// ---------- place: block b owns nodes [256b,256b+256) -> exclusive csr region ----------
__global__ void k_place(const int* __restrict__ rs, const unsigned* __restrict__ pr,
                        int* __restrict__ csr){
  __shared__ int lcur[256];
  int b = blockIdx.x, t = threadIdx.x;
  int nb = b * 256 + t;
  lcur[t] = (nb < NN) ? rs[nb] : 0;
  int base = rs[b * 256];
  int endn = (b + 1) * 256; if (endn > NN) endn = NN;
  int end = rs[endn];
  __syncthreads();
  for (int i = base + t; i < end; i += 256){
    unsigned p = pr[i];
    int pos = atomicAdd(&lcur[(p >> 16) & 255], 1);
    csr[pos] = (int)(p & 0xFFFFu);
  }
}

// ---------- fused layer-1 softmax weights + gather + ELU (wave per node) ----------
__global__ void k_agg1m(const int* __restrict__ rs, const int* __restrict__ csr,
                        const __half* __restrict__ h1h, const float* __restrict__ als,
                        const float* __restrict__ ald, const float* __restrict__ b1,
                        __half* __restrict__ g1h){
  int t = threadIdx.x, wv = t >> 6, lane = t & 63;
  int head = lane >> 4, q = lane & 15;
  int n = blockIdx.x * 4 + wv;
  int e0 = rs[n], e1 = rs[n + 1];
  int deg = e1 - e0;
  float adh = ald[n*4 + head];

  float w0r = 0.f, w1r = 0.f, w2r = 0.f, w3r = 0.f;
  int   s0r = 0,   s1r = 0,   s2r = 0,   s3r = 0;
  float den = 0.f;
  if (q      < deg){ s0r = csr[e0 + q];      w0r = expf(lrelu(als[s0r*4+head] + adh)); den += w0r; }
  if (q + 16 < deg){ s1r = csr[e0 + 16 + q]; w1r = expf(lrelu(als[s1r*4+head] + adh)); den += w1r; }
  if (q + 32 < deg){ s2r = csr[e0 + 32 + q]; w2r = expf(lrelu(als[s2r*4+head] + adh)); den += w2r; }
  if (q + 48 < deg){ s3r = csr[e0 + 48 + q]; w3r = expf(lrelu(als[s3r*4+head] + adh)); den += w3r; }
  for (int e = e0 + 64 + q; e < e1; e += 16) den += expf(lrelu(als[csr[e]*4+head] + adh));
  den += __shfl_xor(den, 1); den += __shfl_xor(den, 2);
  den += __shfl_xor(den, 4); den += __shfl_xor(den, 8);
  float selfw = expf(lrelu(als[n*4+head] + adh));
  float inv = 1.f / (den + selfw + 1e-16f);
  float wself = selfw * inv;

  float a0, a1, a2, a3;
  { float2 r = *(const float2*)(h1h + (size_t)n * HH + lane * 4);
    float f0,f1,f2,f3; unp4(r, f0,f1,f2,f3);
    a0 = wself*f0; a1 = wself*f1; a2 = wself*f2; a3 = wself*f3; }

  int hb = lane & 48;
  int cnt = deg < 64 ? deg : 64;
  auto pass = [&](float wp, int sp, int off){
    int lim = cnt - off; if (lim <= 0) return; if (lim > 16) lim = 16;
    for (int q2 = 0; q2 < lim; q2 += 4){          // wave-uniform trip count
      int j1 = q2 + 1, j2 = q2 + 2, j3 = q2 + 3;
      float m1 = (j1 < lim) ? inv : 0.f; if (j1 >= lim) j1 = q2;
      float m2 = (j2 < lim) ? inv : 0.f; if (j2 >= lim) j2 = q2;
      float m3 = (j3 < lim) ? inv : 0.f; if (j3 >= lim) j3 = q2;
      float wa = inv * __shfl(wp, hb + q2); int sa = __shfl(sp, hb + q2);
      float wb = m1  * __shfl(wp, hb + j1); int sb = __shfl(sp, hb + j1);
      float wc = m2  * __shfl(wp, hb + j2); int sc = __shfl(sp, hb + j2);
      float wd = m3  * __shfl(wp, hb + j3); int sd = __shfl(sp, hb + j3);
      float2 ra = *(const float2*)(h1h + (size_t)sa * HH + lane * 4);
      float2 rb = *(const float2*)(h1h + (size_t)sb * HH + lane * 4);
      float2 rc = *(const float2*)(h1h + (size_t)sc * HH + lane * 4);
      float2 rd = *(const float2*)(h1h + (size_t)sd * HH + lane * 4);
      float f0,f1,f2,f3;
      unp4(ra, f0,f1,f2,f3); a0=fmaf(wa,f0,a0); a1=fmaf(wa,f1,a1); a2=fmaf(wa,f2,a2); a3=fmaf(wa,f3,a3);
      unp4(rb, f0,f1,f2,f3); a0=fmaf(wb,f0,a0); a1=fmaf(wb,f1,a1); a2=fmaf(wb,f2,a2); a3=fmaf(wb,f3,a3);
      unp4(rc, f0,f1,f2,f3); a0=fmaf(wc,f0,a0); a1=fmaf(wc,f1,a1); a2=fmaf(wc,f2,a2); a3=fmaf(wc,f3,a3);
      unp4(rd, f0,f1,f2,f3); a0=fmaf(wd,f0,a0); a1=fmaf(wd,f1,a1); a2=fmaf(wd,f2,a2); a3=fmaf(wd,f3,a3);
    }
  };
  pass(w0r, s0r, 0); pass(w1r, s1r, 16); pass(w2r, s2r, 32); pass(w3r, s3r, 48);
  // rare tail: deg > 64, recompute weights directly (uniform loop)
  for (int e = e0 + 64; e < e1; ++e){
    int s = csr[e];
    float w = inv * expf(lrelu(als[s*4+head] + adh));
    float2 r = *(const float2*)(h1h + (size_t)s * HH + lane * 4);
    float f0,f1,f2,f3; unp4(r, f0,f1,f2,f3);
    a0=fmaf(w,f0,a0); a1=fmaf(w,f1,a1); a2=fmaf(w,f2,a2); a3=fmaf(w,f3,a3);
  }

  float4 b4 = *(const float4*)(b1 + lane * 4);
  __half2 p0 = __floats2half2_rn(elu_(a0 + b4.x), elu_(a1 + b4.y));
  __half2 p1 = __floats2half2_rn(elu_(a2 + b4.z), elu_(a3 + b4.w));
  float2 outv; ((__half2*)&outv)[0] = p0; ((__half2*)&outv)[1] = p1;
  *(float2*)(g1h + (size_t)n * HH + lane * 4) = outv;
}

// ---------- h2 = g1 @ W2 via MFMA 16x16x32_f16, fused alpha2 ----------
__global__ void k_gemm2m(const __half* __restrict__ g1h, const __half* __restrict__ Bp,
                         const float* __restrict__ as2, const float* __restrict__ ad2,
                         __half* __restrict__ h2h, float* __restrict__ als2, float* __restrict__ ald2){
  int t = threadIdx.x, wv = t >> 6, lane = t & 63;
  int n0 = blockIdx.x * 64 + wv * 16;    // 16 rows per wave
  int arow = n0 + (lane & 15);
  if (arow > NN - 1) arow = NN - 1;      // clamp for loads; stores guarded
  const _Float16* gbase = (const _Float16*)g1h + (size_t)arow * HH + (lane >> 4) * 8;
  const f16x8* bbase = (const f16x8*)Bp + lane;   // + (kt*4+ct)*64

  f32x4 acc0 = {0.f,0.f,0.f,0.f}, acc1 = {0.f,0.f,0.f,0.f};
  f32x4 acc2 = {0.f,0.f,0.f,0.f}, acc3 = {0.f,0.f,0.f,0.f};
#pragma unroll
  for (int kt = 0; kt < 8; ++kt){
    f16x8 a = *(const f16x8*)(gbase + kt * 32);
    acc0 = __builtin_amdgcn_mfma_f32_16x16x32_f16(a, bbase[(kt*4 + 0) * 64], acc0, 0, 0, 0);
    acc1 = __builtin_amdgcn_mfma_f32_16x16x32_f16(a, bbase[(kt*4 + 1) * 64], acc1, 0, 0, 0);
    acc2 = __builtin_amdgcn_mfma_f32_16x16x32_f16(a, bbase[(kt*4 + 2) * 64], acc2, 0, 0, 0);
    acc3 = __builtin_amdgcn_mfma_f32_16x16x32_f16(a, bbase[(kt*4 + 3) * 64], acc3, 0, 0, 0);
  }
  int c4 = lane & 15, g4 = lane >> 4;
  float as2v0 = as2[c4], as2v1 = as2[16 + c4], as2v2 = as2[32 + c4], as2v3 = as2[48 + c4];
  float ad2v0 = ad2[c4], ad2v1 = ad2[16 + c4], ad2v2 = ad2[32 + c4], ad2v3 = ad2[48 + c4];
  float vs[4], vd[4];
#pragma unroll
  for (int i = 0; i < 4; ++i){
    int n = n0 + g4 * 4 + i;
    if (n < NN){
      h2h[(size_t)n * HID + c4]      = (__half)acc0[i];
      h2h[(size_t)n * HID + 16 + c4] = (__half)acc1[i];
      h2h[(size_t)n * HID + 32 + c4] = (__half)acc2[i];
      h2h[(size_t)n * HID + 48 + c4] = (__half)acc3[i];
    }
    vs[i] = acc0[i]*as2v0 + acc1[i]*as2v1 + acc2[i]*as2v2 + acc3[i]*as2v3;
    vd[i] = acc0[i]*ad2v0 + acc1[i]*ad2v1 + acc2[i]*ad2v2 + acc3[i]*ad2v3;
  }
#pragma unroll
  for (int off = 1; off < 16; off <<= 1){
#pragma unroll
    for (int i = 0; i < 4; ++i){
      vs[i] += __shfl_xor(vs[i], off);
      vd[i] += __shfl_xor(vd[i], off);
    }
  }
  if (c4 == 0){
#pragma unroll
    for (int i = 0; i < 4; ++i){
      int n = n0 + g4 * 4 + i;
      if (n < NN){ als2[n] = vs[i]; ald2[n] = vd[i]; }
    }
  }
}

// ---------- layer-2 weights + gather + ELU -> o2 fp16 (16-lane group per node) ----------
__global__ void k_agg2g(const int* __restrict__ rs, const int* __restrict__ csr,
                        const __half* __restrict__ h2h, const float* __restrict__ als,
                        const float* __restrict__ ald, const float* __restrict__ b2,
                        __half* __restrict__ o2h){
  int t = threadIdx.x, lane = t & 63;
  int q = lane & 15;                 // lane within 16-lane group
  int n = blockIdx.x * 16 + (t >> 4);  // group owns node n
  int e0 = rs[n], e1 = rs[n + 1];
  int deg = e1 - e0;
  float adn = ald[n];

  // phase A: weights for edges q, q+16, q+32, q+48 of OWN node
  float w0r = 0.f, w1r = 0.f, w2r = 0.f, w3r = 0.f;
  int   s0r = 0,   s1r = 0,   s2r = 0,   s3r = 0;
  float den = 0.f;
  if (q      < deg){ s0r = csr[e0 + q];      w0r = expf(lrelu(als[s0r] + adn)); den += w0r; }
  if (q + 16 < deg){ s1r = csr[e0 + 16 + q]; w1r = expf(lrelu(als[s1r] + adn)); den += w1r; }
  if (q + 32 < deg){ s2r = csr[e0 + 32 + q]; w2r = expf(lrelu(als[s2r] + adn)); den += w2r; }
  if (q + 48 < deg){ s3r = csr[e0 + 48 + q]; w3r = expf(lrelu(als[s3r] + adn)); den += w3r; }
  for (int e = e0 + 64 + q; e < e1; e += 16) den += expf(lrelu(als[csr[e]] + adn));
  den += __shfl_xor(den, 1); den += __shfl_xor(den, 2);
  den += __shfl_xor(den, 4); den += __shfl_xor(den, 8);
  float selfw = expf(lrelu(als[n] + adn));
  float inv = 1.f / (den + selfw + 1e-16f);
  float wself = selfw * inv;

  // self term: lane q covers channels q*4..q*4+3
  float a0, a1, a2, a3;
  { float2 r = *(const float2*)(h2h + (size_t)n * HID + q * 4);
    float f0,f1,f2,f3; unp4(r, f0,f1,f2,f3);
    a0 = wself*f0; a1 = wself*f1; a2 = wself*f2; a3 = wself*f3; }

  // wave-uniform edge count (max over the 4 groups); zero weights pad shorter groups
  int dmax = deg;
  dmax = max(dmax, __shfl_xor(dmax, 16));
  dmax = max(dmax, __shfl_xor(dmax, 32));
  int cnt = dmax < 64 ? dmax : 64;
  int gb = lane & 48;
  auto pass = [&](float wp, int sp, int off){
    int lim = cnt - off; if (lim <= 0) return; if (lim > 16) lim = 16;
    for (int j = 0; j < lim; j += 2){
      int j1 = (j + 1 < lim) ? j + 1 : j;
      float mb = (j + 1 < lim) ? inv : 0.f;
      float wa = inv * __shfl(wp, gb + j);  int sa = __shfl(sp, gb + j);
      float wb = mb  * __shfl(wp, gb + j1); int sb = __shfl(sp, gb + j1);
      float2 ra = *(const float2*)(h2h + (size_t)sa * HID + q * 4);
      float2 rb = *(const float2*)(h2h + (size_t)sb * HID + q * 4);
      float f0,f1,f2,f3;
      unp4(ra, f0,f1,f2,f3); a0=fmaf(wa,f0,a0); a1=fmaf(wa,f1,a1); a2=fmaf(wa,f2,a2); a3=fmaf(wa,f3,a3);
      unp4(rb, f0,f1,f2,f3); a0=fmaf(wb,f0,a0); a1=fmaf(wb,f1,a1); a2=fmaf(wb,f2,a2); a3=fmaf(wb,f3,a3);
    }
  };
  pass(w0r, s0r, 0); pass(w1r, s1r, 16); pass(w2r, s2r, 32); pass(w3r, s3r, 48);
  // rare tail: deg > 64, per-group serial recompute (no cross-lane ops)
  for (int e = e0 + 64; e < e1; ++e){
    int s = csr[e];
    float w = inv * expf(lrelu(als[s] + adn));
    float2 r = *(const float2*)(h2h + (size_t)s * HID + q * 4);
    float f0,f1,f2,f3; unp4(r, f0,f1,f2,f3);
    a0=fmaf(w,f0,a0); a1=fmaf(w,f1,a1); a2=fmaf(w,f2,a2); a3=fmaf(w,f3,a3);
  }

  float4 b4 = *(const float4*)(b2 + q * 4);
  __half2 p0 = __floats2half2_rn(elu_(a0 + b4.x), elu_(a1 + b4.y));
  __half2 p1 = __floats2half2_rn(elu_(a2 + b4.z), elu_(a3 + b4.w));
  float2 outv; ((__half2*)&outv)[0] = p0; ((__half2*)&outv)[1] = p1;
  *(float2*)(o2h + (size_t)n * HID + q * 4) = outv;
}

// ---------- hW = o2 @ Wh via MFMA + fused scores (16 nodes/wave) ----------
__global__ void k_hws(const __half* __restrict__ o2h, const __half* __restrict__ Bwh,
                      const float* __restrict__ tWb, const float* __restrict__ w2,
                      const float* __restrict__ b2s, float* __restrict__ out){
  __shared__ float tws[1024];
  __shared__ float w2s[64];
  int t = threadIdx.x, wv = t >> 6, lane = t & 63;
  for (int i = t; i < 1024; i += 256) tws[i] = tWb[i];
  if (t < 64) w2s[t] = w2[t];
  __syncthreads();

  int n0 = blockIdx.x * 64 + wv * 16;    // 16 rows per wave
  int arow = n0 + (lane & 15);
  if (arow > NN - 1) arow = NN - 1;
  const _Float16* obase = (const _Float16*)o2h + (size_t)arow * HID + (lane >> 4) * 8;
  const f16x8* bbase = (const f16x8*)Bwh + lane;   // + (kt*4+ct)*64

  f32x4 acc[4];
#pragma unroll
  for (int ct = 0; ct < 4; ++ct) acc[ct] = (f32x4){0.f,0.f,0.f,0.f};
#pragma unroll
  for (int kt = 0; kt < 2; ++kt){
    f16x8 a = *(const f16x8*)(obase + kt * 32);
#pragma unroll
    for (int ct = 0; ct < 4; ++ct)
      acc[ct] = __builtin_amdgcn_mfma_f32_16x16x32_f16(a, bbase[(kt*4 + ct) * 64], acc[ct], 0, 0, 0);
  }
  // C layout: col = ct*16 + c4, row = g4*4 + i   (16 nodes n0+row)
  int c4 = lane & 15, g4 = lane >> 4;
  float wv0 = w2s[c4], wv1 = w2s[16 + c4], wv2 = w2s[32 + c4], wv3 = w2s[48 + c4];
  float bias = b2s[0];
#pragma unroll
  for (int i = 0; i < 4; ++i){
    int n = n0 + g4 * 4 + i;
    float v[16];
#pragma unroll
    for (int b = 0; b < 16; ++b){
      const float* twb = tws + b * 64;
      v[b] = fmaxf(acc[0][i] + twb[c4], 0.f)      * wv0
           + fmaxf(acc[1][i] + twb[16 + c4], 0.f) * wv1
           + fmaxf(acc[2][i] + twb[32 + c4], 0.f) * wv2
           + fmaxf(acc[3][i] + twb[48 + c4], 0.f) * wv3;
    }
    // 16-value butterfly over the 16-lane group (masks 8,4,2,1)
    bool h3 = (lane & 8) != 0;
    float u[8];
#pragma unroll
    for (int j = 0; j < 8; ++j){
      float keep = h3 ? v[j+8] : v[j];
      float send = h3 ? v[j]   : v[j+8];
      u[j] = keep + __shfl_xor(send, 8);
    }
    bool h2b = (lane & 4) != 0;
    float p[4];
#pragma unroll
    for (int j = 0; j < 4; ++j){
      float keep = h2b ? u[j+4] : u[j];
      float send = h2b ? u[j]   : u[j+4];
      p[j] = keep + __shfl_xor(send, 4);
    }
    bool h1b = (lane & 2) != 0;
    float qq[2];
#pragma unroll
    for (int j = 0; j < 2; ++j){
      float keep = h1b ? p[j+2] : p[j];
      float send = h1b ? p[j]   : p[j+2];
      qq[j] = keep + __shfl_xor(send, 2);
    }
    bool h0 = (lane & 1) != 0;
    float keep = h0 ? qq[1] : qq[0];
    float send = h0 ? qq[0] : qq[1];
    float z = keep + __shfl_xor(send, 1);
    // lane holds score for batch b = c4, node n
    if (n < NN) out[(size_t)c4 * NN + n] = z + bias;
  }
}

extern "C" void kernel_launch(void* const* d_in, const int* in_sizes, int n_in,
                              void* d_out, int out_size, void* d_ws, size_t ws_size,
                              hipStream_t stream){
  const float* x    = (const float*)d_in[0];
  const int*   ei   = (const int*)  d_in[1];
  const float* task = (const float*)d_in[2];
  const float* W1   = (const float*)d_in[3];
  const float* as1  = (const float*)d_in[4];
  const float* ad1  = (const float*)d_in[5];
  const float* b1   = (const float*)d_in[6];
  const float* W2   = (const float*)d_in[7];
  const float* as2  = (const float*)d_in[8];
  const float* ad2  = (const float*)d_in[9];
  const float* b2   = (const float*)d_in[10];
  const float* teW1 = (const float*)d_in[11];
  const float* teb1 = (const float*)d_in[12];
  const float* teW2 = (const float*)d_in[13];
  const float* teb2 = (const float*)d_in[14];
  const float* clW1 = (const float*)d_in[15];
  const float* clb1 = (const float*)d_in[16];
  const float* clW2 = (const float*)d_in[17];
  const float* clb2 = (const float*)d_in[18];
  float* out = (float*)d_out;
  float* ws  = (float*)d_ws;

  // workspace layout (float-sized slots)
  __half* h1h  = (__half*)ws;                    // 12.8M halfs -> 6.4M floats
  float* als1  = ws + 6400000;                   // 200,000
  float* ald1  = als1 + 200000;                  // 200,000
  __half* g1h  = (__half*)(ald1 + 200000);       // 12.8M halfs -> 6.4M floats
  __half* h2h  = (__half*)(ald1 + 200000 + 6400000);  // 3.2M halfs -> 1.6M floats
  float* als2  = ald1 + 200000 + 6400000 + 1600000;   // 50,000
  float* ald2  = als2 + 50000;                   // 50,000
  float* tWb   = ald2 + 50000;                   // 1,024
  int*   deg   = (int*)(tWb + 1024);             // 50,000
  int*   rs    = deg + 50000;                    // 50,001 (+pad)
  int*   csr   = rs + 50004;                     // 800,000
  int*   psum  = csr + 800000;                   // 256
  int*   bcur  = psum + 256;                     // 256
  __half* Bp   = (__half*)(bcur + 256);          // 16,384 halfs (MFMA-ordered W2)
  __half* Bp1  = Bp + 16384;                     // 32,768 halfs (MFMA-ordered W1)
  __half* Bwh  = Bp1 + 32768;                    // 4,096 halfs (MFMA-ordered Wh)
  unsigned* pr = (unsigned*)(Bwh + 4096);        // 800,000 packed pairs (3.2 MB)
  __half* o2h  = (__half*)(pr + 800000);         // 3.2M halfs (o2, fp16)

  hipMemsetAsync(deg, 0, 50000 * sizeof(int), stream);
  // deg histogram + weight prep + task encoder (independent work, one launch)
  k_misc   <<<3152, 256, 0, stream>>>(ei, deg, W2, W1, Bp, Bp1, Bwh,
                                      task, teW1, teb1, teW2, teb2, clW1, clb1, tWb);
  k_psum   <<<196, 256, 0, stream>>>(deg, psum);
  k_wroffs <<<196, 256, 0, stream>>>(deg, psum, rs, bcur);
  // LDS-binned edge partition + layer-1 GEMM (independent, one launch)
  k_binGemm<<<200 + (NN + 63)/64, 256, 0, stream>>>(ei, bcur, pr, x, Bp1,
                                                    as1, ad1, h1h, als1, ald1);
  // exclusive-region CSR placement
  k_place  <<<196, 256, 0, stream>>>(rs, pr, csr);
  // layer 1 aggregate
  k_agg1m  <<<12500, 256, 0, stream>>>(rs, csr, h1h, als1, ald1, b1, g1h);
  // layer 2 GEMM
  k_gemm2m <<<(NN + 63)/64, 256, 0, stream>>>(g1h, Bp, as2, ad2, h2h, als2, ald2);
  // layer 2 aggregate -> o2 (fp16)
  k_agg2g  <<<3125, 256, 0, stream>>>(rs, csr, h2h, als2, ald2, b2, o2h);
  // hW MFMA + fused scores
  k_hws    <<<(NN + 63)/64, 256, 0, stream>>>(o2h, Bwh, tWb, clW2, clb2, out);
}

// Round 14
// 176.916 us; speedup vs baseline: 7.6303x; 1.1891x over previous
//
#include <hip/hip_runtime.h>
#include <hip/hip_fp16.h>

#define NN 50000
#define NE 800000
#define FN 128
#define HH 256      // HEADS*HID
#define HID 64
#define NBKT 196    // 256-node buckets
#define CHUNK 4000  // edges per bin block; 200*4000 == NE
#define REGCAP 8192 // per-bucket region capacity (avg 4096, max ~4350)

typedef _Float16 f16x8 __attribute__((ext_vector_type(8)));
typedef float f32x4 __attribute__((ext_vector_type(4)));

__device__ __forceinline__ float lrelu(float v){ return v >= 0.f ? v : 0.2f * v; }
__device__ __forceinline__ float elu_(float v){ return v > 0.f ? v : expm1f(v); }

__device__ __forceinline__ void unp4(const float2 r, float& f0, float& f1, float& f2, float& f3){
  const __half2* hp = (const __half2*)&r;
  float2 a = __half22float2(hp[0]);
  float2 b = __half22float2(hp[1]);
  f0 = a.x; f1 = a.y; f2 = b.x; f3 = b.y;
}

// ---------- merged: weight prep (W1,W2,Wh) + task encoder + binCnt zero ----------
__global__ void k_misc(const float* __restrict__ W2, const float* __restrict__ W1,
                       __half* __restrict__ Bp, __half* __restrict__ Bp1, __half* __restrict__ Bwh,
                       const float* __restrict__ task, const float* __restrict__ W1t,
                       const float* __restrict__ b1t, const float* __restrict__ W2t,
                       const float* __restrict__ b2t, const float* __restrict__ clW1,
                       const float* __restrict__ clb1, float* __restrict__ tWb,
                       int* __restrict__ binCnt){
  int bid = blockIdx.x, t = threadIdx.x;
  if (bid < 26){                         // prep: 26 blocks cover f<6656
    int f = bid * 256 + t;
    if (f < 2048){
      int lane = f & 63;
      int ct = (f >> 6) & 3, kt = f >> 8;
      int kbase = kt * 32 + (lane >> 4) * 8;
      int col = ct * 16 + (lane & 15);
#pragma unroll
      for (int i = 0; i < 8; ++i)
        Bp[(size_t)f * 8 + i] = (__half)W2[(kbase + i) * HID + col];
    } else if (f < 6144){
      int g = f - 2048;
      int lane = g & 63;
      int ct = (g >> 6) & 15, kt = g >> 10;
      int kbase = kt * 32 + (lane >> 4) * 8;
      int col = ct * 16 + (lane & 15);
#pragma unroll
      for (int i = 0; i < 8; ++i)
        Bp1[(size_t)g * 8 + i] = (__half)W1[(kbase + i) * HH + col];
    } else {
      int g = f - 6144;                  // (kt*4+ct)*64+lane, kt<2, ct<4
      int lane = g & 63;
      int ct = (g >> 6) & 3, kt = g >> 8;
      int kbase = kt * 32 + (lane >> 4) * 8;
      int col = ct * 16 + (lane & 15);
#pragma unroll
      for (int i = 0; i < 8; ++i)
        Bwh[(size_t)g * 8 + i] = (__half)clW1[(kbase + i) * HID + col];
    }
  } else {                               // task block + binCnt zero
    binCnt[t] = 0;
    __shared__ float t1[16][64];
    __shared__ float t2[16][64];
    for (int idx = t; idx < 1024; idx += 256){
      int b = idx >> 6, c = idx & 63;
      float acc = b1t[c];
      for (int k = 0; k < 128; ++k) acc = fmaf(task[b*128 + k], W1t[k*64 + c], acc);
      t1[b][c] = fmaxf(acc, 0.f);
    }
    __syncthreads();
    for (int idx = t; idx < 1024; idx += 256){
      int b = idx >> 6, c = idx & 63;
      float acc = b2t[c];
      for (int k = 0; k < 64; ++k) acc = fmaf(t1[b][k], W2t[k*64 + c], acc);
      t2[b][c] = acc;
    }
    __syncthreads();
    for (int idx = t; idx < 1024; idx += 256){
      int b = idx >> 6, c = idx & 63;
      float acc = clb1[c];
      for (int k = 0; k < 64; ++k) acc = fmaf(t2[b][k], clW1[(64 + k)*64 + c], acc);
      tWb[idx] = acc;
    }
  }
}

// ---------- merged: LDS-binned edge partition into regions + (h1 = x @ W1 MFMA) ----------
// packed: src(16b) | dlocal(8b)<<16 | bucket(8b)<<24
__global__ void k_binGemm(const int* __restrict__ ei, int* __restrict__ binCnt,
                          unsigned* __restrict__ pr,
                          const float* __restrict__ x, const __half* __restrict__ Bp1,
                          const float* __restrict__ as1, const float* __restrict__ ad1,
                          __half* __restrict__ h1h, float* __restrict__ als, float* __restrict__ ald){
  __shared__ int hist[NBKT];
  __shared__ int lstart[NBKT];
  __shared__ int gpos[NBKT];
  __shared__ int cnt[NBKT];
  __shared__ unsigned stage[CHUNK];      // 16 KB
  int bid = blockIdx.x, t = threadIdx.x;
  if (bid < 200){                        // bin: 200*4000 == NE
    int e_base = bid * CHUNK;
    if (t < NBKT){ hist[t] = 0; cnt[t] = 0; }
    __syncthreads();
    for (int i = t; i < CHUNK; i += 256)
      atomicAdd(&hist[ei[NE + e_base + i] >> 8], 1);
    __syncthreads();
    {
      int lane = t & 63, wvi = t >> 6;
      int v = (t < NBKT) ? hist[t] : 0;
      int iv = v;
#pragma unroll
      for (int off = 1; off < 64; off <<= 1){
        int u = __shfl_up(iv, off);
        if (lane >= off) iv += u;
      }
      __shared__ int wsum[4];
      if (lane == 63) wsum[wvi] = iv;
      __syncthreads();
      int add = 0;
      for (int w = 0; w < wvi; ++w) add += wsum[w];
      iv += add;
      if (t < NBKT){
        lstart[t] = iv - v;
        gpos[t] = (v > 0) ? atomicAdd(&binCnt[t], v) : 0;
      }
    }
    __syncthreads();
    for (int i = t; i < CHUNK; i += 256){
      int e = e_base + i;
      int s = ei[e], d = ei[NE + e];
      int bb = d >> 8;
      int r = atomicAdd(&cnt[bb], 1);
      stage[lstart[bb] + r] = (unsigned)s | ((unsigned)(d & 255) << 16) | ((unsigned)bb << 24);
    }
    __syncthreads();
    for (int i = t; i < CHUNK; i += 256){
      unsigned p = stage[i];
      int bb = p >> 24;
      pr[(size_t)bb * REGCAP + gpos[bb] + (i - lstart[bb])] = p;
    }
    return;
  }
  // gemm1m part
  int blk = bid - 200;
  int wv = t >> 6, lane = t & 63;
  int n0 = blk * 64 + wv * 16;           // 16 rows per wave
  int arow = n0 + (lane & 15);
  if (arow > NN - 1) arow = NN - 1;      // clamp for loads; stores guarded
  const float* xbase = x + (size_t)arow * FN + (lane >> 4) * 8;
  const f16x8* bbase = (const f16x8*)Bp1 + lane;   // + (kt*16+ct)*64

  f32x4 acc[16];
#pragma unroll
  for (int ct = 0; ct < 16; ++ct) acc[ct] = (f32x4){0.f,0.f,0.f,0.f};

#pragma unroll
  for (int kt = 0; kt < 4; ++kt){
    float4 xa = *(const float4*)(xbase + kt * 32);
    float4 xb = *(const float4*)(xbase + kt * 32 + 4);
    f16x8 a;
    a[0] = (_Float16)xa.x; a[1] = (_Float16)xa.y; a[2] = (_Float16)xa.z; a[3] = (_Float16)xa.w;
    a[4] = (_Float16)xb.x; a[5] = (_Float16)xb.y; a[6] = (_Float16)xb.z; a[7] = (_Float16)xb.w;
#pragma unroll
    for (int ct = 0; ct < 16; ++ct)
      acc[ct] = __builtin_amdgcn_mfma_f32_16x16x32_f16(a, bbase[(kt*16 + ct) * 64], acc[ct], 0, 0, 0);
  }

  // C/D mapping: col = ct*16 + (lane&15), row = (lane>>4)*4 + i
  int c4 = lane & 15, g4 = lane >> 4;
#pragma unroll
  for (int ct = 0; ct < 16; ++ct){
#pragma unroll
    for (int i = 0; i < 4; ++i){
      int n = n0 + g4 * 4 + i;
      if (n < NN) h1h[(size_t)n * HH + ct * 16 + c4] = (__half)acc[ct][i];
    }
  }
#pragma unroll
  for (int h = 0; h < 4; ++h){
    float sa0 = as1[(h*4+0)*16 + c4], sa1 = as1[(h*4+1)*16 + c4];
    float sa2 = as1[(h*4+2)*16 + c4], sa3 = as1[(h*4+3)*16 + c4];
    float da0 = ad1[(h*4+0)*16 + c4], da1 = ad1[(h*4+1)*16 + c4];
    float da2 = ad1[(h*4+2)*16 + c4], da3 = ad1[(h*4+3)*16 + c4];
#pragma unroll
    for (int i = 0; i < 4; ++i){
      float vs = acc[h*4+0][i]*sa0 + acc[h*4+1][i]*sa1 + acc[h*4+2][i]*sa2 + acc[h*4+3][i]*sa3;
      float vd = acc[h*4+0][i]*da0 + acc[h*4+1][i]*da1 + acc[h*4+2][i]*da2 + acc[h*4+3][i]*da3;
#pragma unroll
      for (int off = 1; off < 16; off <<= 1){
        vs += __shfl_xor(vs, off);
        vd += __shfl_xor(vd, off);
      }
      if (c4 == 0){
        int n = n0 + g4 * 4 + i;
        if (n < NN){ als[n*4 + h] = vs; ald[n*4 + h] = vd; }
      }
    }
  }
}

// ---------- rs + csr from regions: block b owns bucket b (nodes [256b,256b+256)) ----------
__global__ void k_rsplace(const int* __restrict__ binCnt, const unsigned* __restrict__ pr,
                          int* __restrict__ rs, int* __restrict__ csr){
  __shared__ int bbase[256];
  __shared__ int hist[256];
  __shared__ int lp[256];
  __shared__ int wsA[4];
  __shared__ int wsB[4];
  int b = blockIdx.x, t = threadIdx.x;
  int lane = t & 63, wv = t >> 6;
  // exclusive scan of the 196 bucket counts (redundant per block; cheap)
  {
    int v = (t < NBKT) ? binCnt[t] : 0;
    int iv = v;
#pragma unroll
    for (int off = 1; off < 64; off <<= 1){
      int u = __shfl_up(iv, off);
      if (lane >= off) iv += u;
    }
    if (lane == 63) wsA[wv] = iv;
    __syncthreads();
    int add = 0;
    for (int w = 0; w < wv; ++w) add += wsA[w];
    bbase[t] = iv + add - v;
    hist[t] = 0;
  }
  __syncthreads();
  int myBase = bbase[b];
  int myCnt  = binCnt[b];
  const unsigned* reg = pr + (size_t)b * REGCAP;
  for (int i = t; i < myCnt; i += 256)
    atomicAdd(&hist[(reg[i] >> 16) & 255], 1);
  __syncthreads();
  // exclusive scan of the 256 per-node counts
  int excl;
  {
    int v = hist[t];
    int iv = v;
#pragma unroll
    for (int off = 1; off < 64; off <<= 1){
      int u = __shfl_up(iv, off);
      if (lane >= off) iv += u;
    }
    if (lane == 63) wsB[wv] = iv;
    __syncthreads();
    int add = 0;
    for (int w = 0; w < wv; ++w) add += wsB[w];
    excl = myBase + iv + add - v;
    lp[t] = excl;
  }
  int idx = b * 256 + t;
  if (idx < NN) rs[idx] = excl;
  if (b == 0 && t == 0) rs[NN] = NE;
  __syncthreads();            // lp ready; rs reads done before cursor atomics
  for (int i = t; i < myCnt; i += 256){
    unsigned p = reg[i];
    int pos = atomicAdd(&lp[(p >> 16) & 255], 1);
    csr[pos] = (int)(p & 0xFFFFu);
  }
}

// ---------- fused layer-1 softmax weights + gather + ELU (wave per node) ----------
__global__ void k_agg1m(const int* __restrict__ rs, const int* __restrict__ csr,
                        const __half* __restrict__ h1h, const float* __restrict__ als,
                        const float* __restrict__ ald, const float* __restrict__ b1,
                        __half* __restrict__ g1h){
  int t = threadIdx.x, wv = t >> 6, lane = t & 63;
  int head = lane >> 4, q = lane & 15;
  int n = blockIdx.x * 4 + wv;
  int e0 = rs[n], e1 = rs[n + 1];
  int deg = e1 - e0;
  float adh = ald[n*4 + head];

  float w0r = 0.f, w1r = 0.f, w2r = 0.f, w3r = 0.f;
  int   s0r = 0,   s1r = 0,   s2r = 0,   s3r = 0;
  float den = 0.f;
  if (q      < deg){ s0r = csr[e0 + q];      w0r = expf(lrelu(als[s0r*4+head] + adh)); den += w0r; }
  if (q + 16 < deg){ s1r = csr[e0 + 16 + q]; w1r = expf(lrelu(als[s1r*4+head] + adh)); den += w1r; }
  if (q + 32 < deg){ s2r = csr[e0 + 32 + q]; w2r = expf(lrelu(als[s2r*4+head] + adh)); den += w2r; }
  if (q + 48 < deg){ s3r = csr[e0 + 48 + q]; w3r = expf(lrelu(als[s3r*4+head] + adh)); den += w3r; }
  for (int e = e0 + 64 + q; e < e1; e += 16) den += expf(lrelu(als[csr[e]*4+head] + adh));
  den += __shfl_xor(den, 1); den += __shfl_xor(den, 2);
  den += __shfl_xor(den, 4); den += __shfl_xor(den, 8);
  float selfw = expf(lrelu(als[n*4+head] + adh));
  float inv = 1.f / (den + selfw + 1e-16f);
  float wself = selfw * inv;

  float a0, a1, a2, a3;
  { float2 r = *(const float2*)(h1h + (size_t)n * HH + lane * 4);
    float f0,f1,f2,f3; unp4(r, f0,f1,f2,f3);
    a0 = wself*f0; a1 = wself*f1; a2 = wself*f2; a3 = wself*f3; }

  int hb = lane & 48;
  int cnt = deg < 64 ? deg : 64;
  auto pass = [&](float wp, int sp, int off){
    int lim = cnt - off; if (lim <= 0) return; if (lim > 16) lim = 16;
    for (int q2 = 0; q2 < lim; q2 += 4){          // wave-uniform trip count
      int j1 = q2 + 1, j2 = q2 + 2, j3 = q2 + 3;
      float m1 = (j1 < lim) ? inv : 0.f; if (j1 >= lim) j1 = q2;
      float m2 = (j2 < lim) ? inv : 0.f; if (j2 >= lim) j2 = q2;
      float m3 = (j3 < lim) ? inv : 0.f; if (j3 >= lim) j3 = q2;
      float wa = inv * __shfl(wp, hb + q2); int sa = __shfl(sp, hb + q2);
      float wb = m1  * __shfl(wp, hb + j1); int sb = __shfl(sp, hb + j1);
      float wc = m2  * __shfl(wp, hb + j2); int sc = __shfl(sp, hb + j2);
      float wd = m3  * __shfl(wp, hb + j3); int sd = __shfl(sp, hb + j3);
      float2 ra = *(const float2*)(h1h + (size_t)sa * HH + lane * 4);
      float2 rb = *(const float2*)(h1h + (size_t)sb * HH + lane * 4);
      float2 rc = *(const float2*)(h1h + (size_t)sc * HH + lane * 4);
      float2 rd = *(const float2*)(h1h + (size_t)sd * HH + lane * 4);
      float f0,f1,f2,f3;
      unp4(ra, f0,f1,f2,f3); a0=fmaf(wa,f0,a0); a1=fmaf(wa,f1,a1); a2=fmaf(wa,f2,a2); a3=fmaf(wa,f3,a3);
      unp4(rb, f0,f1,f2,f3); a0=fmaf(wb,f0,a0); a1=fmaf(wb,f1,a1); a2=fmaf(wb,f2,a2); a3=fmaf(wb,f3,a3);
      unp4(rc, f0,f1,f2,f3); a0=fmaf(wc,f0,a0); a1=fmaf(wc,f1,a1); a2=fmaf(wc,f2,a2); a3=fmaf(wc,f3,a3);
      unp4(rd, f0,f1,f2,f3); a0=fmaf(wd,f0,a0); a1=fmaf(wd,f1,a1); a2=fmaf(wd,f2,a2); a3=fmaf(wd,f3,a3);
    }
  };
  pass(w0r, s0r, 0); pass(w1r, s1r, 16); pass(w2r, s2r, 32); pass(w3r, s3r, 48);
  // rare tail: deg > 64, recompute weights directly (uniform loop)
  for (int e = e0 + 64; e < e1; ++e){
    int s = csr[e];
    float w = inv * expf(lrelu(als[s*4+head] + adh));
    float2 r = *(const float2*)(h1h + (size_t)s * HH + lane * 4);
    float f0,f1,f2,f3; unp4(r, f0,f1,f2,f3);
    a0=fmaf(w,f0,a0); a1=fmaf(w,f1,a1); a2=fmaf(w,f2,a2); a3=fmaf(w,f3,a3);
  }

  float4 b4 = *(const float4*)(b1 + lane * 4);
  __half2 p0 = __floats2half2_rn(elu_(a0 + b4.x), elu_(a1 + b4.y));
  __half2 p1 = __floats2half2_rn(elu_(a2 + b4.z), elu_(a3 + b4.w));
  float2 outv; ((__half2*)&outv)[0] = p0; ((__half2*)&outv)[1] = p1;
  *(float2*)(g1h + (size_t)n * HH + lane * 4) = outv;
}

// ---------- h2 = g1 @ W2 via MFMA 16x16x32_f16, fused alpha2 ----------
__global__ void k_gemm2m(const __half* __restrict__ g1h, const __half* __restrict__ Bp,
                         const float* __restrict__ as2, const float* __restrict__ ad2,
                         __half* __restrict__ h2h, float* __restrict__ als2, float* __restrict__ ald2){
  int t = threadIdx.x, wv = t >> 6, lane = t & 63;
  int n0 = blockIdx.x * 64 + wv * 16;    // 16 rows per wave
  int arow = n0 + (lane & 15);
  if (arow > NN - 1) arow = NN - 1;      // clamp for loads; stores guarded
  const _Float16* gbase = (const _Float16*)g1h + (size_t)arow * HH + (lane >> 4) * 8;
  const f16x8* bbase = (const f16x8*)Bp + lane;   // + (kt*4+ct)*64

  f32x4 acc0 = {0.f,0.f,0.f,0.f}, acc1 = {0.f,0.f,0.f,0.f};
  f32x4 acc2 = {0.f,0.f,0.f,0.f}, acc3 = {0.f,0.f,0.f,0.f};
#pragma unroll
  for (int kt = 0; kt < 8; ++kt){
    f16x8 a = *(const f16x8*)(gbase + kt * 32);
    acc0 = __builtin_amdgcn_mfma_f32_16x16x32_f16(a, bbase[(kt*4 + 0) * 64], acc0, 0, 0, 0);
    acc1 = __builtin_amdgcn_mfma_f32_16x16x32_f16(a, bbase[(kt*4 + 1) * 64], acc1, 0, 0, 0);
    acc2 = __builtin_amdgcn_mfma_f32_16x16x32_f16(a, bbase[(kt*4 + 2) * 64], acc2, 0, 0, 0);
    acc3 = __builtin_amdgcn_mfma_f32_16x16x32_f16(a, bbase[(kt*4 + 3) * 64], acc3, 0, 0, 0);
  }
  int c4 = lane & 15, g4 = lane >> 4;
  float as2v0 = as2[c4], as2v1 = as2[16 + c4], as2v2 = as2[32 + c4], as2v3 = as2[48 + c4];
  float ad2v0 = ad2[c4], ad2v1 = ad2[16 + c4], ad2v2 = ad2[32 + c4], ad2v3 = ad2[48 + c4];
  float vs[4], vd[4];
#pragma unroll
  for (int i = 0; i < 4; ++i){
    int n = n0 + g4 * 4 + i;
    if (n < NN){
      h2h[(size_t)n * HID + c4]      = (__half)acc0[i];
      h2h[(size_t)n * HID + 16 + c4] = (__half)acc1[i];
      h2h[(size_t)n * HID + 32 + c4] = (__half)acc2[i];
      h2h[(size_t)n * HID + 48 + c4] = (__half)acc3[i];
    }
    vs[i] = acc0[i]*as2v0 + acc1[i]*as2v1 + acc2[i]*as2v2 + acc3[i]*as2v3;
    vd[i] = acc0[i]*ad2v0 + acc1[i]*ad2v1 + acc2[i]*ad2v2 + acc3[i]*ad2v3;
  }
#pragma unroll
  for (int off = 1; off < 16; off <<= 1){
#pragma unroll
    for (int i = 0; i < 4; ++i){
      vs[i] += __shfl_xor(vs[i], off);
      vd[i] += __shfl_xor(vd[i], off);
    }
  }
  if (c4 == 0){
#pragma unroll
    for (int i = 0; i < 4; ++i){
      int n = n0 + g4 * 4 + i;
      if (n < NN){ als2[n] = vs[i]; ald2[n] = vd[i]; }
    }
  }
}

// ---------- fused: layer-2 weights+gather+ELU (LDS) -> o@Wh MFMA -> scores ----------
// block = 64 nodes; 16-lane group handles 4 nodes sequentially; o in padded LDS.
#define OSTRIDE 72   // halfs; 144 B rows -> <=2-way LDS bank aliasing
__global__ void k_agg2f(const int* __restrict__ rs, const int* __restrict__ csr,
                        const __half* __restrict__ h2h, const float* __restrict__ als,
                        const float* __restrict__ ald, const float* __restrict__ b2,
                        const __half* __restrict__ Bwh, const float* __restrict__ tWb,
                        const float* __restrict__ w2, const float* __restrict__ b2s,
                        float* __restrict__ out){
  __shared__ __half o_lds[64 * OSTRIDE];
  __shared__ float tws[1024];
  __shared__ float w2s[64];
  int t = threadIdx.x, lane = t & 63, wv = t >> 6;
  for (int i = t; i < 1024; i += 256) tws[i] = tWb[i];
  if (t < 64) w2s[t] = w2[t];

  int q = lane & 15;
  int g = t >> 4;                      // group 0..15
  int n0b = blockIdx.x * 64;
  int gb = lane & 48;
#pragma unroll 1
  for (int j = 0; j < 4; ++j){
    int nl = g * 4 + j;                // node_local 0..63
    int n = n0b + nl;
    int nc = (n < NN) ? n : NN - 1;
    int e0 = rs[nc], e1 = rs[nc + 1];
    int deg = e1 - e0;
    float adn = ald[nc];

    float w0r = 0.f, w1r = 0.f, w2r = 0.f, w3r = 0.f;
    int   s0r = 0,   s1r = 0,   s2r = 0,   s3r = 0;
    float den = 0.f;
    if (q      < deg){ s0r = csr[e0 + q];      w0r = expf(lrelu(als[s0r] + adn)); den += w0r; }
    if (q + 16 < deg){ s1r = csr[e0 + 16 + q]; w1r = expf(lrelu(als[s1r] + adn)); den += w1r; }
    if (q + 32 < deg){ s2r = csr[e0 + 32 + q]; w2r = expf(lrelu(als[s2r] + adn)); den += w2r; }
    if (q + 48 < deg){ s3r = csr[e0 + 48 + q]; w3r = expf(lrelu(als[s3r] + adn)); den += w3r; }
    for (int e = e0 + 64 + q; e < e1; e += 16) den += expf(lrelu(als[csr[e]] + adn));
    den += __shfl_xor(den, 1); den += __shfl_xor(den, 2);
    den += __shfl_xor(den, 4); den += __shfl_xor(den, 8);
    float selfw = expf(lrelu(als[nc] + adn));
    float inv = 1.f / (den + selfw + 1e-16f);
    float wself = selfw * inv;

    float a0, a1, a2, a3;
    { float2 r = *(const float2*)(h2h + (size_t)nc * HID + q * 4);
      float f0,f1,f2,f3; unp4(r, f0,f1,f2,f3);
      a0 = wself*f0; a1 = wself*f1; a2 = wself*f2; a3 = wself*f3; }

    int dmax = deg;
    dmax = max(dmax, __shfl_xor(dmax, 16));
    dmax = max(dmax, __shfl_xor(dmax, 32));
    int cnt = dmax < 64 ? dmax : 64;
    auto pass = [&](float wp, int sp, int off){
      int lim = cnt - off; if (lim <= 0) return; if (lim > 16) lim = 16;
      for (int jj = 0; jj < lim; jj += 2){
        int j1 = (jj + 1 < lim) ? jj + 1 : jj;
        float mb = (jj + 1 < lim) ? inv : 0.f;
        float wa = inv * __shfl(wp, gb + jj); int sa = __shfl(sp, gb + jj);
        float wb = mb  * __shfl(wp, gb + j1); int sb = __shfl(sp, gb + j1);
        float2 ra = *(const float2*)(h2h + (size_t)sa * HID + q * 4);
        float2 rb = *(const float2*)(h2h + (size_t)sb * HID + q * 4);
        float f0,f1,f2,f3;
        unp4(ra, f0,f1,f2,f3); a0=fmaf(wa,f0,a0); a1=fmaf(wa,f1,a1); a2=fmaf(wa,f2,a2); a3=fmaf(wa,f3,a3);
        unp4(rb, f0,f1,f2,f3); a0=fmaf(wb,f0,a0); a1=fmaf(wb,f1,a1); a2=fmaf(wb,f2,a2); a3=fmaf(wb,f3,a3);
      }
    };
    pass(w0r, s0r, 0); pass(w1r, s1r, 16); pass(w2r, s2r, 32); pass(w3r, s3r, 48);
    for (int e = e0 + 64; e < e1; ++e){
      int s = csr[e];
      float w = inv * expf(lrelu(als[s] + adn));
      float2 r = *(const float2*)(h2h + (size_t)s * HID + q * 4);
      float f0,f1,f2,f3; unp4(r, f0,f1,f2,f3);
      a0=fmaf(w,f0,a0); a1=fmaf(w,f1,a1); a2=fmaf(w,f2,a2); a3=fmaf(w,f3,a3);
    }

    float4 b4 = *(const float4*)(b2 + q * 4);
    __half2 p0 = __floats2half2_rn(elu_(a0 + b4.x), elu_(a1 + b4.y));
    __half2 p1 = __floats2half2_rn(elu_(a2 + b4.z), elu_(a3 + b4.w));
    float2 outv; ((__half2*)&outv)[0] = p0; ((__half2*)&outv)[1] = p1;
    *(float2*)(o_lds + nl * OSTRIDE + q * 4) = outv;
  }
  __syncthreads();

  // hW MFMA + fused scores (wave wv handles nodes n0b + wv*16 .. +15)
  const _Float16* obase = (const _Float16*)o_lds + (wv * 16 + (lane & 15)) * OSTRIDE + (lane >> 4) * 8;
  const f16x8* bbase = (const f16x8*)Bwh + lane;   // + (kt*4+ct)*64

  f32x4 acc[4];
#pragma unroll
  for (int ct = 0; ct < 4; ++ct) acc[ct] = (f32x4){0.f,0.f,0.f,0.f};
#pragma unroll
  for (int kt = 0; kt < 2; ++kt){
    f16x8 a = *(const f16x8*)(obase + kt * 32);
#pragma unroll
    for (int ct = 0; ct < 4; ++ct)
      acc[ct] = __builtin_amdgcn_mfma_f32_16x16x32_f16(a, bbase[(kt*4 + ct) * 64], acc[ct], 0, 0, 0);
  }
  int c4 = lane & 15, g4 = lane >> 4;
  float wv0 = w2s[c4], wv1 = w2s[16 + c4], wv2 = w2s[32 + c4], wv3 = w2s[48 + c4];
  float bias = b2s[0];
#pragma unroll
  for (int i = 0; i < 4; ++i){
    int n = n0b + wv * 16 + g4 * 4 + i;
    float v[16];
#pragma unroll
    for (int b = 0; b < 16; ++b){
      const float* twb = tws + b * 64;
      v[b] = fmaxf(acc[0][i] + twb[c4], 0.f)      * wv0
           + fmaxf(acc[1][i] + twb[16 + c4], 0.f) * wv1
           + fmaxf(acc[2][i] + twb[32 + c4], 0.f) * wv2
           + fmaxf(acc[3][i] + twb[48 + c4], 0.f) * wv3;
    }
    bool h3 = (lane & 8) != 0;
    float u[8];
#pragma unroll
    for (int jj = 0; jj < 8; ++jj){
      float keep = h3 ? v[jj+8] : v[jj];
      float send = h3 ? v[jj]   : v[jj+8];
      u[jj] = keep + __shfl_xor(send, 8);
    }
    bool h2b = (lane & 4) != 0;
    float p[4];
#pragma unroll
    for (int jj = 0; jj < 4; ++jj){
      float keep = h2b ? u[jj+4] : u[jj];
      float send = h2b ? u[jj]   : u[jj+4];
      p[jj] = keep + __shfl_xor(send, 4);
    }
    bool h1b = (lane & 2) != 0;
    float qq[2];
#pragma unroll
    for (int jj = 0; jj < 2; ++jj){
      float keep = h1b ? p[jj+2] : p[jj];
      float send = h1b ? p[jj]   : p[jj+2];
      qq[jj] = keep + __shfl_xor(send, 2);
    }
    bool h0 = (lane & 1) != 0;
    float keep = h0 ? qq[1] : qq[0];
    float send = h0 ? qq[0] : qq[1];
    float z = keep + __shfl_xor(send, 1);
    if (n < NN) out[(size_t)c4 * NN + n] = z + bias;
  }
}

extern "C" void kernel_launch(void* const* d_in, const int* in_sizes, int n_in,
                              void* d_out, int out_size, void* d_ws, size_t ws_size,
                              hipStream_t stream){
  const float* x    = (const float*)d_in[0];
  const int*   ei   = (const int*)  d_in[1];
  const float* task = (const float*)d_in[2];
  const float* W1   = (const float*)d_in[3];
  const float* as1  = (const float*)d_in[4];
  const float* ad1  = (const float*)d_in[5];
  const float* b1   = (const float*)d_in[6];
  const float* W2   = (const float*)d_in[7];
  const float* as2  = (const float*)d_in[8];
  const float* ad2  = (const float*)d_in[9];
  const float* b2   = (const float*)d_in[10];
  const float* teW1 = (const float*)d_in[11];
  const float* teb1 = (const float*)d_in[12];
  const float* teW2 = (const float*)d_in[13];
  const float* teb2 = (const float*)d_in[14];
  const float* clW1 = (const float*)d_in[15];
  const float* clb1 = (const float*)d_in[16];
  const float* clW2 = (const float*)d_in[17];
  const float* clb2 = (const float*)d_in[18];
  float* out = (float*)d_out;
  float* ws  = (float*)d_ws;

  // workspace layout (float-sized slots)
  __half* h1h  = (__half*)ws;                    // 12.8M halfs -> 6.4M floats
  float* als1  = ws + 6400000;                   // 200,000
  float* ald1  = als1 + 200000;                  // 200,000
  __half* g1h  = (__half*)(ald1 + 200000);       // 12.8M halfs -> 6.4M floats
  __half* h2h  = (__half*)(ald1 + 200000 + 6400000);  // 3.2M halfs -> 1.6M floats
  float* als2  = ald1 + 200000 + 6400000 + 1600000;   // 50,000
  float* ald2  = als2 + 50000;                   // 50,000
  float* tWb   = ald2 + 50000;                   // 1,024
  int*   rs    = (int*)(tWb + 1024);             // 50,001 (+pad)
  int*   csr   = rs + 50004;                     // 800,000
  int*   binCnt= csr + 800000;                   // 256
  __half* Bp   = (__half*)(binCnt + 256);        // 16,384 halfs (MFMA-ordered W2)
  __half* Bp1  = Bp + 16384;                     // 32,768 halfs (MFMA-ordered W1)
  __half* Bwh  = Bp1 + 32768;                    // 4,096 halfs (MFMA-ordered Wh)
  unsigned* pr = (unsigned*)(Bwh + 4096);        // 196*8192 packed pairs (6.4 MB)

  // weight prep + task encoder + binCnt zero (27 blocks)
  k_misc   <<<27, 256, 0, stream>>>(W2, W1, Bp, Bp1, Bwh,
                                    task, teW1, teb1, teW2, teb2, clW1, clb1, tWb, binCnt);
  // LDS-binned edge partition into regions + layer-1 GEMM (one launch)
  k_binGemm<<<200 + (NN + 63)/64, 256, 0, stream>>>(ei, binCnt, pr, x, Bp1,
                                                    as1, ad1, h1h, als1, ald1);
  // rs + csr from regions
  k_rsplace<<<NBKT, 256, 0, stream>>>(binCnt, pr, rs, csr);
  // layer 1 aggregate
  k_agg1m  <<<12500, 256, 0, stream>>>(rs, csr, h1h, als1, ald1, b1, g1h);
  // layer 2 GEMM
  k_gemm2m <<<(NN + 63)/64, 256, 0, stream>>>(g1h, Bp, as2, ad2, h2h, als2, ald2);
  // layer 2 aggregate + hW MFMA + scores (fused)
  k_agg2f  <<<(NN + 63)/64, 256, 0, stream>>>(rs, csr, h2h, als2, ald2, b2,
                                              Bwh, tWb, clW2, clb2, out);
}